// Round 3
// baseline (5343.599 us; speedup 1.0000x reference)
//
#include <hip/hip_runtime.h>
#include <math.h>

// N=4, L=S=4096, C=256, K=100, NHEAD=8, D=32. FP32 I/O.
// Big GEMMs: bf16x3 split MFMA (hi*hi + hi*lo + lo*hi, fp32 acc) ~ fp32 fidelity.
// Sample loop batched into 48 packed segments (6 samples x 8 batch-halves),
// 128-aligned inside an [8][4864]-row arena.
// LN fused into GEMM epilogues (gemm256: full 256-col row per block).
// R1: panel-major weights (256-col groups of [k/32][n&255][32]) for coalesced
//     B loads; depth-1 register prefetch.
// R2: wB Q fused into K/V gmain (per-sel segment ranges); zmsg 32 rows/block;
//     softmax+argmax fused. (depth-2 prefetch REVERTED in R3: 409->434 regression)
// R3: dispatch-count cuts (~95 -> ~80/replay; measured ~20us/dispatch overhead):
//     kv direct-store (no memset/atomics) when nch==1; topic pipeline 5->1
//     (tm_all); topicp+transpose folded into seedsF (writes sT directly);
//     gather folded into ord.

typedef __attribute__((ext_vector_type(8))) short short8;
typedef __attribute__((ext_vector_type(4))) short s4;
typedef __attribute__((ext_vector_type(4))) float f32x4;

#define ARENA 4864  // rows per g in packed arena (4096 + 6*128 alignment pad)

__device__ __forceinline__ short f2bf(float f) {
  unsigned u = __float_as_uint(f);
  return (short)((u + 0x7FFFu + ((u >> 16) & 1u)) >> 16);
}
__device__ __forceinline__ float bf2f(short s) {
  return __uint_as_float(((unsigned)(unsigned short)s) << 16);
}

// ---------------------------------------------------------------------------
// Weight prep: per layer L, panel-major bf16 hi/lo planes.
// Layout per matrix: 256-col groups; group g holds cols [g*256,(g+1)*256);
// within group: panel p = k/32 (8192 shorts each); within panel: (n&255)*32+(k&31).
// Per-layer stride 1310720 shorts:
//   +0       QKV [768][256] hi (Wq group0, Wk group1, Wv group2), lo +196608
//   +393216  Wm  [256][256] hi, lo +65536
//   +524288  W1  [512][512] hi (2 groups of 131072), lo +262144
//   +1048576 W2  [256][512] hi, lo +131072
// ---------------------------------------------------------------------------
__global__ void prep_w_kernel(const float* __restrict__ Wq, const float* __restrict__ Wk,
                              const float* __restrict__ Wv, const float* __restrict__ Wm,
                              const float* __restrict__ W1, const float* __restrict__ W2,
                              short* __restrict__ wb) {
  long i = (long)blockIdx.x * 256 + threadIdx.x;
  if (i >= 8L * 655360) return;
  int L = (int)(i / 655360);
  int r = (int)(i % 655360);
  long base = (long)L * 1310720;
  float v; long dhi; int loD;
  if (r < 196608) {
    int n = r >> 8, k = r & 255;
    const float* s = (n < 256) ? (Wq + (long)L * 65536)
                   : (n < 512) ? (Wk + (long)L * 65536) : (Wv + (long)L * 65536);
    v = s[k * 256 + (n & 255)];
    dhi = base + ((long)(n >> 8) << 16) + ((long)(k >> 5) << 13) + ((n & 255) << 5) + (k & 31);
    loD = 196608;
  } else if (r < 262144) {
    int j = r - 196608; int n = j >> 8, k = j & 255;
    v = Wm[(long)L * 65536 + k * 256 + n];
    dhi = base + 393216 + ((long)(k >> 5) << 13) + (n << 5) + (k & 31);
    loD = 65536;
  } else if (r < 524288) {
    int j = r - 262144; int n = j >> 9, k = j & 511;
    v = W1[(long)L * 262144 + (long)k * 512 + n];
    dhi = base + 524288 + ((long)(n >> 8) << 17) + ((long)(k >> 5) << 13) + ((n & 255) << 5) + (k & 31);
    loD = 262144;
  } else {
    int j = r - 524288; int n = j >> 9, k = j & 511;
    v = W2[(long)L * 131072 + (long)k * 256 + n];
    dhi = base + 1048576 + ((long)(k >> 5) << 13) + (n << 5) + (k & 31);
    loD = 131072;
  }
  short h = f2bf(v);
  wb[dhi] = h;
  wb[dhi + loD] = f2bf(v - bf2f(h));
}

// ---------------------------------------------------------------------------
// gemm_main: 128x128 tiles, plain-batch OR packed-segment addressing,
// up to 3 column-routed outputs, optional dual A ([x | A2] for h1).
// modes: 0 none, 1 relu, 2 elu(x)+1. Panel-layout B + depth-1 prefetch.
// Per-column-group segment ranges: sel==0 uses [gmin,gmax], sel>=1 uses
// [gminB,gmaxB] (lets one launch do Q on x-half and K/V on source-half).
// ---------------------------------------------------------------------------
__global__ __launch_bounds__(256) void gemm_main_kernel(
    const float* __restrict__ A, const float* __restrict__ A2, int aw,
    const short* __restrict__ Bh, int loD,
    float* __restrict__ C0, float* __restrict__ C1, float* __restrict__ C2,
    int M, int Kd, int outW, long sA, long sC,
    const int* __restrict__ cnt, int bmask, int bxor,
    const int* __restrict__ segOff, const int* __restrict__ segCnt,
    int gmin, int gmax, int gminB, int gmaxB,
    int mode0, int mode1, int mode2)
{
  int colg = blockIdx.x * 128;
  int sel = colg / outW;
  int glo = (sel == 0) ? gmin : gminB;
  int ghi = (sel == 0) ? gmax : gmaxB;
  int z = blockIdx.z;
  long aBase, cBase; int cntb;
  if (segOff) {
    int g = z & 7;
    if (g < glo || g > ghi) return;
    long rb = (long)g * ARENA + segOff[z];
    aBase = rb * aw; cBase = rb * (long)outW;
    cntb = segCnt[z];
  } else {
    int ab = (z & bmask) ^ bxor;
    aBase = (long)ab * sA; cBase = (long)z * sC;
    cntb = cnt ? min(cnt[ab], M) : M;
  }
  int row0 = blockIdx.y * 128;
  if (row0 >= cntb) return;
  float* Cb = (sel == 0 ? C0 : (sel == 1 ? C1 : C2)) + cBase;
  int mode = (sel == 0 ? mode0 : (sel == 1 ? mode1 : mode2));
  int colo = colg % outW;

  int t = threadIdx.x;
  int lane = t & 63, wid = t >> 6, wm = wid >> 1, wn = wid & 1;
  int fi = lane & 15, fq = lane >> 4;

  __shared__ __align__(16) short Ah[128][36];
  __shared__ __align__(16) short Al[128][36];
  __shared__ __align__(16) short Bsh[128][36];
  __shared__ __align__(16) short Bsl[128][36];

  f32x4 acc[4][4];
  #pragma unroll
  for (int i = 0; i < 4; i++)
    #pragma unroll
    for (int j = 0; j < 4; j++)
      acc[i][j] = (f32x4){0.f, 0.f, 0.f, 0.f};

  int tr = t >> 3, tc = (t & 7) * 4;
  int nc = t >> 1, kh = (t & 1) * 16;
  int gb = colg >> 8;
  int cg = (colg & 255) + nc;
  const short* bBase = Bh + (long)gb * ((long)Kd << 8) + (long)cg * 32 + kh;

  float4 avp[4];
  short8 bhp[2], blp[2];

  auto issueA = [&](int k0) {
    bool useA2 = (A2 != nullptr) && (k0 >= 256);
    const float* Asrc = useA2 ? A2 : A;
    int kcol = useA2 ? (k0 - 256) : k0;
    #pragma unroll
    for (int p = 0; p < 4; p++) {
      int gr = row0 + tr + p * 32;
      avp[p] = make_float4(0.f, 0.f, 0.f, 0.f);
      if (gr < M) avp[p] = *(const float4*)&Asrc[aBase + (long)gr * aw + kcol + tc];
    }
  };
  auto issueB = [&](int k0) {
    const short* bs = bBase + ((long)(k0 >> 5) << 13);
    bhp[0] = *(const short8*)bs;
    bhp[1] = *(const short8*)(bs + 8);
    blp[0] = *(const short8*)(bs + loD);
    blp[1] = *(const short8*)(bs + loD + 8);
  };

  issueA(0); issueB(0);
  for (int k0 = 0; k0 < Kd; k0 += 32) {
    #pragma unroll
    for (int p = 0; p < 4; p++) {
      float vv[4] = {avp[p].x, avp[p].y, avp[p].z, avp[p].w};
      s4 h4, l4;
      #pragma unroll
      for (int e = 0; e < 4; e++) {
        short h = f2bf(vv[e]); h4[e] = h; l4[e] = f2bf(vv[e] - bf2f(h));
      }
      *(s4*)&Ah[tr + p * 32][tc] = h4;
      *(s4*)&Al[tr + p * 32][tc] = l4;
    }
    *(short8*)&Bsh[nc][kh]     = bhp[0];
    *(short8*)&Bsh[nc][kh + 8] = bhp[1];
    *(short8*)&Bsl[nc][kh]     = blp[0];
    *(short8*)&Bsl[nc][kh + 8] = blp[1];
    if (k0 + 32 < Kd) { issueA(k0 + 32); issueB(k0 + 32); }
    __syncthreads();
    short8 ah[4], al[4], bh[4], bl[4];
    #pragma unroll
    for (int i = 0; i < 4; i++) {
      ah[i] = *(const short8*)&Ah[wm * 64 + i * 16 + fi][fq * 8];
      al[i] = *(const short8*)&Al[wm * 64 + i * 16 + fi][fq * 8];
    }
    #pragma unroll
    for (int j = 0; j < 4; j++) {
      bh[j] = *(const short8*)&Bsh[wn * 64 + j * 16 + fi][fq * 8];
      bl[j] = *(const short8*)&Bsl[wn * 64 + j * 16 + fi][fq * 8];
    }
    #pragma unroll
    for (int i = 0; i < 4; i++)
      #pragma unroll
      for (int j = 0; j < 4; j++) {
        acc[i][j] = __builtin_amdgcn_mfma_f32_16x16x32_bf16(ah[i], bh[j], acc[i][j], 0, 0, 0);
        acc[i][j] = __builtin_amdgcn_mfma_f32_16x16x32_bf16(ah[i], bl[j], acc[i][j], 0, 0, 0);
        acc[i][j] = __builtin_amdgcn_mfma_f32_16x16x32_bf16(al[i], bh[j], acc[i][j], 0, 0, 0);
      }
    __syncthreads();
  }
  #pragma unroll
  for (int i = 0; i < 4; i++) {
    #pragma unroll
    for (int reg = 0; reg < 4; reg++) {
      int gr = row0 + wm * 64 + i * 16 + fq * 4 + reg;
      if (gr >= M || gr >= cntb) continue;
      #pragma unroll
      for (int j = 0; j < 4; j++) {
        int cc = colo + wn * 64 + j * 16 + fi;
        float v = acc[i][j][reg];
        if (mode == 1) { if (v < 0.f) v = 0.f; }
        else if (mode == 2) { v = (v > 0.f) ? (v + 1.f) : expf(v); }
        Cb[(long)gr * outW + cc] = v;
      }
    }
  }
}

// ---------------------------------------------------------------------------
// gemm256: N=256 exactly, 128x256 tile per block (full output row), plain or
// packed addressing. modes: 0 none, 2 elu+1, 3 LN->C, 4 X += LN (h2+residual).
// Panel-layout B + depth-1 prefetch (R1 version; depth-2 regressed).
// ---------------------------------------------------------------------------
__global__ __launch_bounds__(256) void gemm256_kernel(
    const float* __restrict__ A, int aw, const short* __restrict__ Bh, int loD,
    float* __restrict__ C, float* __restrict__ X,
    int M, int Kd, long sA, long sC, long sX,
    const int* __restrict__ cnt, int bmask, int bxor,
    const int* __restrict__ segOff, const int* __restrict__ segCnt, int gmin, int gmax,
    int mode)
{
  int z = blockIdx.z;
  long aBase, cBase, xBase; int cntb;
  if (segOff) {
    int g = z & 7;
    if (g < gmin || g > gmax) return;
    long rb = (long)g * ARENA + segOff[z];
    aBase = rb * aw; cBase = rb * 256; xBase = rb * 256;
    cntb = segCnt[z];
  } else {
    int ab = (z & bmask) ^ bxor;
    aBase = (long)ab * sA; cBase = (long)z * sC; xBase = (long)ab * sX;
    cntb = cnt ? min(cnt[ab], M) : M;
  }
  int row0 = blockIdx.y * 128;
  if (row0 >= cntb) return;

  int t = threadIdx.x;
  int lane = t & 63, wid = t >> 6, wm = wid >> 1, wn = wid & 1;
  int fi = lane & 15, fq = lane >> 4;

  __shared__ __align__(16) short Ah[128][36];
  __shared__ __align__(16) short Al[128][36];
  __shared__ __align__(16) short Bsh[256][36];
  __shared__ __align__(16) short Bsl[256][36];
  __shared__ float lnS[2][128];
  __shared__ float lnQ[2][128];
  __shared__ float muS[128];
  __shared__ float rsS[128];

  f32x4 acc[4][8];
  #pragma unroll
  for (int i = 0; i < 4; i++)
    #pragma unroll
    for (int j = 0; j < 8; j++)
      acc[i][j] = (f32x4){0.f, 0.f, 0.f, 0.f};

  int tr = t >> 3, tc = (t & 7) * 4;
  const short* bBase = Bh + (long)t * 32;

  float4 avp[4];
  short8 bhp[4], blp[4];

  auto issueA = [&](int k0) {
    #pragma unroll
    for (int p = 0; p < 4; p++) {
      int gr = row0 + tr + p * 32;
      avp[p] = make_float4(0.f, 0.f, 0.f, 0.f);
      if (gr < M) avp[p] = *(const float4*)&A[aBase + (long)gr * aw + k0 + tc];
    }
  };
  auto issueB = [&](int k0) {
    const short* bs = bBase + ((long)(k0 >> 5) << 13);
    #pragma unroll
    for (int q = 0; q < 4; q++) {
      bhp[q] = *(const short8*)(bs + q * 8);
      blp[q] = *(const short8*)(bs + loD + q * 8);
    }
  };

  issueA(0); issueB(0);
  for (int k0 = 0; k0 < Kd; k0 += 32) {
    #pragma unroll
    for (int p = 0; p < 4; p++) {
      float vv[4] = {avp[p].x, avp[p].y, avp[p].z, avp[p].w};
      s4 h4, l4;
      #pragma unroll
      for (int e = 0; e < 4; e++) {
        short h = f2bf(vv[e]); h4[e] = h; l4[e] = f2bf(vv[e] - bf2f(h));
      }
      *(s4*)&Ah[tr + p * 32][tc] = h4;
      *(s4*)&Al[tr + p * 32][tc] = l4;
    }
    #pragma unroll
    for (int q = 0; q < 4; q++) {
      *(short8*)&Bsh[t][q * 8] = bhp[q];
      *(short8*)&Bsl[t][q * 8] = blp[q];
    }
    if (k0 + 32 < Kd) { issueA(k0 + 32); issueB(k0 + 32); }
    __syncthreads();
    short8 ah[4], al[4];
    #pragma unroll
    for (int i = 0; i < 4; i++) {
      ah[i] = *(const short8*)&Ah[wm * 64 + i * 16 + fi][fq * 8];
      al[i] = *(const short8*)&Al[wm * 64 + i * 16 + fi][fq * 8];
    }
    #pragma unroll
    for (int jh = 0; jh < 2; jh++) {
      short8 bh[4], bl[4];
      #pragma unroll
      for (int j = 0; j < 4; j++) {
        bh[j] = *(const short8*)&Bsh[wn * 128 + (jh * 4 + j) * 16 + fi][fq * 8];
        bl[j] = *(const short8*)&Bsl[wn * 128 + (jh * 4 + j) * 16 + fi][fq * 8];
      }
      #pragma unroll
      for (int i = 0; i < 4; i++)
        #pragma unroll
        for (int j = 0; j < 4; j++) {
          acc[i][jh * 4 + j] = __builtin_amdgcn_mfma_f32_16x16x32_bf16(ah[i], bh[j], acc[i][jh * 4 + j], 0, 0, 0);
          acc[i][jh * 4 + j] = __builtin_amdgcn_mfma_f32_16x16x32_bf16(ah[i], bl[j], acc[i][jh * 4 + j], 0, 0, 0);
          acc[i][jh * 4 + j] = __builtin_amdgcn_mfma_f32_16x16x32_bf16(al[i], bh[j], acc[i][jh * 4 + j], 0, 0, 0);
        }
    }
    __syncthreads();
  }

  if (mode >= 3) {
    // per-row LN stats across all 256 cols
    #pragma unroll
    for (int i = 0; i < 4; i++)
      #pragma unroll
      for (int reg = 0; reg < 4; reg++) {
        float s = 0.f, q = 0.f;
        #pragma unroll
        for (int j = 0; j < 8; j++) { float v = acc[i][j][reg]; s += v; q += v * v; }
        #pragma unroll
        for (int m = 1; m < 16; m <<= 1) { s += __shfl_xor(s, m, 64); q += __shfl_xor(q, m, 64); }
        if (fi == 0) {
          int row = wm * 64 + i * 16 + fq * 4 + reg;
          lnS[wn][row] = s; lnQ[wn][row] = q;
        }
      }
    __syncthreads();
    if (t < 128) {
      float s = lnS[0][t] + lnS[1][t];
      float q = lnQ[0][t] + lnQ[1][t];
      float m = s * (1.f / 256.f);
      float var = q * (1.f / 256.f) - m * m;
      muS[t] = m; rsS[t] = rsqrtf(var + 1e-5f);
    }
    __syncthreads();
  }

  #pragma unroll
  for (int i = 0; i < 4; i++) {
    #pragma unroll
    for (int reg = 0; reg < 4; reg++) {
      int row = wm * 64 + i * 16 + fq * 4 + reg;
      int gr = row0 + row;
      if (gr >= M || gr >= cntb) continue;
      #pragma unroll
      for (int j = 0; j < 8; j++) {
        int col = wn * 128 + j * 16 + fi;
        float v = acc[i][j][reg];
        if (mode == 2) { v = (v > 0.f) ? (v + 1.f) : expf(v); C[cBase + (long)gr * 256 + col] = v; }
        else if (mode == 3) { C[cBase + (long)gr * 256 + col] = (v - muS[row]) * rsS[row]; }
        else if (mode == 4) { X[xBase + (long)gr * 256 + col] += (v - muS[row]) * rsS[row]; }
        else { C[cBase + (long)gr * 256 + col] = v; }
      }
    }
  }
}

// ---------------------------------------------------------------------------
// fp32-B MFMA GEMM (dmatrix only).
// ---------------------------------------------------------------------------
__global__ __launch_bounds__(256) void gemm_f32b_kernel(
    const float* __restrict__ A, const float* __restrict__ B, float* __restrict__ C,
    int M, int N, int Kd, long sA, long sB, long sC, float alpha)
{
  int b = blockIdx.z;
  const float* Ab = A + (long)b * sA;
  const float* Bb = B + (long)b * sB;
  float* Cb = C + (long)b * sC;
  int row0 = blockIdx.y * 128, col0 = blockIdx.x * 128;
  int t = threadIdx.x;
  int lane = t & 63, wid = t >> 6, wm = wid >> 1, wn = wid & 1;
  int fi = lane & 15, fq = lane >> 4;
  __shared__ __align__(16) short Ah[128][36];
  __shared__ __align__(16) short Al[128][36];
  __shared__ __align__(16) short Bsh[128][36];
  __shared__ __align__(16) short Bsl[128][36];
  f32x4 acc[4][4];
  #pragma unroll
  for (int i = 0; i < 4; i++)
    #pragma unroll
    for (int j = 0; j < 4; j++)
      acc[i][j] = (f32x4){0.f, 0.f, 0.f, 0.f};
  int tr = t >> 3, tc = (t & 7) * 4;
  int bn = (t & 31) * 4, bk = t >> 5;
  for (int k0 = 0; k0 < Kd; k0 += 32) {
    #pragma unroll
    for (int p = 0; p < 4; p++) {
      int r = tr + p * 32, gr = row0 + r;
      float4 v = make_float4(0.f, 0.f, 0.f, 0.f);
      if (gr < M) v = *(const float4*)&Ab[(long)gr * Kd + k0 + tc];
      float vv[4] = {v.x, v.y, v.z, v.w};
      #pragma unroll
      for (int e = 0; e < 4; e++) {
        short h = f2bf(vv[e]); Ah[r][tc + e] = h; Al[r][tc + e] = f2bf(vv[e] - bf2f(h));
      }
    }
    #pragma unroll
    for (int p = 0; p < 4; p++) {
      int kk = bk + p * 8;
      long gkN = (long)(k0 + kk) * N;
      #pragma unroll
      for (int e = 0; e < 4; e++) {
        int gc = col0 + bn + e;
        float v = (gc < N) ? Bb[gkN + gc] : 0.f;
        short h = f2bf(v); Bsh[bn + e][kk] = h; Bsl[bn + e][kk] = f2bf(v - bf2f(h));
      }
    }
    __syncthreads();
    short8 ah[4], al[4], bh[4], bl[4];
    #pragma unroll
    for (int i = 0; i < 4; i++) {
      ah[i] = *(const short8*)&Ah[wm * 64 + i * 16 + fi][fq * 8];
      al[i] = *(const short8*)&Al[wm * 64 + i * 16 + fi][fq * 8];
    }
    #pragma unroll
    for (int j = 0; j < 4; j++) {
      bh[j] = *(const short8*)&Bsh[wn * 64 + j * 16 + fi][fq * 8];
      bl[j] = *(const short8*)&Bsl[wn * 64 + j * 16 + fi][fq * 8];
    }
    #pragma unroll
    for (int i = 0; i < 4; i++)
      #pragma unroll
      for (int j = 0; j < 4; j++) {
        acc[i][j] = __builtin_amdgcn_mfma_f32_16x16x32_bf16(ah[i], bh[j], acc[i][j], 0, 0, 0);
        acc[i][j] = __builtin_amdgcn_mfma_f32_16x16x32_bf16(ah[i], bl[j], acc[i][j], 0, 0, 0);
        acc[i][j] = __builtin_amdgcn_mfma_f32_16x16x32_bf16(al[i], bh[j], acc[i][j], 0, 0, 0);
      }
    __syncthreads();
  }
  #pragma unroll
  for (int i = 0; i < 4; i++) {
    #pragma unroll
    for (int reg = 0; reg < 4; reg++) {
      int gr = row0 + wm * 64 + i * 16 + fq * 4 + reg;
      if (gr >= M) continue;
      #pragma unroll
      for (int j = 0; j < 4; j++) {
        int gc = col0 + wn * 64 + j * 16 + fi;
        if (gc < N) Cb[(long)gr * N + gc] = acc[i][j][reg] * alpha;
      }
    }
  }
}

// ---------------------------------------------------------------------------
__device__ __forceinline__ float2 blk_sum2_256(float a, float b)
{
  __shared__ float sa[4], sb[4];
  int lane = threadIdx.x & 63, w = threadIdx.x >> 6;
  #pragma unroll
  for (int off = 32; off > 0; off >>= 1) { a += __shfl_down(a, off, 64); b += __shfl_down(b, off, 64); }
  if (lane == 0) { sa[w] = a; sb[w] = b; }
  __syncthreads();
  float ra = sa[0] + sa[1] + sa[2] + sa[3];
  float rb = sb[0] + sb[1] + sb[2] + sb[3];
  __syncthreads();
  return make_float2(ra, rb);
}

__global__ void cvt2_kernel(float* dst, const float* s0, const float* s1, long n) {
  long i = (long)blockIdx.x * 256 + threadIdx.x;
  if (i < n) dst[i] = s0[i];
  else if (i < 2 * n) dst[i] = s1[i - n];
}

__global__ void bcast_seeds_kernel(float* seeds, const float* st) {
  long i = (long)blockIdx.x * 256 + threadIdx.x;
  if (i < 4L * 25600) seeds[i] = st[i % 25600];
}

// KV[s,h,d,e] = / += sum_r K*V*inv_s ; Ksum[s,h,d] = / += sum_r K.
// gridDim.z==1 -> direct store (no memset/atomics needed); else chunked atomic.
__global__ __launch_bounds__(1024) void kv_kernel(
    const float* __restrict__ Kb, const float* __restrict__ Vb,
    float* __restrict__ KV, float* __restrict__ Ksum,
    int s_len, float inv_s, int bmask, int bxor,
    const int* __restrict__ segOff, const int* __restrict__ segCnt,
    int axor, int gmin, int gmax, int chunk)
{
  int s = blockIdx.x, h = blockIdx.y;
  long srcBase; int slim;
  if (segOff) {
    int g = s & 7;
    if (g < gmin || g > gmax) return;
    int src = s ^ axor;
    srcBase = (long)(src & 7) * ARENA + segOff[src];
    slim = segCnt[src];
  } else {
    srcBase = (long)s * s_len;
    slim = s_len;
  }
  bool direct = (gridDim.z == 1);
  int s0b = blockIdx.z * chunk;
  int send = min(s0b + chunk, slim);
  __shared__ float Kt[32][33];
  __shared__ float Vt[32][33];
  int tx = threadIdx.x, ty = threadIdx.y;
  float acc = 0.f, ks = 0.f;
  for (int s0 = s0b; s0 < send; s0 += 32) {
    int sr = s0 + ty;
    float kvv = 0.f, vvv = 0.f;
    if (sr < send) {
      long base = (srcBase + sr) * 256 + h * 32 + tx;
      kvv = Kb[base]; vvv = Vb[base];
    }
    Kt[ty][tx] = kvv; Vt[ty][tx] = vvv;
    __syncthreads();
    #pragma unroll
    for (int j = 0; j < 32; j++) acc += Kt[j][ty] * Vt[j][tx];
    if (tx == 0) {
      #pragma unroll
      for (int j = 0; j < 32; j++) ks += Kt[j][ty];
    }
    __syncthreads();
  }
  if (direct) {
    KV[((s * 8 + h) * 32 + ty) * 32 + tx] = acc * inv_s;
    if (tx == 0) Ksum[s * 256 + h * 32 + ty] = ks;
  } else {
    if (s0b >= send) return;
    atomicAdd(&KV[((s * 8 + h) * 32 + ty) * 32 + tx], acc * inv_s);
    if (tx == 0) atomicAdd(&Ksum[s * 256 + h * 32 + ty], ks);
  }
}

// msg = (Q·KV) * Z * s_scale ; Z = 1/(Q·Ksum + 1e-6). plain or packed.
// 32 rows per block (amortizes the 32KB KV tile load 4x vs 8 rows).
__global__ __launch_bounds__(256) void zmsg_kernel(
    const float* __restrict__ Q, const float* __restrict__ KV,
    const float* __restrict__ Ksum, float* __restrict__ msg, int l, float s_scale,
    const int* __restrict__ cnt,
    const int* __restrict__ segOff, const int* __restrict__ segCnt, int gmin, int gmax)
{
  int s = blockIdx.x;
  long rowBase; int cb;
  if (segOff) {
    int g = s & 7;
    if (g < gmin || g > gmax) return;
    rowBase = (long)g * ARENA + segOff[s];
    cb = segCnt[s];
  } else {
    rowBase = (long)s * l;
    cb = cnt ? min(cnt[s], l) : l;
  }
  int r0 = blockIdx.y * 32;
  if (r0 >= cb) return;
  int t = threadIdx.x;
  __shared__ float KVs[8192];
  __shared__ float QL[256];
  __shared__ float Zl[8];
  for (int i = t; i < 8192; i += 256) KVs[i] = KV[s * 8192 + i];
  float Ks = Ksum[s * 256 + t];
  __syncthreads();
  int h = t >> 5, e = t & 31;
  for (int rr = 0; rr < 32; rr++) {
    int row = r0 + rr;
    if (row >= cb) break;
    long base = (rowBase + row) * 256;
    QL[t] = Q[base + t];
    __syncthreads();
    float p = QL[t] * Ks;
    #pragma unroll
    for (int off = 16; off > 0; off >>= 1) p += __shfl_down(p, off, 32);
    if (e == 0) Zl[h] = 1.f / (p + 1e-6f);
    __syncthreads();
    float acc = 0.f;
    const float* kvh = KVs + h * 1024;
    #pragma unroll
    for (int d = 0; d < 32; d++) acc += QL[h * 32 + d] * kvh[d * 32 + e];
    msg[base + t] = acc * Zl[h] * s_scale;
    __syncthreads();
  }
}

// ---------------- topic pipeline: all 5 stages in one kernel (4 blocks) -----
__global__ __launch_bounds__(256) void tm_all_kernel(const float* __restrict__ t0,
                                                     const float* __restrict__ t1,
                                                     int* __restrict__ tmidx) {
  int n = blockIdx.x, t = threadIdx.x;
  __shared__ float TM[100][100];
  __shared__ float cmax[100], csum[100], rmax[100], rsum[100];
  for (int i = t; i < 10000; i += 256) {
    int m = i / 100, l = i % 100;
    float acc = 0.f;
    for (int d = 0; d < 96; d++)
      acc += t0[(n * 96 + d) * 100 + m] * t1[(n * 96 + d) * 100 + l];
    TM[m][l] = floorf(acc * 0.0625f);
  }
  __syncthreads();
  if (t < 100) {
    int l = t;
    float mx = -1e30f;
    for (int m = 0; m < 100; m++) mx = fmaxf(mx, TM[m][l]);
    float s = 0.f;
    for (int m = 0; m < 100; m++) s += expf(TM[m][l] - mx);
    cmax[l] = mx; csum[l] = s;
    int m = t;
    float mx2 = -1e30f;
    for (int l2 = 0; l2 < 100; l2++) mx2 = fmaxf(mx2, TM[m][l2]);
    float s2 = 0.f;
    for (int l2 = 0; l2 < 100; l2++) s2 += expf(TM[m][l2] - mx2);
    rmax[m] = mx2; rsum[m] = s2;
  }
  __syncthreads();
  if (t < 100) {
    int m = t;
    float best = -1e30f; int bi = 0;
    for (int l = 0; l < 100; l++) {
      float x = TM[m][l];
      float v = (expf(x - cmax[l]) / csum[l]) * (expf(x - rmax[m]) / rsum[m]);
      if (v > best) { best = v; bi = l; }
    }
    tmidx[n * 100 + m] = bi;
  }
}

// seedsF: adaptive-pool(seeds,160) ++ topicp (computed inline from raw topics)
// -> LN -> write TRANSPOSED sT[n][d][k] directly (folds topicp + transpose).
__global__ void seedsF_kernel(const float* __restrict__ seeds,
                              const float* __restrict__ t0raw,
                              const float* __restrict__ t1raw,
                              const int* __restrict__ tmidx, float* __restrict__ sT) {
  int n = blockIdx.x, k = blockIdx.y, t = threadIdx.x;
  float v;
  if (t < 160) {
    int s = (t * 256) / 160;
    int e = ((t + 1) * 256 + 159) / 160;
    float a = 0.f;
    for (int i = s; i < e; i++) a += seeds[(n * 100 + k) * 256 + i];
    v = a / (float)(e - s);
  } else {
    int j = t - 160;
    int g = tmidx[300 + k];
    float a, b;
    if (j < 48) {
      a = t0raw[(n * 96 + 2 * j) * 100 + k];
      b = t0raw[(n * 96 + 2 * j + 1) * 100 + k];
    } else {
      int d0 = 2 * j - 96;
      a = t1raw[(n * 96 + d0) * 100 + g];
      b = t1raw[(n * 96 + d0 + 1) * 100 + g];
    }
    v = 0.5f * (a + b);
  }
  float2 r = blk_sum2_256(v, v * v);
  float m = r.x * (1.f / 256.f);
  float var = r.y * (1.f / 256.f) - m * m;
  sT[n * 25600 + t * 100 + k] = (v - m) * rsqrtf(var + 1e-5f);
}

// ---------------- dmatrix post ----------------
// softmax + row-argmax fused (argmax = first max index, matches jnp.argmax).
__global__ void softmax_rows_kernel(const float* dm, float* prob, int* amax) {
  long row = blockIdx.x; int t = threadIdx.x;
  __shared__ float red[128]; __shared__ int ri[128];
  float v = (t < 100) ? dm[row * 100 + t] : -1e30f;
  red[t] = v; ri[t] = t; __syncthreads();
  for (int off = 64; off > 0; off >>= 1) {
    if (t < off) {
      if (red[t + off] > red[t] || (red[t + off] == red[t] && ri[t + off] < ri[t])) {
        red[t] = red[t + off]; ri[t] = ri[t + off];
      }
    }
    __syncthreads();
  }
  float mx = red[0];
  if (t == 0) amax[row] = ri[0];
  __syncthreads();
  float e = (t < 100) ? expf(v - mx) : 0.f;
  red[t] = e; __syncthreads();
  for (int off = 64; off > 0; off >>= 1) { if (t < off) red[t] += red[t + off]; __syncthreads(); }
  float s = red[0];
  if (t < 100) prob[row * 100 + t] = e / s;
}

__global__ void colsum_kernel(const float* prob, float* cs0, float* cs1) {
  int k = blockIdx.x, n = blockIdx.y, half = blockIdx.z;
  int t = threadIdx.x;
  const float* p = prob + ((long)n * 8192 + half * 4096) * 100 + k;
  float s = 0.f;
  for (int m = t; m < 4096; m += 256) s += p[(long)m * 100];
  float2 r = blk_sum2_256(s, 0.f);
  if (t == 0) (half ? cs1 : cs0)[n * 100 + k] = r.x;
}

__global__ void topk_kernel(const float* cs0, const float* cs1, int* inds) {
  int n = blockIdx.x, t = threadIdx.x;
  __shared__ float rv[128]; __shared__ int ri[128]; __shared__ int sbest;
  float base = (t < 100) ? cs0[n * 100 + t] * cs1[n * 100 + t] : -1.f;
  for (int kk = 0; kk < 6; kk++) {
    rv[t] = base; ri[t] = t; __syncthreads();
    for (int off = 64; off > 0; off >>= 1) {
      if (t < off) {
        if (rv[t + off] > rv[t] || (rv[t + off] == rv[t] && ri[t + off] < ri[t])) { rv[t] = rv[t + off]; ri[t] = ri[t + off]; }
      }
      __syncthreads();
    }
    if (t == 0) { inds[n * 6 + kk] = ri[0]; sbest = ri[0]; }
    __syncthreads();
    if (t == sbest) base = -1.f;
    __syncthreads();
  }
}

// ---------------- packed sample machinery ----------------
__global__ __launch_bounds__(1024) void count_kernel(const int* amax, const int* inds, int* segCnt) {
  int seg = blockIdx.x;
  int kk = seg >> 3, g = seg & 7, n = g & 3, half = g >> 2;
  int target = inds[n * 6 + kk];
  const int* am = amax + n * 8192 + half * 4096;
  int t = threadIdx.x;
  int lc = 0;
  #pragma unroll
  for (int j = 0; j < 4; j++) lc += (am[t * 4 + j] == target) ? 1 : 0;
  __shared__ int red[16];
  #pragma unroll
  for (int off = 32; off > 0; off >>= 1) lc += __shfl_down(lc, off, 64);
  if ((t & 63) == 0) red[t >> 6] = lc;
  __syncthreads();
  if (t == 0) {
    int s = 0;
    for (int w = 0; w < 16; w++) s += red[w];
    segCnt[seg] = s;
  }
}

__global__ void offs_kernel(const int* segCnt, int* segOff, float* condf) {
  int t = threadIdx.x;
  if (t < 8) {
    int run = 0;
    for (int kk = 0; kk < 6; kk++) {
      segOff[kk * 8 + t] = run;
      run += (segCnt[kk * 8 + t] + 127) & ~127;
    }
  }
  if (t >= 8 && t < 14) {
    int kk = t - 8;
    int a = 0, b = 0;
    for (int g = 0; g < 4; g++) { a += segCnt[kk * 8 + g]; b += segCnt[kk * 8 + 4 + g]; }
    condf[kk] = (a > 0 && b > 0) ? 1.f : 0.f;
  }
}

// ord: stable compaction order + DIRECT gather of the packed rows (folds
// gather_kernel: each found token copies its 1KB feature row to the arena).
__global__ __launch_bounds__(1024) void ord_kernel(const int* amax, const int* inds,
                                                   const int* segOff, int* ordP,
                                                   float* __restrict__ nf,
                                                   const float* __restrict__ f01) {
  int seg = blockIdx.x;
  int kk = seg >> 3, g = seg & 7, n = g & 3, half = g >> 2;
  int target = inds[n * 6 + kk];
  const int* am = amax + n * 8192 + half * 4096;
  int t = threadIdx.x;
  __shared__ int ts[1024];
  int f[4]; int lc = 0;
  #pragma unroll
  for (int j = 0; j < 4; j++) { f[j] = (am[t * 4 + j] == target) ? 1 : 0; lc += f[j]; }
  ts[t] = lc; __syncthreads();
  for (int off = 1; off < 1024; off <<= 1) {
    int add = (t >= off) ? ts[t - off] : 0;
    __syncthreads();
    ts[t] += add;
    __syncthreads();
  }
  int run = (t == 0) ? 0 : ts[t - 1];
  long base = (long)g * ARENA + segOff[seg];
  int* o = ordP + base;
  #pragma unroll
  for (int j = 0; j < 4; j++) {
    if (f[j]) {
      int tok = t * 4 + j;
      o[run] = tok;
      const float4* s4p = (const float4*)&f01[((long)g * 4096 + tok) * 256];
      float4* d4p = (float4*)&nf[(base + run) * 256];
      for (int c = 0; c < 64; c++) d4p[c] = s4p[c];
      run++;
    }
  }
}

__global__ void scatter_kernel(float* up, const float* nf, const int* ordP,
                               const int* segOff, const int* segCnt, const float* condf) {
  int seg = blockIdx.y;
  int kk = seg >> 3, g = seg & 7;
  int cntb = segCnt[seg];
  int row0 = blockIdx.x * 128;
  if (row0 >= cntb) return;
  long base = (long)g * ARENA + segOff[seg];
  float cf = condf[kk];
  int t = threadIdx.x;
  int c4 = (t & 63) * 4, rr = t >> 6;
  for (int p = 0; p < 32; p++) {
    int r = row0 + p * 4 + rr;
    if (r >= cntb) break;
    int tok = ordP[base + r];
    float4 add = *(const float4*)&nf[(base + r) * 256 + c4];
    float4* dst = (float4*)&up[((long)g * 4096 + tok) * 256 + c4];
    float4 cur = *dst;
    cur.x += add.x * cf; cur.y += add.y * cf; cur.z += add.z * cf; cur.w += add.w * cf;
    *dst = cur;
  }
}

// up01 aliases out's feat region (index-identical); in-place RMW.
__global__ void final_mix_kernel(const float* f01, float* out_up, const int* amax,
                                 const int* inds) {
  int b = blockIdx.y, half = b >> 2, n = b & 3;
  int l = blockIdx.x, c = threadIdx.x;
  int a = amax[n * 8192 + half * 4096 + l];
  const int* in_ = inds + n * 6;
  bool member = (a == in_[0]) | (a == in_[1]) | (a == in_[2]) | (a == in_[3]) | (a == in_[4]) | (a == in_[5]);
  long idx = ((long)b * 4096 + l) * 256 + c;
  float up = out_up[idx];
  out_up[idx] = (member ? 0.f : 1.f) * f01[idx] + up;
}

__global__ void tmi_kernel(const float* dmat, float* out) {
  int n = blockIdx.y, half = blockIdx.z;
  long i = (long)blockIdx.x * 256 + threadIdx.x;
  const float* dm = dmat + (long)n * 819200 + (long)half * 409600;
  int a = (int)(i / 100), b = (int)(i % 100);
  int y = a >> 6, x = a & 63;
  float sum = 0.f;
  for (int dy = -1; dy <= 1; dy++) {
    int yy = y + dy; if (yy < 0 || yy >= 64) continue;
    for (int dx = -1; dx <= 1; dx++) {
      int xc = x + dx; if (xc < 0 || xc >= 64) continue;
      sum += dm[b * 4096 + yy * 64 + xc];
    }
  }
  out[8388608L + (long)half * 1638400 + (long)n * 409600 + i] = dm[i] * (sum * (1.f / 9.f));
}

// ---------------------------------------------------------------------------
extern "C" void kernel_launch(void* const* d_in, const int* in_sizes, int n_in,
                              void* d_out, int out_size, void* d_ws, size_t ws_size,
                              hipStream_t stream)
{
  (void)in_sizes; (void)n_in; (void)out_size; (void)ws_size;
  const float* feat0_in = (const float*)d_in[0];
  const float* feat1_in = (const float*)d_in[1];
  const float* topic0 = (const float*)d_in[2];
  const float* topic1 = (const float*)d_in[3];
  const float* seed_tokens = (const float*)d_in[4];
  const float* Wq = (const float*)d_in[5];
  const float* Wk = (const float*)d_in[6];
  const float* Wv = (const float*)d_in[7];
  const float* Wm = (const float*)d_in[8];
  const float* W1 = (const float*)d_in[9];
  const float* W2 = (const float*)d_in[10];
  float* out = (float*)d_out;

  float* base = (float*)d_ws;
  long off = 0;
  auto alloc = [&](long n) -> float* { float* p = base + off; off += (n + 255) & ~255L; return p; };
  float* f01   = alloc(8388608);          // [8][4096][256]
  float* qb    = alloc(8L * ARENA * 256); // Q / LN(msg2)
  float* kb    = alloc(8L * ARENA * 256); // K / msg / h1 low   (kb,vb contiguous)
  float* vb    = alloc(8L * ARENA * 256); // V / h1 high
  float* nf    = alloc(8L * ARENA * 256); // packed sample tokens
  float* seeds = alloc(102400);
  float* kvks  = alloc(48 * 8192 + 48 * 256);
  float* dmat  = alloc(3276800);
  short* wbuf  = (short*)alloc(5242880);
  float* sT    = alloc(102400);
  float* cs0   = alloc(400);
  float* cs1   = alloc(400);
  float* condf = alloc(256);
  int* tmidx  = (int*)alloc(400);
  int* amax   = (int*)alloc(32768);
  int* inds   = (int*)alloc(256);
  int* segCnt = (int*)alloc(256);
  int* segOffA= (int*)alloc(256);
  int* ordP   = (int*)alloc(8L * ARENA);
  float* up01 = out;                      // aliases out's feat region

  auto WOFF = [](int l) -> long { return (long)l * 1310720; };

  auto gmain = [&](const float* A, const float* A2, int aw, long wOff, int loD,
                   float* c0, float* c1, float* c2, int M, int Kd, int Ntot, int outW,
                   long sA_, long sC_, int bm, int bx,
                   const int* sOff, int gmin, int gmax, int gminB, int gmaxB,
                   int m0, int m1, int m2_, int nb) {
    dim3 g(Ntot / 128, (M + 127) / 128, nb), blk(256);
    gemm_main_kernel<<<g, blk, 0, stream>>>(A, A2, aw, wbuf + wOff, loD, c0, c1, c2,
        M, Kd, outW, sA_, sC_, nullptr, bm, bx, sOff, sOff ? segCnt : nullptr,
        gmin, gmax, gminB, gmaxB, m0, m1, m2_);
  };
  auto g256 = [&](const float* A, int aw, long wOff, int loD, float* C, float* X,
                  int M, int Kd, long sA_, long sC_, long sX_, int bm, int bx,
                  const int* sOff, int gmin, int gmax, int mode, int nb) {
    dim3 g(1, (M + 127) / 128, nb), blk(256);
    gemm256_kernel<<<g, blk, 0, stream>>>(A, aw, wbuf + wOff, loD, C, X,
        M, Kd, sA_, sC_, sX_, nullptr, bm, bx, sOff, sOff ? segCnt : nullptr, gmin, gmax, mode);
  };
  // encTail: Q in qb, K in kb, V in vb already. kv -> zmsg(msg->kb) ->
  // msg2+LN -> qb -> h1 -> kbvb[row][512] -> h2+addLN -> x
  // nch==1: kv direct-store (no memset); nch>1: chunked atomic (needs memset).
  auto encTail = [&](float* x, int l, int s_len, float s_scale, int layer, int nb,
                     long sAx, const int* sOff, int gmin, int gmax, int axor,
                     int bmKV, int bxKV, int nch) {
    if (nch > 1)
      hipMemsetAsync(kvks, 0, (48 * 8192 + 48 * 256) * sizeof(float), stream);
    int chunk = (s_len + nch - 1) / nch;
    kv_kernel<<<dim3(nb, 8, nch), dim3(32, 32), 0, stream>>>(
        kb, vb, kvks, kvks + 48 * 8192, s_len, 1.f / s_scale, bmKV, bxKV,
        sOff, sOff ? segCnt : nullptr, axor, gmin, gmax, chunk);
    zmsg_kernel<<<dim3(nb, (l + 31) / 32), 256, 0, stream>>>(
        qb, kvks, kvks + 48 * 8192, kb, l, s_scale, nullptr,
        sOff, sOff ? segCnt : nullptr, gmin, gmax);
    g256(kb, 256, WOFF(layer) + 393216, 65536, qb, nullptr,
         l, 256, sAx, sAx, 0, 7, 0, sOff, gmin, gmax, 3, nb);
    gmain(x, qb, 256, WOFF(layer) + 524288, 262144, kb, nullptr, nullptr,
          l, 512, 512, 512, sAx, sAx * 2, 7, 0, sOff, gmin, gmax, gmin, gmax, 1, 0, 0, nb);
    g256(kb, 512, WOFF(layer) + 1048576, 131072, nullptr, x,
         l, 512, sAx * 2, 0, sAx, 7, 0, sOff, gmin, gmax, 4, nb);
  };

  // ---- init ----
  cvt2_kernel<<<32768, 256, 0, stream>>>(f01, feat0_in, feat1_in, 4194304);
  bcast_seeds_kernel<<<400, 256, 0, stream>>>(seeds, seed_tokens);
  prep_w_kernel<<<20480, 256, 0, stream>>>(Wq, Wk, Wv, Wm, W1, W2, wbuf);

  // ---- topic pipeline (one kernel) ----
  tm_all_kernel<<<4, 256, 0, stream>>>(topic0, topic1, tmidx);

  // ---- main encoder layers ----
  auto encSeedLayer = [&](int layer) {
    g256(seeds, 256, WOFF(layer), 196608, qb, nullptr,
         100, 256, 25600, 25600, 0, 7, 0, nullptr, 0, 7, 2, 4);
    gmain(feat0_in, nullptr, 256, WOFF(layer) + 65536, 196608, kb, vb, nullptr,
          4096, 256, 512, 256, 1048576, 2097152, 7, 0, nullptr, 0, 7, 0, 7, 2, 0, 0, 4);
    gmain(feat1_in, nullptr, 256, WOFF(layer) + 65536, 196608, kb + 1048576, vb + 1048576, nullptr,
          4096, 256, 512, 256, 1048576, 2097152, 7, 0, nullptr, 0, 7, 0, 7, 2, 0, 0, 4);
    encTail(seeds, 100, 8192, 8192.f, layer, 4, 25600, nullptr, 0, 7, 0, 7, 0, 8);
  };
  auto encFeatLayer = [&](int layer) {
    g256(f01, 256, WOFF(layer), 196608, qb, nullptr,
         4096, 256, 1048576, 1048576, 0, 7, 0, nullptr, 0, 7, 2, 8);
    gmain(seeds, nullptr, 256, WOFF(layer) + 65536, 196608, kb, vb, nullptr,
          100, 256, 512, 256, 25600, 25600, 3, 0, nullptr, 0, 7, 0, 7, 2, 0, 0, 8);
    encTail(f01, 4096, 100, 100.f, layer, 8, 1048576, nullptr, 0, 7, 0, 7, 0, 1);
  };

  encSeedLayer(0);
  encFeatLayer(1);
  encSeedLayer(2);
  encFeatLayer(3);

  // ---- seeds final + dmatrix ----
  seedsF_kernel<<<dim3(4, 100), 256, 0, stream>>>(seeds, topic0, topic1, tmidx, sT);
  {
    dim3 g(1, 32, 4), blk(256);
    gemm_f32b_kernel<<<g, blk, 0, stream>>>(feat0_in, sT, dmat, 4096, 100, 256, 1048576, 25600, 819200, 0.0625f);
    gemm_f32b_kernel<<<g, blk, 0, stream>>>(feat1_in, sT, dmat + 409600, 4096, 100, 256, 1048576, 25600, 819200, 0.0625f);
  }
  float* prob = kb;
  softmax_rows_kernel<<<32768, 128, 0, stream>>>(dmat, prob, amax);
  colsum_kernel<<<dim3(100, 4, 2), 256, 0, stream>>>(prob, cs0, cs1);
  topk_kernel<<<4, 128, 0, stream>>>(cs0, cs1, inds);

  hipMemsetAsync(up01, 0, 8388608 * sizeof(float), stream);

  // ---- sample phase: all 6 samples x 8 halves packed into 48 segments ----
  count_kernel<<<48, 1024, 0, stream>>>(amax, inds, segCnt);
  offs_kernel<<<1, 64, 0, stream>>>(segCnt, segOffA, condf);
  ord_kernel<<<48, 1024, 0, stream>>>(amax, inds, segOffA, ordP, nf, f01);

  for (int idt = 0; idt < 2; idt++) {
    int wA = 4 + idt * 2, wB = wA + 1;
    // wA: self-attention, all 48 segments (Q,K,V in one 768-wide launch)
    gmain(nf, nullptr, 256, WOFF(wA), 196608, qb, kb, vb,
          4096, 256, 768, 256, 0, 0, 0, 0, segOffA, 0, 7, 0, 7, 2, 2, 0, 48);
    encTail(nf, 4096, 4096, 4096.f, wA, 48, 0, segOffA, 0, 7, 0, 0, 0, 1);
    // wB step 1: x = g0..3 (Q), source = g4..7 (K,V) — single fused launch
    gmain(nf, nullptr, 256, WOFF(wB), 196608, qb, kb, vb,
          4096, 256, 768, 256, 0, 0, 0, 0, segOffA, 0, 3, 4, 7, 2, 2, 0, 48);
    encTail(nf, 4096, 4096, 4096.f, wB, 48, 0, segOffA, 0, 3, 4, 0, 0, 1);
    // wB step 2: x = g4..7 (Q), source = UPDATED g0..3 (K,V)
    gmain(nf, nullptr, 256, WOFF(wB), 196608, qb, kb, vb,
          4096, 256, 768, 256, 0, 0, 0, 0, segOffA, 4, 7, 0, 3, 2, 2, 0, 48);
    encTail(nf, 4096, 4096, 4096.f, wB, 48, 0, segOffA, 4, 7, 4, 0, 0, 1);
  }
  scatter_kernel<<<dim3(32, 48), 256, 0, stream>>>(up01, nf, ordP, segOffA, segCnt, condf);

  // ---- outputs ----
  final_mix_kernel<<<dim3(4096, 8), 256, 0, stream>>>(f01, up01, amax, inds);
  tmi_kernel<<<dim3(1600, 4, 2), 256, 0, stream>>>(dmat, out);
}

// Round 4
// 2609.546 us; speedup vs baseline: 2.0477x; 2.0477x over previous
//
#include <hip/hip_runtime.h>
#include <math.h>

// N=4, L=S=4096, C=256, K=100, NHEAD=8, D=32. FP32 I/O.
// Big GEMMs: bf16x3 split MFMA (hi*hi + hi*lo + lo*hi, fp32 acc) ~ fp32 fidelity.
// Sample loop batched into 48 packed segments (6 samples x 8 batch-halves),
// 128-aligned inside an [8][4864]-row arena.
// R1: panel-major weights (256-col groups of [k/32][n&255][32]); depth-1 prefetch.
// R2: wB Q fused into K/V gmain; zmsg 32 rows/block; softmax+argmax fused.
// R3: kv direct-store; tm_all; seedsF folds topicp+transpose; ord folds gather.
// R4: packed GEMMs driven by DEVICE-BUILT DENSE BLOCK TABLES (seg,row0).
//     Old packed grids (X, 32, 48) put all active blocks at launch idx 32z/192z
//     == 0 mod 8 -> all on XCD 0 (block->XCD = idx%8), serializing ~48 blocks
//     onto one XCD's CUs/L2 (412us vs ~13us critical-path model). Dense tables
//     spread active blocks over all 8 XCDs. g256 packed re-tiled 128->32 rows
//     (gemm256_seg: ~190 active blocks, ~42KB LDS -> 3 blocks/CU).

typedef __attribute__((ext_vector_type(8))) short short8;
typedef __attribute__((ext_vector_type(4))) short s4;
typedef __attribute__((ext_vector_type(4))) float f32x4;

#define ARENA 4864  // rows per g in packed arena (4096 + 6*128 alignment pad)

__device__ __forceinline__ short f2bf(float f) {
  unsigned u = __float_as_uint(f);
  return (short)((u + 0x7FFFu + ((u >> 16) & 1u)) >> 16);
}
__device__ __forceinline__ float bf2f(short s) {
  return __uint_as_float(((unsigned)(unsigned short)s) << 16);
}

// ---------------------------------------------------------------------------
// Weight prep: per layer L, panel-major bf16 hi/lo planes.
// Layout per matrix: 256-col groups; group g holds cols [g*256,(g+1)*256);
// within group: panel p = k/32 (8192 shorts each); within panel: (n&255)*32+(k&31).
// Per-layer stride 1310720 shorts:
//   +0       QKV [768][256] hi (Wq group0, Wk group1, Wv group2), lo +196608
//   +393216  Wm  [256][256] hi, lo +65536
//   +524288  W1  [512][512] hi (2 groups of 131072), lo +262144
//   +1048576 W2  [256][512] hi, lo +131072
// ---------------------------------------------------------------------------
__global__ void prep_w_kernel(const float* __restrict__ Wq, const float* __restrict__ Wk,
                              const float* __restrict__ Wv, const float* __restrict__ Wm,
                              const float* __restrict__ W1, const float* __restrict__ W2,
                              short* __restrict__ wb) {
  long i = (long)blockIdx.x * 256 + threadIdx.x;
  if (i >= 8L * 655360) return;
  int L = (int)(i / 655360);
  int r = (int)(i % 655360);
  long base = (long)L * 1310720;
  float v; long dhi; int loD;
  if (r < 196608) {
    int n = r >> 8, k = r & 255;
    const float* s = (n < 256) ? (Wq + (long)L * 65536)
                   : (n < 512) ? (Wk + (long)L * 65536) : (Wv + (long)L * 65536);
    v = s[k * 256 + (n & 255)];
    dhi = base + ((long)(n >> 8) << 16) + ((long)(k >> 5) << 13) + ((n & 255) << 5) + (k & 31);
    loD = 196608;
  } else if (r < 262144) {
    int j = r - 196608; int n = j >> 8, k = j & 255;
    v = Wm[(long)L * 65536 + k * 256 + n];
    dhi = base + 393216 + ((long)(k >> 5) << 13) + (n << 5) + (k & 31);
    loD = 65536;
  } else if (r < 524288) {
    int j = r - 262144; int n = j >> 9, k = j & 511;
    v = W1[(long)L * 262144 + (long)k * 512 + n];
    dhi = base + 524288 + ((long)(n >> 8) << 17) + ((long)(k >> 5) << 13) + ((n & 255) << 5) + (k & 31);
    loD = 262144;
  } else {
    int j = r - 524288; int n = j >> 9, k = j & 511;
    v = W2[(long)L * 131072 + (long)k * 256 + n];
    dhi = base + 1048576 + ((long)(k >> 5) << 13) + (n << 5) + (k & 31);
    loD = 131072;
  }
  short h = f2bf(v);
  wb[dhi] = h;
  wb[dhi + loD] = f2bf(v - bf2f(h));
}

// ---------------------------------------------------------------------------
// gemm_main: 128x128 tiles. Plain-batch (z-grid) OR packed via dense block
// table (grid.y indexes (seg,row0); sel==0 -> tabQ, sel>=1 -> tabKV).
// modes: 0 none, 1 relu, 2 elu(x)+1.
// ---------------------------------------------------------------------------
__global__ __launch_bounds__(256) void gemm_main_kernel(
    const float* __restrict__ A, const float* __restrict__ A2, int aw,
    const short* __restrict__ Bh, int loD,
    float* __restrict__ C0, float* __restrict__ C1, float* __restrict__ C2,
    int M, int Kd, int outW, long sA, long sC,
    int bmask, int bxor,
    const int* __restrict__ segOff, const int* __restrict__ segCnt,
    const int2* __restrict__ tabQ, const int2* __restrict__ tabKV,
    const int* __restrict__ tabCnt, int tQ, int tKV,
    int mode0, int mode1, int mode2)
{
  int colg = blockIdx.x * 128;
  int sel = colg / outW;
  long aBase, cBase; int cntb, row0;
  if (tabQ) {
    const int2* tab = (sel == 0) ? tabQ : tabKV;
    int n = tabCnt[(sel == 0) ? tQ : tKV];
    int y = blockIdx.y;
    if (y >= n) return;
    int2 e = tab[y];
    long rb = (long)(e.x & 7) * ARENA + segOff[e.x];
    aBase = rb * aw; cBase = rb * (long)outW;
    cntb = segCnt[e.x];
    row0 = e.y;
  } else {
    int z = blockIdx.z;
    int ab = (z & bmask) ^ bxor;
    aBase = (long)ab * sA; cBase = (long)z * sC;
    cntb = M;
    row0 = blockIdx.y * 128;
    if (row0 >= cntb) return;
  }
  float* Cb = (sel == 0 ? C0 : (sel == 1 ? C1 : C2)) + cBase;
  int mode = (sel == 0 ? mode0 : (sel == 1 ? mode1 : mode2));
  int colo = colg % outW;

  int t = threadIdx.x;
  int lane = t & 63, wid = t >> 6, wm = wid >> 1, wn = wid & 1;
  int fi = lane & 15, fq = lane >> 4;

  __shared__ __align__(16) short Ah[128][36];
  __shared__ __align__(16) short Al[128][36];
  __shared__ __align__(16) short Bsh[128][36];
  __shared__ __align__(16) short Bsl[128][36];

  f32x4 acc[4][4];
  #pragma unroll
  for (int i = 0; i < 4; i++)
    #pragma unroll
    for (int j = 0; j < 4; j++)
      acc[i][j] = (f32x4){0.f, 0.f, 0.f, 0.f};

  int tr = t >> 3, tc = (t & 7) * 4;
  int nc = t >> 1, kh = (t & 1) * 16;
  int gb = colg >> 8;
  int cg = (colg & 255) + nc;
  const short* bBase = Bh + (long)gb * ((long)Kd << 8) + (long)cg * 32 + kh;

  float4 avp[4];
  short8 bhp[2], blp[2];

  auto issueA = [&](int k0) {
    bool useA2 = (A2 != nullptr) && (k0 >= 256);
    const float* Asrc = useA2 ? A2 : A;
    int kcol = useA2 ? (k0 - 256) : k0;
    #pragma unroll
    for (int p = 0; p < 4; p++) {
      int gr = row0 + tr + p * 32;
      avp[p] = make_float4(0.f, 0.f, 0.f, 0.f);
      if (gr < M) avp[p] = *(const float4*)&Asrc[aBase + (long)gr * aw + kcol + tc];
    }
  };
  auto issueB = [&](int k0) {
    const short* bs = bBase + ((long)(k0 >> 5) << 13);
    bhp[0] = *(const short8*)bs;
    bhp[1] = *(const short8*)(bs + 8);
    blp[0] = *(const short8*)(bs + loD);
    blp[1] = *(const short8*)(bs + loD + 8);
  };

  issueA(0); issueB(0);
  for (int k0 = 0; k0 < Kd; k0 += 32) {
    #pragma unroll
    for (int p = 0; p < 4; p++) {
      float vv[4] = {avp[p].x, avp[p].y, avp[p].z, avp[p].w};
      s4 h4, l4;
      #pragma unroll
      for (int e = 0; e < 4; e++) {
        short h = f2bf(vv[e]); h4[e] = h; l4[e] = f2bf(vv[e] - bf2f(h));
      }
      *(s4*)&Ah[tr + p * 32][tc] = h4;
      *(s4*)&Al[tr + p * 32][tc] = l4;
    }
    *(short8*)&Bsh[nc][kh]     = bhp[0];
    *(short8*)&Bsh[nc][kh + 8] = bhp[1];
    *(short8*)&Bsl[nc][kh]     = blp[0];
    *(short8*)&Bsl[nc][kh + 8] = blp[1];
    if (k0 + 32 < Kd) { issueA(k0 + 32); issueB(k0 + 32); }
    __syncthreads();
    short8 ah[4], al[4], bh[4], bl[4];
    #pragma unroll
    for (int i = 0; i < 4; i++) {
      ah[i] = *(const short8*)&Ah[wm * 64 + i * 16 + fi][fq * 8];
      al[i] = *(const short8*)&Al[wm * 64 + i * 16 + fi][fq * 8];
    }
    #pragma unroll
    for (int j = 0; j < 4; j++) {
      bh[j] = *(const short8*)&Bsh[wn * 64 + j * 16 + fi][fq * 8];
      bl[j] = *(const short8*)&Bsl[wn * 64 + j * 16 + fi][fq * 8];
    }
    #pragma unroll
    for (int i = 0; i < 4; i++)
      #pragma unroll
      for (int j = 0; j < 4; j++) {
        acc[i][j] = __builtin_amdgcn_mfma_f32_16x16x32_bf16(ah[i], bh[j], acc[i][j], 0, 0, 0);
        acc[i][j] = __builtin_amdgcn_mfma_f32_16x16x32_bf16(ah[i], bl[j], acc[i][j], 0, 0, 0);
        acc[i][j] = __builtin_amdgcn_mfma_f32_16x16x32_bf16(al[i], bh[j], acc[i][j], 0, 0, 0);
      }
    __syncthreads();
  }
  #pragma unroll
  for (int i = 0; i < 4; i++) {
    #pragma unroll
    for (int reg = 0; reg < 4; reg++) {
      int gr = row0 + wm * 64 + i * 16 + fq * 4 + reg;
      if (gr >= M || gr >= cntb) continue;
      #pragma unroll
      for (int j = 0; j < 4; j++) {
        int cc = colo + wn * 64 + j * 16 + fi;
        float v = acc[i][j][reg];
        if (mode == 1) { if (v < 0.f) v = 0.f; }
        else if (mode == 2) { v = (v > 0.f) ? (v + 1.f) : expf(v); }
        Cb[(long)gr * outW + cc] = v;
      }
    }
  }
}

// ---------------------------------------------------------------------------
// gemm256: N=256, 128x256 tile, PLAIN batch only. modes: 0 none, 2 elu+1,
// 3 LN->C, 4 X += LN.
// ---------------------------------------------------------------------------
__global__ __launch_bounds__(256) void gemm256_kernel(
    const float* __restrict__ A, int aw, const short* __restrict__ Bh, int loD,
    float* __restrict__ C, float* __restrict__ X,
    int M, int Kd, long sA, long sC, long sX,
    int bmask, int bxor, int mode)
{
  int z = blockIdx.z;
  int ab = (z & bmask) ^ bxor;
  long aBase = (long)ab * sA, cBase = (long)z * sC, xBase = (long)ab * sX;
  int row0 = blockIdx.y * 128;
  if (row0 >= M) return;

  int t = threadIdx.x;
  int lane = t & 63, wid = t >> 6, wm = wid >> 1, wn = wid & 1;
  int fi = lane & 15, fq = lane >> 4;

  __shared__ __align__(16) short Ah[128][36];
  __shared__ __align__(16) short Al[128][36];
  __shared__ __align__(16) short Bsh[256][36];
  __shared__ __align__(16) short Bsl[256][36];
  __shared__ float lnS[2][128];
  __shared__ float lnQ[2][128];
  __shared__ float muS[128];
  __shared__ float rsS[128];

  f32x4 acc[4][8];
  #pragma unroll
  for (int i = 0; i < 4; i++)
    #pragma unroll
    for (int j = 0; j < 8; j++)
      acc[i][j] = (f32x4){0.f, 0.f, 0.f, 0.f};

  int tr = t >> 3, tc = (t & 7) * 4;
  const short* bBase = Bh + (long)t * 32;

  float4 avp[4];
  short8 bhp[4], blp[4];

  auto issueA = [&](int k0) {
    #pragma unroll
    for (int p = 0; p < 4; p++) {
      int gr = row0 + tr + p * 32;
      avp[p] = make_float4(0.f, 0.f, 0.f, 0.f);
      if (gr < M) avp[p] = *(const float4*)&A[aBase + (long)gr * aw + k0 + tc];
    }
  };
  auto issueB = [&](int k0) {
    const short* bs = bBase + ((long)(k0 >> 5) << 13);
    #pragma unroll
    for (int q = 0; q < 4; q++) {
      bhp[q] = *(const short8*)(bs + q * 8);
      blp[q] = *(const short8*)(bs + loD + q * 8);
    }
  };

  issueA(0); issueB(0);
  for (int k0 = 0; k0 < Kd; k0 += 32) {
    #pragma unroll
    for (int p = 0; p < 4; p++) {
      float vv[4] = {avp[p].x, avp[p].y, avp[p].z, avp[p].w};
      s4 h4, l4;
      #pragma unroll
      for (int e = 0; e < 4; e++) {
        short h = f2bf(vv[e]); h4[e] = h; l4[e] = f2bf(vv[e] - bf2f(h));
      }
      *(s4*)&Ah[tr + p * 32][tc] = h4;
      *(s4*)&Al[tr + p * 32][tc] = l4;
    }
    #pragma unroll
    for (int q = 0; q < 4; q++) {
      *(short8*)&Bsh[t][q * 8] = bhp[q];
      *(short8*)&Bsl[t][q * 8] = blp[q];
    }
    if (k0 + 32 < Kd) { issueA(k0 + 32); issueB(k0 + 32); }
    __syncthreads();
    short8 ah[4], al[4];
    #pragma unroll
    for (int i = 0; i < 4; i++) {
      ah[i] = *(const short8*)&Ah[wm * 64 + i * 16 + fi][fq * 8];
      al[i] = *(const short8*)&Al[wm * 64 + i * 16 + fi][fq * 8];
    }
    #pragma unroll
    for (int jh = 0; jh < 2; jh++) {
      short8 bh[4], bl[4];
      #pragma unroll
      for (int j = 0; j < 4; j++) {
        bh[j] = *(const short8*)&Bsh[wn * 128 + (jh * 4 + j) * 16 + fi][fq * 8];
        bl[j] = *(const short8*)&Bsl[wn * 128 + (jh * 4 + j) * 16 + fi][fq * 8];
      }
      #pragma unroll
      for (int i = 0; i < 4; i++)
        #pragma unroll
        for (int j = 0; j < 4; j++) {
          acc[i][jh * 4 + j] = __builtin_amdgcn_mfma_f32_16x16x32_bf16(ah[i], bh[j], acc[i][jh * 4 + j], 0, 0, 0);
          acc[i][jh * 4 + j] = __builtin_amdgcn_mfma_f32_16x16x32_bf16(ah[i], bl[j], acc[i][jh * 4 + j], 0, 0, 0);
          acc[i][jh * 4 + j] = __builtin_amdgcn_mfma_f32_16x16x32_bf16(al[i], bh[j], acc[i][jh * 4 + j], 0, 0, 0);
        }
    }
    __syncthreads();
  }

  if (mode >= 3) {
    #pragma unroll
    for (int i = 0; i < 4; i++)
      #pragma unroll
      for (int reg = 0; reg < 4; reg++) {
        float s = 0.f, q = 0.f;
        #pragma unroll
        for (int j = 0; j < 8; j++) { float v = acc[i][j][reg]; s += v; q += v * v; }
        #pragma unroll
        for (int m = 1; m < 16; m <<= 1) { s += __shfl_xor(s, m, 64); q += __shfl_xor(q, m, 64); }
        if (fi == 0) {
          int row = wm * 64 + i * 16 + fq * 4 + reg;
          lnS[wn][row] = s; lnQ[wn][row] = q;
        }
      }
    __syncthreads();
    if (t < 128) {
      float s = lnS[0][t] + lnS[1][t];
      float q = lnQ[0][t] + lnQ[1][t];
      float m = s * (1.f / 256.f);
      float var = q * (1.f / 256.f) - m * m;
      muS[t] = m; rsS[t] = rsqrtf(var + 1e-5f);
    }
    __syncthreads();
  }

  #pragma unroll
  for (int i = 0; i < 4; i++) {
    #pragma unroll
    for (int reg = 0; reg < 4; reg++) {
      int row = wm * 64 + i * 16 + fq * 4 + reg;
      int gr = row0 + row;
      if (gr >= M) continue;
      #pragma unroll
      for (int j = 0; j < 8; j++) {
        int col = wn * 128 + j * 16 + fi;
        float v = acc[i][j][reg];
        if (mode == 2) { v = (v > 0.f) ? (v + 1.f) : expf(v); C[cBase + (long)gr * 256 + col] = v; }
        else if (mode == 3) { C[cBase + (long)gr * 256 + col] = (v - muS[row]) * rsS[row]; }
        else if (mode == 4) { X[xBase + (long)gr * 256 + col] += (v - muS[row]) * rsS[row]; }
        else { C[cBase + (long)gr * 256 + col] = v; }
      }
    }
  }
}

// ---------------------------------------------------------------------------
// gemm256_seg: N=256, 32x256 tile, packed-only, dense block table.
// 4 waves: wave w covers cols [64w,64w+64), rows 0..31. ~42KB LDS -> 3 blk/CU.
// Kd == aw (256 or 512). modes: 3 LN->C, 4 X += LN.
// ---------------------------------------------------------------------------
__global__ __launch_bounds__(256) void gemm256_seg_kernel(
    const float* __restrict__ A, int aw, const short* __restrict__ Bh, int loD,
    float* __restrict__ C, float* __restrict__ X,
    const int* __restrict__ segOff, const int* __restrict__ segCnt,
    const int2* __restrict__ tab, const int* __restrict__ nTab, int mode)
{
  int y = blockIdx.y;
  if (y >= nTab[0]) return;
  int2 e = tab[y];
  long rb = (long)(e.x & 7) * ARENA + segOff[e.x];
  int cntb = segCnt[e.x];
  int row0 = e.y;
  long aBase = rb * aw, cBase = rb * 256, xBase = rb * 256;

  int t = threadIdx.x;
  int lane = t & 63, w = t >> 6;
  int fi = lane & 15, fq = lane >> 4;

  __shared__ __align__(16) short Ah[32][36];
  __shared__ __align__(16) short Al[32][36];
  __shared__ __align__(16) short Bsh[256][36];
  __shared__ __align__(16) short Bsl[256][36];
  __shared__ float lnS[4][32];
  __shared__ float lnQ[4][32];
  __shared__ float muS[32];
  __shared__ float rsS[32];

  f32x4 acc[2][4];
  #pragma unroll
  for (int i = 0; i < 2; i++)
    #pragma unroll
    for (int j = 0; j < 4; j++)
      acc[i][j] = (f32x4){0.f, 0.f, 0.f, 0.f};

  int tr = t >> 3, tc = (t & 7) * 4;  // tr 0..31
  const short* bBase = Bh + (long)t * 32;

  float4 avp;
  short8 bhp[4], blp[4];

  // rows row0..row0+31 stay inside the segment's 128-aligned arena slot.
  auto issueA = [&](int k0) {
    avp = *(const float4*)&A[aBase + (long)(row0 + tr) * aw + k0 + tc];
  };
  auto issueB = [&](int k0) {
    const short* bs = bBase + ((long)(k0 >> 5) << 13);
    #pragma unroll
    for (int q = 0; q < 4; q++) {
      bhp[q] = *(const short8*)(bs + q * 8);
      blp[q] = *(const short8*)(bs + loD + q * 8);
    }
  };

  issueA(0); issueB(0);
  for (int k0 = 0; k0 < aw; k0 += 32) {
    {
      float vv[4] = {avp.x, avp.y, avp.z, avp.w};
      s4 h4, l4;
      #pragma unroll
      for (int e2 = 0; e2 < 4; e2++) {
        short h = f2bf(vv[e2]); h4[e2] = h; l4[e2] = f2bf(vv[e2] - bf2f(h));
      }
      *(s4*)&Ah[tr][tc] = h4;
      *(s4*)&Al[tr][tc] = l4;
    }
    #pragma unroll
    for (int q = 0; q < 4; q++) {
      *(short8*)&Bsh[t][q * 8] = bhp[q];
      *(short8*)&Bsl[t][q * 8] = blp[q];
    }
    if (k0 + 32 < aw) { issueA(k0 + 32); issueB(k0 + 32); }
    __syncthreads();
    short8 ah[2], al[2];
    #pragma unroll
    for (int i = 0; i < 2; i++) {
      ah[i] = *(const short8*)&Ah[i * 16 + fi][fq * 8];
      al[i] = *(const short8*)&Al[i * 16 + fi][fq * 8];
    }
    #pragma unroll
    for (int j = 0; j < 4; j++) {
      short8 bh = *(const short8*)&Bsh[w * 64 + j * 16 + fi][fq * 8];
      short8 bl = *(const short8*)&Bsl[w * 64 + j * 16 + fi][fq * 8];
      #pragma unroll
      for (int i = 0; i < 2; i++) {
        acc[i][j] = __builtin_amdgcn_mfma_f32_16x16x32_bf16(ah[i], bh, acc[i][j], 0, 0, 0);
        acc[i][j] = __builtin_amdgcn_mfma_f32_16x16x32_bf16(ah[i], bl, acc[i][j], 0, 0, 0);
        acc[i][j] = __builtin_amdgcn_mfma_f32_16x16x32_bf16(al[i], bh, acc[i][j], 0, 0, 0);
      }
    }
    __syncthreads();
  }

  if (mode >= 3) {
    #pragma unroll
    for (int i = 0; i < 2; i++)
      #pragma unroll
      for (int reg = 0; reg < 4; reg++) {
        float s = 0.f, q = 0.f;
        #pragma unroll
        for (int j = 0; j < 4; j++) { float v = acc[i][j][reg]; s += v; q += v * v; }
        #pragma unroll
        for (int m = 1; m < 16; m <<= 1) { s += __shfl_xor(s, m, 64); q += __shfl_xor(q, m, 64); }
        if (fi == 0) {
          int row = i * 16 + fq * 4 + reg;
          lnS[w][row] = s; lnQ[w][row] = q;
        }
      }
    __syncthreads();
    if (t < 32) {
      float s = lnS[0][t] + lnS[1][t] + lnS[2][t] + lnS[3][t];
      float q = lnQ[0][t] + lnQ[1][t] + lnQ[2][t] + lnQ[3][t];
      float m = s * (1.f / 256.f);
      float var = q * (1.f / 256.f) - m * m;
      muS[t] = m; rsS[t] = rsqrtf(var + 1e-5f);
    }
    __syncthreads();
  }

  #pragma unroll
  for (int i = 0; i < 2; i++) {
    #pragma unroll
    for (int reg = 0; reg < 4; reg++) {
      int row = i * 16 + fq * 4 + reg;
      int gr = row0 + row;
      if (gr >= cntb) continue;
      #pragma unroll
      for (int j = 0; j < 4; j++) {
        int col = w * 64 + j * 16 + fi;
        float v = acc[i][j][reg];
        if (mode == 3) { C[cBase + (long)gr * 256 + col] = (v - muS[row]) * rsS[row]; }
        else if (mode == 4) { X[xBase + (long)gr * 256 + col] += (v - muS[row]) * rsS[row]; }
        else if (mode == 2) { v = (v > 0.f) ? (v + 1.f) : expf(v); C[cBase + (long)gr * 256 + col] = v; }
        else { C[cBase + (long)gr * 256 + col] = v; }
      }
    }
  }
}

// ---------------------------------------------------------------------------
// fp32-B MFMA GEMM (dmatrix only).
// ---------------------------------------------------------------------------
__global__ __launch_bounds__(256) void gemm_f32b_kernel(
    const float* __restrict__ A, const float* __restrict__ B, float* __restrict__ C,
    int M, int N, int Kd, long sA, long sB, long sC, float alpha)
{
  int b = blockIdx.z;
  const float* Ab = A + (long)b * sA;
  const float* Bb = B + (long)b * sB;
  float* Cb = C + (long)b * sC;
  int row0 = blockIdx.y * 128, col0 = blockIdx.x * 128;
  int t = threadIdx.x;
  int lane = t & 63, wid = t >> 6, wm = wid >> 1, wn = wid & 1;
  int fi = lane & 15, fq = lane >> 4;
  __shared__ __align__(16) short Ah[128][36];
  __shared__ __align__(16) short Al[128][36];
  __shared__ __align__(16) short Bsh[128][36];
  __shared__ __align__(16) short Bsl[128][36];
  f32x4 acc[4][4];
  #pragma unroll
  for (int i = 0; i < 4; i++)
    #pragma unroll
    for (int j = 0; j < 4; j++)
      acc[i][j] = (f32x4){0.f, 0.f, 0.f, 0.f};
  int tr = t >> 3, tc = (t & 7) * 4;
  int bn = (t & 31) * 4, bk = t >> 5;
  for (int k0 = 0; k0 < Kd; k0 += 32) {
    #pragma unroll
    for (int p = 0; p < 4; p++) {
      int r = tr + p * 32, gr = row0 + r;
      float4 v = make_float4(0.f, 0.f, 0.f, 0.f);
      if (gr < M) v = *(const float4*)&Ab[(long)gr * Kd + k0 + tc];
      float vv[4] = {v.x, v.y, v.z, v.w};
      #pragma unroll
      for (int e = 0; e < 4; e++) {
        short h = f2bf(vv[e]); Ah[r][tc + e] = h; Al[r][tc + e] = f2bf(vv[e] - bf2f(h));
      }
    }
    #pragma unroll
    for (int p = 0; p < 4; p++) {
      int kk = bk + p * 8;
      long gkN = (long)(k0 + kk) * N;
      #pragma unroll
      for (int e = 0; e < 4; e++) {
        int gc = col0 + bn + e;
        float v = (gc < N) ? Bb[gkN + gc] : 0.f;
        short h = f2bf(v); Bsh[bn + e][kk] = h; Bsl[bn + e][kk] = f2bf(v - bf2f(h));
      }
    }
    __syncthreads();
    short8 ah[4], al[4], bh[4], bl[4];
    #pragma unroll
    for (int i = 0; i < 4; i++) {
      ah[i] = *(const short8*)&Ah[wm * 64 + i * 16 + fi][fq * 8];
      al[i] = *(const short8*)&Al[wm * 64 + i * 16 + fi][fq * 8];
    }
    #pragma unroll
    for (int j = 0; j < 4; j++) {
      bh[j] = *(const short8*)&Bsh[wn * 64 + j * 16 + fi][fq * 8];
      bl[j] = *(const short8*)&Bsl[wn * 64 + j * 16 + fi][fq * 8];
    }
    #pragma unroll
    for (int i = 0; i < 4; i++)
      #pragma unroll
      for (int j = 0; j < 4; j++) {
        acc[i][j] = __builtin_amdgcn_mfma_f32_16x16x32_bf16(ah[i], bh[j], acc[i][j], 0, 0, 0);
        acc[i][j] = __builtin_amdgcn_mfma_f32_16x16x32_bf16(ah[i], bl[j], acc[i][j], 0, 0, 0);
        acc[i][j] = __builtin_amdgcn_mfma_f32_16x16x32_bf16(al[i], bh[j], acc[i][j], 0, 0, 0);
      }
    __syncthreads();
  }
  #pragma unroll
  for (int i = 0; i < 4; i++) {
    #pragma unroll
    for (int reg = 0; reg < 4; reg++) {
      int gr = row0 + wm * 64 + i * 16 + fq * 4 + reg;
      if (gr >= M) continue;
      #pragma unroll
      for (int j = 0; j < 4; j++) {
        int gc = col0 + wn * 64 + j * 16 + fi;
        if (gc < N) Cb[(long)gr * N + gc] = acc[i][j][reg] * alpha;
      }
    }
  }
}

// ---------------------------------------------------------------------------
__device__ __forceinline__ float2 blk_sum2_256(float a, float b)
{
  __shared__ float sa[4], sb[4];
  int lane = threadIdx.x & 63, w = threadIdx.x >> 6;
  #pragma unroll
  for (int off = 32; off > 0; off >>= 1) { a += __shfl_down(a, off, 64); b += __shfl_down(b, off, 64); }
  if (lane == 0) { sa[w] = a; sb[w] = b; }
  __syncthreads();
  float ra = sa[0] + sa[1] + sa[2] + sa[3];
  float rb = sb[0] + sb[1] + sb[2] + sb[3];
  __syncthreads();
  return make_float2(ra, rb);
}

__global__ void cvt2_kernel(float* dst, const float* s0, const float* s1, long n) {
  long i = (long)blockIdx.x * 256 + threadIdx.x;
  if (i < n) dst[i] = s0[i];
  else if (i < 2 * n) dst[i] = s1[i - n];
}

__global__ void bcast_seeds_kernel(float* seeds, const float* st) {
  long i = (long)blockIdx.x * 256 + threadIdx.x;
  if (i < 4L * 25600) seeds[i] = st[i % 25600];
}

// KV[s,h,d,e] = / += sum_r K*V*inv_s ; Ksum[s,h,d] = / += sum_r K.
__global__ __launch_bounds__(1024) void kv_kernel(
    const float* __restrict__ Kb, const float* __restrict__ Vb,
    float* __restrict__ KV, float* __restrict__ Ksum,
    int s_len, float inv_s, int bmask, int bxor,
    const int* __restrict__ segOff, const int* __restrict__ segCnt,
    int axor, int gmin, int gmax, int chunk)
{
  int s = blockIdx.x, h = blockIdx.y;
  long srcBase; int slim;
  if (segOff) {
    int g = s & 7;
    if (g < gmin || g > gmax) return;
    int src = s ^ axor;
    srcBase = (long)(src & 7) * ARENA + segOff[src];
    slim = segCnt[src];
  } else {
    srcBase = (long)s * s_len;
    slim = s_len;
  }
  bool direct = (gridDim.z == 1);
  int s0b = blockIdx.z * chunk;
  int send = min(s0b + chunk, slim);
  __shared__ float Kt[32][33];
  __shared__ float Vt[32][33];
  int tx = threadIdx.x, ty = threadIdx.y;
  float acc = 0.f, ks = 0.f;
  for (int s0 = s0b; s0 < send; s0 += 32) {
    int sr = s0 + ty;
    float kvv = 0.f, vvv = 0.f;
    if (sr < send) {
      long base = (srcBase + sr) * 256 + h * 32 + tx;
      kvv = Kb[base]; vvv = Vb[base];
    }
    Kt[ty][tx] = kvv; Vt[ty][tx] = vvv;
    __syncthreads();
    #pragma unroll
    for (int j = 0; j < 32; j++) acc += Kt[j][ty] * Vt[j][tx];
    if (tx == 0) {
      #pragma unroll
      for (int j = 0; j < 32; j++) ks += Kt[j][ty];
    }
    __syncthreads();
  }
  if (direct) {
    KV[((s * 8 + h) * 32 + ty) * 32 + tx] = acc * inv_s;
    if (tx == 0) Ksum[s * 256 + h * 32 + ty] = ks;
  } else {
    if (s0b >= send) return;
    atomicAdd(&KV[((s * 8 + h) * 32 + ty) * 32 + tx], acc * inv_s);
    if (tx == 0) atomicAdd(&Ksum[s * 256 + h * 32 + ty], ks);
  }
}

// msg = (Q·KV) * Z * s_scale ; Z = 1/(Q·Ksum + 1e-6).
__global__ __launch_bounds__(256) void zmsg_kernel(
    const float* __restrict__ Q, const float* __restrict__ KV,
    const float* __restrict__ Ksum, float* __restrict__ msg, int l, float s_scale,
    const int* __restrict__ segOff, const int* __restrict__ segCnt, int gmin, int gmax)
{
  int s = blockIdx.x;
  long rowBase; int cb;
  if (segOff) {
    int g = s & 7;
    if (g < gmin || g > gmax) return;
    rowBase = (long)g * ARENA + segOff[s];
    cb = segCnt[s];
  } else {
    rowBase = (long)s * l;
    cb = l;
  }
  int r0 = blockIdx.y * 32;
  if (r0 >= cb) return;
  int t = threadIdx.x;
  __shared__ float KVs[8192];
  __shared__ float QL[256];
  __shared__ float Zl[8];
  for (int i = t; i < 8192; i += 256) KVs[i] = KV[s * 8192 + i];
  float Ks = Ksum[s * 256 + t];
  __syncthreads();
  int h = t >> 5, e = t & 31;
  for (int rr = 0; rr < 32; rr++) {
    int row = r0 + rr;
    if (row >= cb) break;
    long base = (rowBase + row) * 256;
    QL[t] = Q[base + t];
    __syncthreads();
    float p = QL[t] * Ks;
    #pragma unroll
    for (int off = 16; off > 0; off >>= 1) p += __shfl_down(p, off, 32);
    if (e == 0) Zl[h] = 1.f / (p + 1e-6f);
    __syncthreads();
    float acc = 0.f;
    const float* kvh = KVs + h * 1024;
    #pragma unroll
    for (int d = 0; d < 32; d++) acc += QL[h * 32 + d] * kvh[d * 32 + e];
    msg[base + t] = acc * Zl[h] * s_scale;
    __syncthreads();
  }
}

// ---------------- topic pipeline ----------------
__global__ __launch_bounds__(256) void tm_all_kernel(const float* __restrict__ t0,
                                                     const float* __restrict__ t1,
                                                     int* __restrict__ tmidx) {
  int n = blockIdx.x, t = threadIdx.x;
  __shared__ float TM[100][100];
  __shared__ float cmax[100], csum[100], rmax[100], rsum[100];
  for (int i = t; i < 10000; i += 256) {
    int m = i / 100, l = i % 100;
    float acc = 0.f;
    for (int d = 0; d < 96; d++)
      acc += t0[(n * 96 + d) * 100 + m] * t1[(n * 96 + d) * 100 + l];
    TM[m][l] = floorf(acc * 0.0625f);
  }
  __syncthreads();
  if (t < 100) {
    int l = t;
    float mx = -1e30f;
    for (int m = 0; m < 100; m++) mx = fmaxf(mx, TM[m][l]);
    float s = 0.f;
    for (int m = 0; m < 100; m++) s += expf(TM[m][l] - mx);
    cmax[l] = mx; csum[l] = s;
    int m = t;
    float mx2 = -1e30f;
    for (int l2 = 0; l2 < 100; l2++) mx2 = fmaxf(mx2, TM[m][l2]);
    float s2 = 0.f;
    for (int l2 = 0; l2 < 100; l2++) s2 += expf(TM[m][l2] - mx2);
    rmax[m] = mx2; rsum[m] = s2;
  }
  __syncthreads();
  if (t < 100) {
    int m = t;
    float best = -1e30f; int bi = 0;
    for (int l = 0; l < 100; l++) {
      float x = TM[m][l];
      float v = (expf(x - cmax[l]) / csum[l]) * (expf(x - rmax[m]) / rsum[m]);
      if (v > best) { best = v; bi = l; }
    }
    tmidx[n * 100 + m] = bi;
  }
}

// seedsF: adaptive-pool(seeds,160) ++ topicp (inline) -> LN -> transposed sT.
__global__ void seedsF_kernel(const float* __restrict__ seeds,
                              const float* __restrict__ t0raw,
                              const float* __restrict__ t1raw,
                              const int* __restrict__ tmidx, float* __restrict__ sT) {
  int n = blockIdx.x, k = blockIdx.y, t = threadIdx.x;
  float v;
  if (t < 160) {
    int s = (t * 256) / 160;
    int e = ((t + 1) * 256 + 159) / 160;
    float a = 0.f;
    for (int i = s; i < e; i++) a += seeds[(n * 100 + k) * 256 + i];
    v = a / (float)(e - s);
  } else {
    int j = t - 160;
    int g = tmidx[300 + k];
    float a, b;
    if (j < 48) {
      a = t0raw[(n * 96 + 2 * j) * 100 + k];
      b = t0raw[(n * 96 + 2 * j + 1) * 100 + k];
    } else {
      int d0 = 2 * j - 96;
      a = t1raw[(n * 96 + d0) * 100 + g];
      b = t1raw[(n * 96 + d0 + 1) * 100 + g];
    }
    v = 0.5f * (a + b);
  }
  float2 r = blk_sum2_256(v, v * v);
  float m = r.x * (1.f / 256.f);
  float var = r.y * (1.f / 256.f) - m * m;
  sT[n * 25600 + t * 100 + k] = (v - m) * rsqrtf(var + 1e-5f);
}

// ---------------- dmatrix post ----------------
__global__ void softmax_rows_kernel(const float* dm, float* prob, int* amax) {
  long row = blockIdx.x; int t = threadIdx.x;
  __shared__ float red[128]; __shared__ int ri[128];
  float v = (t < 100) ? dm[row * 100 + t] : -1e30f;
  red[t] = v; ri[t] = t; __syncthreads();
  for (int off = 64; off > 0; off >>= 1) {
    if (t < off) {
      if (red[t + off] > red[t] || (red[t + off] == red[t] && ri[t + off] < ri[t])) {
        red[t] = red[t + off]; ri[t] = ri[t + off];
      }
    }
    __syncthreads();
  }
  float mx = red[0];
  if (t == 0) amax[row] = ri[0];
  __syncthreads();
  float e = (t < 100) ? expf(v - mx) : 0.f;
  red[t] = e; __syncthreads();
  for (int off = 64; off > 0; off >>= 1) { if (t < off) red[t] += red[t + off]; __syncthreads(); }
  float s = red[0];
  if (t < 100) prob[row * 100 + t] = e / s;
}

__global__ void colsum_kernel(const float* prob, float* cs0, float* cs1) {
  int k = blockIdx.x, n = blockIdx.y, half = blockIdx.z;
  int t = threadIdx.x;
  const float* p = prob + ((long)n * 8192 + half * 4096) * 100 + k;
  float s = 0.f;
  for (int m = t; m < 4096; m += 256) s += p[(long)m * 100];
  float2 r = blk_sum2_256(s, 0.f);
  if (t == 0) (half ? cs1 : cs0)[n * 100 + k] = r.x;
}

__global__ void topk_kernel(const float* cs0, const float* cs1, int* inds) {
  int n = blockIdx.x, t = threadIdx.x;
  __shared__ float rv[128]; __shared__ int ri[128]; __shared__ int sbest;
  float base = (t < 100) ? cs0[n * 100 + t] * cs1[n * 100 + t] : -1.f;
  for (int kk = 0; kk < 6; kk++) {
    rv[t] = base; ri[t] = t; __syncthreads();
    for (int off = 64; off > 0; off >>= 1) {
      if (t < off) {
        if (rv[t + off] > rv[t] || (rv[t + off] == rv[t] && ri[t + off] < ri[t])) { rv[t] = rv[t + off]; ri[t] = ri[t + off]; }
      }
      __syncthreads();
    }
    if (t == 0) { inds[n * 6 + kk] = ri[0]; sbest = ri[0]; }
    __syncthreads();
    if (t == sbest) base = -1.f;
    __syncthreads();
  }
}

// ---------------- packed sample machinery ----------------
__global__ __launch_bounds__(1024) void count_kernel(const int* amax, const int* inds, int* segCnt) {
  int seg = blockIdx.x;
  int kk = seg >> 3, g = seg & 7, n = g & 3, half = g >> 2;
  int target = inds[n * 6 + kk];
  const int* am = amax + n * 8192 + half * 4096;
  int t = threadIdx.x;
  int lc = 0;
  #pragma unroll
  for (int j = 0; j < 4; j++) lc += (am[t * 4 + j] == target) ? 1 : 0;
  __shared__ int red[16];
  #pragma unroll
  for (int off = 32; off > 0; off >>= 1) lc += __shfl_down(lc, off, 64);
  if ((t & 63) == 0) red[t >> 6] = lc;
  __syncthreads();
  if (t == 0) {
    int s = 0;
    for (int w = 0; w < 16; w++) s += red[w];
    segCnt[seg] = s;
  }
}

// offs: segment offsets + cond flags + DENSE BLOCK TABLES.
__global__ void offs_kernel(const int* segCnt, int* segOff, float* condf,
                            int* tabCnt,
                            int2* t128_07, int2* t128_03, int2* t128_47,
                            int2* t32_07, int2* t32_03, int2* t32_47) {
  int t = threadIdx.x;
  if (t < 8) {
    int run = 0;
    for (int kk = 0; kk < 6; kk++) {
      segOff[kk * 8 + t] = run;
      run += (segCnt[kk * 8 + t] + 127) & ~127;
    }
  }
  if (t >= 8 && t < 14) {
    int kk = t - 8;
    int a = 0, b = 0;
    for (int g = 0; g < 4; g++) { a += segCnt[kk * 8 + g]; b += segCnt[kk * 8 + 4 + g]; }
    condf[kk] = (a > 0 && b > 0) ? 1.f : 0.f;
  }
  __syncthreads();
  __shared__ int pref[48];
  int2* tabs[6] = {t128_07, t128_03, t128_47, t32_07, t32_03, t32_47};
  for (int tb = 0; tb < 6; tb++) {
    int tile = (tb < 3) ? 128 : 32;
    int r = tb % 3;
    int nb = 0;
    if (t < 48) {
      int g = t & 7;
      bool in = (r == 0) || (r == 1 && g < 4) || (r == 2 && g >= 4);
      if (in) nb = (min(segCnt[t], 4096) + tile - 1) / tile;
      pref[t] = nb;
    }
    __syncthreads();
    for (int o = 1; o < 48; o <<= 1) {
      int v = 0;
      if (t < 48 && t >= o) v = pref[t - o];
      __syncthreads();
      if (t < 48) pref[t] += v;
      __syncthreads();
    }
    if (t < 48 && nb > 0) {
      int st = pref[t] - nb;
      for (int j = 0; j < nb; j++) tabs[tb][st + j] = make_int2(t, j * tile);
    }
    if (t == 0) tabCnt[tb] = pref[47];
    __syncthreads();
  }
}

// ord: stable compaction order + direct gather of packed rows.
__global__ __launch_bounds__(1024) void ord_kernel(const int* amax, const int* inds,
                                                   const int* segOff, int* ordP,
                                                   float* __restrict__ nf,
                                                   const float* __restrict__ f01) {
  int seg = blockIdx.x;
  int kk = seg >> 3, g = seg & 7, n = g & 3, half = g >> 2;
  int target = inds[n * 6 + kk];
  const int* am = amax + n * 8192 + half * 4096;
  int t = threadIdx.x;
  __shared__ int ts[1024];
  int f[4]; int lc = 0;
  #pragma unroll
  for (int j = 0; j < 4; j++) { f[j] = (am[t * 4 + j] == target) ? 1 : 0; lc += f[j]; }
  ts[t] = lc; __syncthreads();
  for (int off = 1; off < 1024; off <<= 1) {
    int add = (t >= off) ? ts[t - off] : 0;
    __syncthreads();
    ts[t] += add;
    __syncthreads();
  }
  int run = (t == 0) ? 0 : ts[t - 1];
  long base = (long)g * ARENA + segOff[seg];
  int* o = ordP + base;
  #pragma unroll
  for (int j = 0; j < 4; j++) {
    if (f[j]) {
      int tok = t * 4 + j;
      o[run] = tok;
      const float4* s4p = (const float4*)&f01[((long)g * 4096 + tok) * 256];
      float4* d4p = (float4*)&nf[(base + run) * 256];
      for (int c = 0; c < 64; c++) d4p[c] = s4p[c];
      run++;
    }
  }
}

__global__ void scatter_kernel(float* up, const float* nf, const int* ordP,
                               const int* segOff, const int* segCnt, const float* condf) {
  int seg = blockIdx.y;
  int kk = seg >> 3, g = seg & 7;
  int cntb = segCnt[seg];
  int row0 = blockIdx.x * 128;
  if (row0 >= cntb) return;
  long base = (long)g * ARENA + segOff[seg];
  float cf = condf[kk];
  int t = threadIdx.x;
  int c4 = (t & 63) * 4, rr = t >> 6;
  for (int p = 0; p < 32; p++) {
    int r = row0 + p * 4 + rr;
    if (r >= cntb) break;
    int tok = ordP[base + r];
    float4 add = *(const float4*)&nf[(base + r) * 256 + c4];
    float4* dst = (float4*)&up[((long)g * 4096 + tok) * 256 + c4];
    float4 cur = *dst;
    cur.x += add.x * cf; cur.y += add.y * cf; cur.z += add.z * cf; cur.w += add.w * cf;
    *dst = cur;
  }
}

// up01 aliases out's feat region (index-identical); in-place RMW.
__global__ void final_mix_kernel(const float* f01, float* out_up, const int* amax,
                                 const int* inds) {
  int b = blockIdx.y, half = b >> 2, n = b & 3;
  int l = blockIdx.x, c = threadIdx.x;
  int a = amax[n * 8192 + half * 4096 + l];
  const int* in_ = inds + n * 6;
  bool member = (a == in_[0]) | (a == in_[1]) | (a == in_[2]) | (a == in_[3]) | (a == in_[4]) | (a == in_[5]);
  long idx = ((long)b * 4096 + l) * 256 + c;
  float up = out_up[idx];
  out_up[idx] = (member ? 0.f : 1.f) * f01[idx] + up;
}

__global__ void tmi_kernel(const float* dmat, float* out) {
  int n = blockIdx.y, half = blockIdx.z;
  long i = (long)blockIdx.x * 256 + threadIdx.x;
  const float* dm = dmat + (long)n * 819200 + (long)half * 409600;
  int a = (int)(i / 100), b = (int)(i % 100);
  int y = a >> 6, x = a & 63;
  float sum = 0.f;
  for (int dy = -1; dy <= 1; dy++) {
    int yy = y + dy; if (yy < 0 || yy >= 64) continue;
    for (int dx = -1; dx <= 1; dx++) {
      int xc = x + dx; if (xc < 0 || xc >= 64) continue;
      sum += dm[b * 4096 + yy * 64 + xc];
    }
  }
  out[8388608L + (long)half * 1638400 + (long)n * 409600 + i] = dm[i] * (sum * (1.f / 9.f));
}

// ---------------------------------------------------------------------------
extern "C" void kernel_launch(void* const* d_in, const int* in_sizes, int n_in,
                              void* d_out, int out_size, void* d_ws, size_t ws_size,
                              hipStream_t stream)
{
  (void)in_sizes; (void)n_in; (void)out_size; (void)ws_size;
  const float* feat0_in = (const float*)d_in[0];
  const float* feat1_in = (const float*)d_in[1];
  const float* topic0 = (const float*)d_in[2];
  const float* topic1 = (const float*)d_in[3];
  const float* seed_tokens = (const float*)d_in[4];
  const float* Wq = (const float*)d_in[5];
  const float* Wk = (const float*)d_in[6];
  const float* Wv = (const float*)d_in[7];
  const float* Wm = (const float*)d_in[8];
  const float* W1 = (const float*)d_in[9];
  const float* W2 = (const float*)d_in[10];
  float* out = (float*)d_out;

  float* base = (float*)d_ws;
  long off = 0;
  auto alloc = [&](long n) -> float* { float* p = base + off; off += (n + 255) & ~255L; return p; };
  float* f01   = alloc(8388608);          // [8][4096][256]
  float* qb    = alloc(8L * ARENA * 256); // Q / LN(msg2)
  float* kb    = alloc(8L * ARENA * 256); // K / msg / h1 low   (kb,vb contiguous)
  float* vb    = alloc(8L * ARENA * 256); // V / h1 high
  float* nf    = alloc(8L * ARENA * 256); // packed sample tokens
  float* seeds = alloc(102400);
  float* kvks  = alloc(48 * 8192 + 48 * 256);
  float* dmat  = alloc(3276800);
  short* wbuf  = (short*)alloc(5242880);
  float* sT    = alloc(102400);
  float* cs0   = alloc(400);
  float* cs1   = alloc(400);
  float* condf = alloc(256);
  int* tmidx  = (int*)alloc(400);
  int* amax   = (int*)alloc(32768);
  int* inds   = (int*)alloc(256);
  int* segCnt = (int*)alloc(256);
  int* segOffA= (int*)alloc(256);
  int* ordP   = (int*)alloc(8L * ARENA);
  int* tabCnt = (int*)alloc(64);
  int2* T128_07 = (int2*)alloc(640);
  int2* T128_03 = (int2*)alloc(320);
  int2* T128_47 = (int2*)alloc(320);
  int2* T32_07  = (int2*)alloc(2176);
  int2* T32_03  = (int2*)alloc(1088);
  int2* T32_47  = (int2*)alloc(1088);
  float* up01 = out;                      // aliases out's feat region

  const int m128[3] = {304, 152, 152};
  const int m32[3]  = {1072, 536, 536};
  int2* T128[3] = {T128_07, T128_03, T128_47};
  int2* T32[3]  = {T32_07, T32_03, T32_47};

  auto WOFF = [](int l) -> long { return (long)l * 1310720; };

  auto gmainZ = [&](const float* A, const float* A2, int aw, long wOff, int loD,
                    float* c0, float* c1, float* c2, int M, int Kd, int Ntot, int outW,
                    long sA_, long sC_, int bm, int bx,
                    int m0, int m1, int m2_, int nb) {
    dim3 g(Ntot / 128, (M + 127) / 128, nb), blk(256);
    gemm_main_kernel<<<g, blk, 0, stream>>>(A, A2, aw, wbuf + wOff, loD, c0, c1, c2,
        M, Kd, outW, sA_, sC_, bm, bx, nullptr, nullptr,
        nullptr, nullptr, nullptr, 0, 0, m0, m1, m2_);
  };
  auto gmainP = [&](const float* A, const float* A2, int aw, long wOff, int loD,
                    float* c0, float* c1, float* c2, int Kd, int Ntot, int outW,
                    int rQ, int rKV, int m0, int m1, int m2_) {
    int ymax = max(m128[rQ], m128[rKV]);
    dim3 g(Ntot / 128, ymax, 1), blk(256);
    gemm_main_kernel<<<g, blk, 0, stream>>>(A, A2, aw, wbuf + wOff, loD, c0, c1, c2,
        4096, Kd, outW, 0, 0, 0, 0, segOffA, segCnt,
        T128[rQ], T128[rKV], tabCnt, rQ, rKV, m0, m1, m2_);
  };
  auto g256Z = [&](const float* A, int aw, long wOff, int loD, float* C, float* X,
                   int M, int Kd, long sA_, long sC_, long sX_, int bm, int bx,
                   int mode, int nb) {
    dim3 g(1, (M + 127) / 128, nb), blk(256);
    gemm256_kernel<<<g, blk, 0, stream>>>(A, aw, wbuf + wOff, loD, C, X,
        M, Kd, sA_, sC_, sX_, bm, bx, mode);
  };
  auto g256P = [&](const float* A, int aw, long wOff, int loD, float* C, float* X,
                   int r, int mode) {
    dim3 g(1, m32[r], 1), blk(256);
    gemm256_seg_kernel<<<g, blk, 0, stream>>>(A, aw, wbuf + wOff, loD, C, X,
        segOffA, segCnt, T32[r], tabCnt + 3 + r, mode);
  };

  auto encTailZ = [&](float* x, int l, int s_len, float s_scale, int layer, int nb,
                      long sAx, int bmKV, int bxKV, int nch) {
    if (nch > 1)
      hipMemsetAsync(kvks, 0, (48 * 8192 + 48 * 256) * sizeof(float), stream);
    int chunk = (s_len + nch - 1) / nch;
    kv_kernel<<<dim3(nb, 8, nch), dim3(32, 32), 0, stream>>>(
        kb, vb, kvks, kvks + 48 * 8192, s_len, 1.f / s_scale, bmKV, bxKV,
        nullptr, nullptr, 0, 0, 7, chunk);
    zmsg_kernel<<<dim3(nb, (l + 31) / 32), 256, 0, stream>>>(
        qb, kvks, kvks + 48 * 8192, kb, l, s_scale, nullptr, nullptr, 0, 7);
    g256Z(kb, 256, WOFF(layer) + 393216, 65536, qb, nullptr,
          l, 256, sAx, sAx, 0, 7, 0, 3, nb);
    gmainZ(x, qb, 256, WOFF(layer) + 524288, 262144, kb, nullptr, nullptr,
           l, 512, 512, 512, sAx, sAx * 2, 7, 0, 1, 0, 0, nb);
    g256Z(kb, 512, WOFF(layer) + 1048576, 131072, nullptr, x,
          l, 512, sAx * 2, 0, sAx, 7, 0, 4, nb);
  };
  auto encTailP = [&](float* x, float s_scale, int layer, int r, int axor,
                      int gmin, int gmax) {
    kv_kernel<<<dim3(48, 8, 1), dim3(32, 32), 0, stream>>>(
        kb, vb, kvks, kvks + 48 * 8192, 4096, 1.f / s_scale, 0, 0,
        segOffA, segCnt, axor, gmin, gmax, 4096);
    zmsg_kernel<<<dim3(48, 128), 256, 0, stream>>>(
        qb, kvks, kvks + 48 * 8192, kb, 4096, s_scale, segOffA, segCnt, gmin, gmax);
    g256P(kb, 256, WOFF(layer) + 393216, 65536, qb, nullptr, r, 3);
    gmainP(x, qb, 256, WOFF(layer) + 524288, 262144, kb, nullptr, nullptr,
           512, 512, 512, r, r, 1, 0, 0);
    g256P(kb, 512, WOFF(layer) + 1048576, 131072, nullptr, x, r, 4);
  };

  // ---- init ----
  cvt2_kernel<<<32768, 256, 0, stream>>>(f01, feat0_in, feat1_in, 4194304);
  bcast_seeds_kernel<<<400, 256, 0, stream>>>(seeds, seed_tokens);
  prep_w_kernel<<<20480, 256, 0, stream>>>(Wq, Wk, Wv, Wm, W1, W2, wbuf);

  // ---- topic pipeline ----
  tm_all_kernel<<<4, 256, 0, stream>>>(topic0, topic1, tmidx);

  // ---- main encoder layers ----
  auto encSeedLayer = [&](int layer) {
    g256Z(seeds, 256, WOFF(layer), 196608, qb, nullptr,
          100, 256, 25600, 25600, 0, 7, 0, 2, 4);
    gmainZ(feat0_in, nullptr, 256, WOFF(layer) + 65536, 196608, kb, vb, nullptr,
           4096, 256, 512, 256, 1048576, 2097152, 7, 0, 2, 0, 0, 4);
    gmainZ(feat1_in, nullptr, 256, WOFF(layer) + 65536, 196608, kb + 1048576, vb + 1048576, nullptr,
           4096, 256, 512, 256, 1048576, 2097152, 7, 0, 2, 0, 0, 4);
    encTailZ(seeds, 100, 8192, 8192.f, layer, 4, 25600, 7, 0, 8);
  };
  auto encFeatLayer = [&](int layer) {
    g256Z(f01, 256, WOFF(layer), 196608, qb, nullptr,
          4096, 256, 1048576, 1048576, 0, 7, 0, 2, 8);
    gmainZ(seeds, nullptr, 256, WOFF(layer) + 65536, 196608, kb, vb, nullptr,
           100, 256, 512, 256, 25600, 25600, 3, 0, 2, 0, 0, 8);
    encTailZ(f01, 4096, 100, 100.f, layer, 8, 1048576, 7, 0, 1);
  };

  encSeedLayer(0);
  encFeatLayer(1);
  encSeedLayer(2);
  encFeatLayer(3);

  // ---- seeds final + dmatrix ----
  seedsF_kernel<<<dim3(4, 100), 256, 0, stream>>>(seeds, topic0, topic1, tmidx, sT);
  {
    dim3 g(1, 32, 4), blk(256);
    gemm_f32b_kernel<<<g, blk, 0, stream>>>(feat0_in, sT, dmat, 4096, 100, 256, 1048576, 25600, 819200, 0.0625f);
    gemm_f32b_kernel<<<g, blk, 0, stream>>>(feat1_in, sT, dmat + 409600, 4096, 100, 256, 1048576, 25600, 819200, 0.0625f);
  }
  float* prob = kb;
  softmax_rows_kernel<<<32768, 128, 0, stream>>>(dmat, prob, amax);
  colsum_kernel<<<dim3(100, 4, 2), 256, 0, stream>>>(prob, cs0, cs1);
  topk_kernel<<<4, 128, 0, stream>>>(cs0, cs1, inds);

  hipMemsetAsync(up01, 0, 8388608 * sizeof(float), stream);

  // ---- sample phase: 48 packed segments, table-driven GEMMs ----
  count_kernel<<<48, 1024, 0, stream>>>(amax, inds, segCnt);
  offs_kernel<<<1, 64, 0, stream>>>(segCnt, segOffA, condf, tabCnt,
                                    T128_07, T128_03, T128_47, T32_07, T32_03, T32_47);
  ord_kernel<<<48, 1024, 0, stream>>>(amax, inds, segOffA, ordP, nf, f01);

  for (int idt = 0; idt < 2; idt++) {
    int wA = 4 + idt * 2, wB = wA + 1;
    gmainP(nf, nullptr, 256, WOFF(wA), 196608, qb, kb, vb,
           256, 768, 256, 0, 0, 2, 2, 0);
    encTailP(nf, 4096.f, wA, 0, 0, 0, 7);
    gmainP(nf, nullptr, 256, WOFF(wB), 196608, qb, kb, vb,
           256, 768, 256, 1, 2, 2, 2, 0);
    encTailP(nf, 4096.f, wB, 1, 4, 0, 3);
    gmainP(nf, nullptr, 256, WOFF(wB), 196608, qb, kb, vb,
           256, 768, 256, 2, 1, 2, 2, 0);
    encTailP(nf, 4096.f, wB, 2, 4, 4, 7);
  }
  scatter_kernel<<<dim3(32, 48), 256, 0, stream>>>(up01, nf, ordP, segOffA, segCnt, condf);

  // ---- outputs ----
  final_mix_kernel<<<dim3(4096, 8), 256, 0, stream>>>(f01, up01, amax, inds);
  tmi_kernel<<<dim3(1600, 4, 2), 256, 0, stream>>>(dmat, out);
}

// Round 6
// 2458.676 us; speedup vs baseline: 2.1734x; 1.0614x over previous
//
#include <hip/hip_runtime.h>
#include <math.h>

// N=4, L=S=4096, C=256, K=100, NHEAD=8, D=32. FP32 I/O.
// Big GEMMs: bf16x3 split MFMA (hi*hi + hi*lo + lo*hi, fp32 acc) ~ fp32 fidelity.
// Sample loop batched into 48 packed segments (6 samples x 8 batch-halves),
// 128-aligned inside an [8][4864]-row arena.
// R1: panel-major weights (256-col groups of [k/32][n&255][32]); depth-1 prefetch.
// R2: wB Q fused into K/V gmain; zmsg 32 rows/block; softmax+argmax fused.
// R3: kv direct-store; seedsF folds topicp+transpose; ord folds gather.
// R4: packed GEMMs driven by device-built dense block tables (seg,row0) --
//     fixes block->XCD aliasing (active idx % 8 == 0 put everything on XCD 0);
//     packed g256 re-tiled 128->32 rows. 5343 -> 2609us.
// R5: tm_all (R3 fusion) measured 211us at 4 blocks (serial strided TM build):
//     split into tm_build (4x100 blocks, t0-col in LDS, coalesced t1 reads)
//     + tm_post (TM in LDS, stats+argmax). scatter grid transposed (active
//     idx was 32*seg == 0 mod 8 -> all on XCD 0; now idx = seg).
//     [resubmit: previous run died to container infra failure, not kernel]

typedef __attribute__((ext_vector_type(8))) short short8;
typedef __attribute__((ext_vector_type(4))) short s4;
typedef __attribute__((ext_vector_type(4))) float f32x4;

#define ARENA 4864  // rows per g in packed arena (4096 + 6*128 alignment pad)

__device__ __forceinline__ short f2bf(float f) {
  unsigned u = __float_as_uint(f);
  return (short)((u + 0x7FFFu + ((u >> 16) & 1u)) >> 16);
}
__device__ __forceinline__ float bf2f(short s) {
  return __uint_as_float(((unsigned)(unsigned short)s) << 16);
}

// ---------------------------------------------------------------------------
// Weight prep: per layer L, panel-major bf16 hi/lo planes.
// Layout per matrix: 256-col groups; group g holds cols [g*256,(g+1)*256);
// within group: panel p = k/32 (8192 shorts each); within panel: (n&255)*32+(k&31).
// Per-layer stride 1310720 shorts:
//   +0       QKV [768][256] hi (Wq group0, Wk group1, Wv group2), lo +196608
//   +393216  Wm  [256][256] hi, lo +65536
//   +524288  W1  [512][512] hi (2 groups of 131072), lo +262144
//   +1048576 W2  [256][512] hi, lo +131072
// ---------------------------------------------------------------------------
__global__ void prep_w_kernel(const float* __restrict__ Wq, const float* __restrict__ Wk,
                              const float* __restrict__ Wv, const float* __restrict__ Wm,
                              const float* __restrict__ W1, const float* __restrict__ W2,
                              short* __restrict__ wb) {
  long i = (long)blockIdx.x * 256 + threadIdx.x;
  if (i >= 8L * 655360) return;
  int L = (int)(i / 655360);
  int r = (int)(i % 655360);
  long base = (long)L * 1310720;
  float v; long dhi; int loD;
  if (r < 196608) {
    int n = r >> 8, k = r & 255;
    const float* s = (n < 256) ? (Wq + (long)L * 65536)
                   : (n < 512) ? (Wk + (long)L * 65536) : (Wv + (long)L * 65536);
    v = s[k * 256 + (n & 255)];
    dhi = base + ((long)(n >> 8) << 16) + ((long)(k >> 5) << 13) + ((n & 255) << 5) + (k & 31);
    loD = 196608;
  } else if (r < 262144) {
    int j = r - 196608; int n = j >> 8, k = j & 255;
    v = Wm[(long)L * 65536 + k * 256 + n];
    dhi = base + 393216 + ((long)(k >> 5) << 13) + (n << 5) + (k & 31);
    loD = 65536;
  } else if (r < 524288) {
    int j = r - 262144; int n = j >> 9, k = j & 511;
    v = W1[(long)L * 262144 + (long)k * 512 + n];
    dhi = base + 524288 + ((long)(n >> 8) << 17) + ((long)(k >> 5) << 13) + ((n & 255) << 5) + (k & 31);
    loD = 262144;
  } else {
    int j = r - 524288; int n = j >> 9, k = j & 511;
    v = W2[(long)L * 131072 + (long)k * 256 + n];
    dhi = base + 1048576 + ((long)(k >> 5) << 13) + (n << 5) + (k & 31);
    loD = 131072;
  }
  short h = f2bf(v);
  wb[dhi] = h;
  wb[dhi + loD] = f2bf(v - bf2f(h));
}

// ---------------------------------------------------------------------------
// gemm_main: 128x128 tiles. Plain-batch (z-grid) OR packed via dense block
// table (grid.y indexes (seg,row0); sel==0 -> tabQ, sel>=1 -> tabKV).
// modes: 0 none, 1 relu, 2 elu(x)+1.
// ---------------------------------------------------------------------------
__global__ __launch_bounds__(256) void gemm_main_kernel(
    const float* __restrict__ A, const float* __restrict__ A2, int aw,
    const short* __restrict__ Bh, int loD,
    float* __restrict__ C0, float* __restrict__ C1, float* __restrict__ C2,
    int M, int Kd, int outW, long sA, long sC,
    int bmask, int bxor,
    const int* __restrict__ segOff, const int* __restrict__ segCnt,
    const int2* __restrict__ tabQ, const int2* __restrict__ tabKV,
    const int* __restrict__ tabCnt, int tQ, int tKV,
    int mode0, int mode1, int mode2)
{
  int colg = blockIdx.x * 128;
  int sel = colg / outW;
  long aBase, cBase; int cntb, row0;
  if (tabQ) {
    const int2* tab = (sel == 0) ? tabQ : tabKV;
    int n = tabCnt[(sel == 0) ? tQ : tKV];
    int y = blockIdx.y;
    if (y >= n) return;
    int2 e = tab[y];
    long rb = (long)(e.x & 7) * ARENA + segOff[e.x];
    aBase = rb * aw; cBase = rb * (long)outW;
    cntb = segCnt[e.x];
    row0 = e.y;
  } else {
    int z = blockIdx.z;
    int ab = (z & bmask) ^ bxor;
    aBase = (long)ab * sA; cBase = (long)z * sC;
    cntb = M;
    row0 = blockIdx.y * 128;
    if (row0 >= cntb) return;
  }
  float* Cb = (sel == 0 ? C0 : (sel == 1 ? C1 : C2)) + cBase;
  int mode = (sel == 0 ? mode0 : (sel == 1 ? mode1 : mode2));
  int colo = colg % outW;

  int t = threadIdx.x;
  int lane = t & 63, wid = t >> 6, wm = wid >> 1, wn = wid & 1;
  int fi = lane & 15, fq = lane >> 4;

  __shared__ __align__(16) short Ah[128][36];
  __shared__ __align__(16) short Al[128][36];
  __shared__ __align__(16) short Bsh[128][36];
  __shared__ __align__(16) short Bsl[128][36];

  f32x4 acc[4][4];
  #pragma unroll
  for (int i = 0; i < 4; i++)
    #pragma unroll
    for (int j = 0; j < 4; j++)
      acc[i][j] = (f32x4){0.f, 0.f, 0.f, 0.f};

  int tr = t >> 3, tc = (t & 7) * 4;
  int nc = t >> 1, kh = (t & 1) * 16;
  int gb = colg >> 8;
  int cg = (colg & 255) + nc;
  const short* bBase = Bh + (long)gb * ((long)Kd << 8) + (long)cg * 32 + kh;

  float4 avp[4];
  short8 bhp[2], blp[2];

  auto issueA = [&](int k0) {
    bool useA2 = (A2 != nullptr) && (k0 >= 256);
    const float* Asrc = useA2 ? A2 : A;
    int kcol = useA2 ? (k0 - 256) : k0;
    #pragma unroll
    for (int p = 0; p < 4; p++) {
      int gr = row0 + tr + p * 32;
      avp[p] = make_float4(0.f, 0.f, 0.f, 0.f);
      if (gr < M) avp[p] = *(const float4*)&Asrc[aBase + (long)gr * aw + kcol + tc];
    }
  };
  auto issueB = [&](int k0) {
    const short* bs = bBase + ((long)(k0 >> 5) << 13);
    bhp[0] = *(const short8*)bs;
    bhp[1] = *(const short8*)(bs + 8);
    blp[0] = *(const short8*)(bs + loD);
    blp[1] = *(const short8*)(bs + loD + 8);
  };

  issueA(0); issueB(0);
  for (int k0 = 0; k0 < Kd; k0 += 32) {
    #pragma unroll
    for (int p = 0; p < 4; p++) {
      float vv[4] = {avp[p].x, avp[p].y, avp[p].z, avp[p].w};
      s4 h4, l4;
      #pragma unroll
      for (int e = 0; e < 4; e++) {
        short h = f2bf(vv[e]); h4[e] = h; l4[e] = f2bf(vv[e] - bf2f(h));
      }
      *(s4*)&Ah[tr + p * 32][tc] = h4;
      *(s4*)&Al[tr + p * 32][tc] = l4;
    }
    *(short8*)&Bsh[nc][kh]     = bhp[0];
    *(short8*)&Bsh[nc][kh + 8] = bhp[1];
    *(short8*)&Bsl[nc][kh]     = blp[0];
    *(short8*)&Bsl[nc][kh + 8] = blp[1];
    if (k0 + 32 < Kd) { issueA(k0 + 32); issueB(k0 + 32); }
    __syncthreads();
    short8 ah[4], al[4], bh[4], bl[4];
    #pragma unroll
    for (int i = 0; i < 4; i++) {
      ah[i] = *(const short8*)&Ah[wm * 64 + i * 16 + fi][fq * 8];
      al[i] = *(const short8*)&Al[wm * 64 + i * 16 + fi][fq * 8];
    }
    #pragma unroll
    for (int j = 0; j < 4; j++) {
      bh[j] = *(const short8*)&Bsh[wn * 64 + j * 16 + fi][fq * 8];
      bl[j] = *(const short8*)&Bsl[wn * 64 + j * 16 + fi][fq * 8];
    }
    #pragma unroll
    for (int i = 0; i < 4; i++)
      #pragma unroll
      for (int j = 0; j < 4; j++) {
        acc[i][j] = __builtin_amdgcn_mfma_f32_16x16x32_bf16(ah[i], bh[j], acc[i][j], 0, 0, 0);
        acc[i][j] = __builtin_amdgcn_mfma_f32_16x16x32_bf16(ah[i], bl[j], acc[i][j], 0, 0, 0);
        acc[i][j] = __builtin_amdgcn_mfma_f32_16x16x32_bf16(al[i], bh[j], acc[i][j], 0, 0, 0);
      }
    __syncthreads();
  }
  #pragma unroll
  for (int i = 0; i < 4; i++) {
    #pragma unroll
    for (int reg = 0; reg < 4; reg++) {
      int gr = row0 + wm * 64 + i * 16 + fq * 4 + reg;
      if (gr >= M || gr >= cntb) continue;
      #pragma unroll
      for (int j = 0; j < 4; j++) {
        int cc = colo + wn * 64 + j * 16 + fi;
        float v = acc[i][j][reg];
        if (mode == 1) { if (v < 0.f) v = 0.f; }
        else if (mode == 2) { v = (v > 0.f) ? (v + 1.f) : expf(v); }
        Cb[(long)gr * outW + cc] = v;
      }
    }
  }
}

// ---------------------------------------------------------------------------
// gemm256: N=256, 128x256 tile, PLAIN batch only. modes: 0 none, 2 elu+1,
// 3 LN->C, 4 X += LN.
// ---------------------------------------------------------------------------
__global__ __launch_bounds__(256) void gemm256_kernel(
    const float* __restrict__ A, int aw, const short* __restrict__ Bh, int loD,
    float* __restrict__ C, float* __restrict__ X,
    int M, int Kd, long sA, long sC, long sX,
    int bmask, int bxor, int mode)
{
  int z = blockIdx.z;
  int ab = (z & bmask) ^ bxor;
  long aBase = (long)ab * sA, cBase = (long)z * sC, xBase = (long)ab * sX;
  int row0 = blockIdx.y * 128;
  if (row0 >= M) return;

  int t = threadIdx.x;
  int lane = t & 63, wid = t >> 6, wm = wid >> 1, wn = wid & 1;
  int fi = lane & 15, fq = lane >> 4;

  __shared__ __align__(16) short Ah[128][36];
  __shared__ __align__(16) short Al[128][36];
  __shared__ __align__(16) short Bsh[256][36];
  __shared__ __align__(16) short Bsl[256][36];
  __shared__ float lnS[2][128];
  __shared__ float lnQ[2][128];
  __shared__ float muS[128];
  __shared__ float rsS[128];

  f32x4 acc[4][8];
  #pragma unroll
  for (int i = 0; i < 4; i++)
    #pragma unroll
    for (int j = 0; j < 8; j++)
      acc[i][j] = (f32x4){0.f, 0.f, 0.f, 0.f};

  int tr = t >> 3, tc = (t & 7) * 4;
  const short* bBase = Bh + (long)t * 32;

  float4 avp[4];
  short8 bhp[4], blp[4];

  auto issueA = [&](int k0) {
    #pragma unroll
    for (int p = 0; p < 4; p++) {
      int gr = row0 + tr + p * 32;
      avp[p] = make_float4(0.f, 0.f, 0.f, 0.f);
      if (gr < M) avp[p] = *(const float4*)&A[aBase + (long)gr * aw + k0 + tc];
    }
  };
  auto issueB = [&](int k0) {
    const short* bs = bBase + ((long)(k0 >> 5) << 13);
    #pragma unroll
    for (int q = 0; q < 4; q++) {
      bhp[q] = *(const short8*)(bs + q * 8);
      blp[q] = *(const short8*)(bs + loD + q * 8);
    }
  };

  issueA(0); issueB(0);
  for (int k0 = 0; k0 < Kd; k0 += 32) {
    #pragma unroll
    for (int p = 0; p < 4; p++) {
      float vv[4] = {avp[p].x, avp[p].y, avp[p].z, avp[p].w};
      s4 h4, l4;
      #pragma unroll
      for (int e = 0; e < 4; e++) {
        short h = f2bf(vv[e]); h4[e] = h; l4[e] = f2bf(vv[e] - bf2f(h));
      }
      *(s4*)&Ah[tr + p * 32][tc] = h4;
      *(s4*)&Al[tr + p * 32][tc] = l4;
    }
    #pragma unroll
    for (int q = 0; q < 4; q++) {
      *(short8*)&Bsh[t][q * 8] = bhp[q];
      *(short8*)&Bsl[t][q * 8] = blp[q];
    }
    if (k0 + 32 < Kd) { issueA(k0 + 32); issueB(k0 + 32); }
    __syncthreads();
    short8 ah[4], al[4];
    #pragma unroll
    for (int i = 0; i < 4; i++) {
      ah[i] = *(const short8*)&Ah[wm * 64 + i * 16 + fi][fq * 8];
      al[i] = *(const short8*)&Al[wm * 64 + i * 16 + fi][fq * 8];
    }
    #pragma unroll
    for (int jh = 0; jh < 2; jh++) {
      short8 bh[4], bl[4];
      #pragma unroll
      for (int j = 0; j < 4; j++) {
        bh[j] = *(const short8*)&Bsh[wn * 128 + (jh * 4 + j) * 16 + fi][fq * 8];
        bl[j] = *(const short8*)&Bsl[wn * 128 + (jh * 4 + j) * 16 + fi][fq * 8];
      }
      #pragma unroll
      for (int i = 0; i < 4; i++)
        #pragma unroll
        for (int j = 0; j < 4; j++) {
          acc[i][jh * 4 + j] = __builtin_amdgcn_mfma_f32_16x16x32_bf16(ah[i], bh[j], acc[i][jh * 4 + j], 0, 0, 0);
          acc[i][jh * 4 + j] = __builtin_amdgcn_mfma_f32_16x16x32_bf16(ah[i], bl[j], acc[i][jh * 4 + j], 0, 0, 0);
          acc[i][jh * 4 + j] = __builtin_amdgcn_mfma_f32_16x16x32_bf16(al[i], bh[j], acc[i][jh * 4 + j], 0, 0, 0);
        }
    }
    __syncthreads();
  }

  if (mode >= 3) {
    #pragma unroll
    for (int i = 0; i < 4; i++)
      #pragma unroll
      for (int reg = 0; reg < 4; reg++) {
        float s = 0.f, q = 0.f;
        #pragma unroll
        for (int j = 0; j < 8; j++) { float v = acc[i][j][reg]; s += v; q += v * v; }
        #pragma unroll
        for (int m = 1; m < 16; m <<= 1) { s += __shfl_xor(s, m, 64); q += __shfl_xor(q, m, 64); }
        if (fi == 0) {
          int row = wm * 64 + i * 16 + fq * 4 + reg;
          lnS[wn][row] = s; lnQ[wn][row] = q;
        }
      }
    __syncthreads();
    if (t < 128) {
      float s = lnS[0][t] + lnS[1][t];
      float q = lnQ[0][t] + lnQ[1][t];
      float m = s * (1.f / 256.f);
      float var = q * (1.f / 256.f) - m * m;
      muS[t] = m; rsS[t] = rsqrtf(var + 1e-5f);
    }
    __syncthreads();
  }

  #pragma unroll
  for (int i = 0; i < 4; i++) {
    #pragma unroll
    for (int reg = 0; reg < 4; reg++) {
      int row = wm * 64 + i * 16 + fq * 4 + reg;
      int gr = row0 + row;
      if (gr >= M) continue;
      #pragma unroll
      for (int j = 0; j < 8; j++) {
        int col = wn * 128 + j * 16 + fi;
        float v = acc[i][j][reg];
        if (mode == 2) { v = (v > 0.f) ? (v + 1.f) : expf(v); C[cBase + (long)gr * 256 + col] = v; }
        else if (mode == 3) { C[cBase + (long)gr * 256 + col] = (v - muS[row]) * rsS[row]; }
        else if (mode == 4) { X[xBase + (long)gr * 256 + col] += (v - muS[row]) * rsS[row]; }
        else { C[cBase + (long)gr * 256 + col] = v; }
      }
    }
  }
}

// ---------------------------------------------------------------------------
// gemm256_seg: N=256, 32x256 tile, packed-only, dense block table.
// 4 waves: wave w covers cols [64w,64w+64), rows 0..31. ~42KB LDS -> 3 blk/CU.
// Kd == aw (256 or 512). modes: 3 LN->C, 4 X += LN.
// ---------------------------------------------------------------------------
__global__ __launch_bounds__(256) void gemm256_seg_kernel(
    const float* __restrict__ A, int aw, const short* __restrict__ Bh, int loD,
    float* __restrict__ C, float* __restrict__ X,
    const int* __restrict__ segOff, const int* __restrict__ segCnt,
    const int2* __restrict__ tab, const int* __restrict__ nTab, int mode)
{
  int y = blockIdx.y;
  if (y >= nTab[0]) return;
  int2 e = tab[y];
  long rb = (long)(e.x & 7) * ARENA + segOff[e.x];
  int cntb = segCnt[e.x];
  int row0 = e.y;
  long aBase = rb * aw, cBase = rb * 256, xBase = rb * 256;

  int t = threadIdx.x;
  int lane = t & 63, w = t >> 6;
  int fi = lane & 15, fq = lane >> 4;

  __shared__ __align__(16) short Ah[32][36];
  __shared__ __align__(16) short Al[32][36];
  __shared__ __align__(16) short Bsh[256][36];
  __shared__ __align__(16) short Bsl[256][36];
  __shared__ float lnS[4][32];
  __shared__ float lnQ[4][32];
  __shared__ float muS[32];
  __shared__ float rsS[32];

  f32x4 acc[2][4];
  #pragma unroll
  for (int i = 0; i < 2; i++)
    #pragma unroll
    for (int j = 0; j < 4; j++)
      acc[i][j] = (f32x4){0.f, 0.f, 0.f, 0.f};

  int tr = t >> 3, tc = (t & 7) * 4;  // tr 0..31
  const short* bBase = Bh + (long)t * 32;

  float4 avp;
  short8 bhp[4], blp[4];

  auto issueA = [&](int k0) {
    avp = *(const float4*)&A[aBase + (long)(row0 + tr) * aw + k0 + tc];
  };
  auto issueB = [&](int k0) {
    const short* bs = bBase + ((long)(k0 >> 5) << 13);
    #pragma unroll
    for (int q = 0; q < 4; q++) {
      bhp[q] = *(const short8*)(bs + q * 8);
      blp[q] = *(const short8*)(bs + loD + q * 8);
    }
  };

  issueA(0); issueB(0);
  for (int k0 = 0; k0 < aw; k0 += 32) {
    {
      float vv[4] = {avp.x, avp.y, avp.z, avp.w};
      s4 h4, l4;
      #pragma unroll
      for (int e2 = 0; e2 < 4; e2++) {
        short h = f2bf(vv[e2]); h4[e2] = h; l4[e2] = f2bf(vv[e2] - bf2f(h));
      }
      *(s4*)&Ah[tr][tc] = h4;
      *(s4*)&Al[tr][tc] = l4;
    }
    #pragma unroll
    for (int q = 0; q < 4; q++) {
      *(short8*)&Bsh[t][q * 8] = bhp[q];
      *(short8*)&Bsl[t][q * 8] = blp[q];
    }
    if (k0 + 32 < aw) { issueA(k0 + 32); issueB(k0 + 32); }
    __syncthreads();
    short8 ah[2], al[2];
    #pragma unroll
    for (int i = 0; i < 2; i++) {
      ah[i] = *(const short8*)&Ah[i * 16 + fi][fq * 8];
      al[i] = *(const short8*)&Al[i * 16 + fi][fq * 8];
    }
    #pragma unroll
    for (int j = 0; j < 4; j++) {
      short8 bh = *(const short8*)&Bsh[w * 64 + j * 16 + fi][fq * 8];
      short8 bl = *(const short8*)&Bsl[w * 64 + j * 16 + fi][fq * 8];
      #pragma unroll
      for (int i = 0; i < 2; i++) {
        acc[i][j] = __builtin_amdgcn_mfma_f32_16x16x32_bf16(ah[i], bh, acc[i][j], 0, 0, 0);
        acc[i][j] = __builtin_amdgcn_mfma_f32_16x16x32_bf16(ah[i], bl, acc[i][j], 0, 0, 0);
        acc[i][j] = __builtin_amdgcn_mfma_f32_16x16x32_bf16(al[i], bh, acc[i][j], 0, 0, 0);
      }
    }
    __syncthreads();
  }

  if (mode >= 3) {
    #pragma unroll
    for (int i = 0; i < 2; i++)
      #pragma unroll
      for (int reg = 0; reg < 4; reg++) {
        float s = 0.f, q = 0.f;
        #pragma unroll
        for (int j = 0; j < 4; j++) { float v = acc[i][j][reg]; s += v; q += v * v; }
        #pragma unroll
        for (int m = 1; m < 16; m <<= 1) { s += __shfl_xor(s, m, 64); q += __shfl_xor(q, m, 64); }
        if (fi == 0) {
          int row = i * 16 + fq * 4 + reg;
          lnS[w][row] = s; lnQ[w][row] = q;
        }
      }
    __syncthreads();
    if (t < 32) {
      float s = lnS[0][t] + lnS[1][t] + lnS[2][t] + lnS[3][t];
      float q = lnQ[0][t] + lnQ[1][t] + lnQ[2][t] + lnQ[3][t];
      float m = s * (1.f / 256.f);
      float var = q * (1.f / 256.f) - m * m;
      muS[t] = m; rsS[t] = rsqrtf(var + 1e-5f);
    }
    __syncthreads();
  }

  #pragma unroll
  for (int i = 0; i < 2; i++) {
    #pragma unroll
    for (int reg = 0; reg < 4; reg++) {
      int row = i * 16 + fq * 4 + reg;
      int gr = row0 + row;
      if (gr >= cntb) continue;
      #pragma unroll
      for (int j = 0; j < 4; j++) {
        int col = w * 64 + j * 16 + fi;
        float v = acc[i][j][reg];
        if (mode == 3) { C[cBase + (long)gr * 256 + col] = (v - muS[row]) * rsS[row]; }
        else if (mode == 4) { X[xBase + (long)gr * 256 + col] += (v - muS[row]) * rsS[row]; }
        else if (mode == 2) { v = (v > 0.f) ? (v + 1.f) : expf(v); C[cBase + (long)gr * 256 + col] = v; }
        else { C[cBase + (long)gr * 256 + col] = v; }
      }
    }
  }
}

// ---------------------------------------------------------------------------
// fp32-B MFMA GEMM (dmatrix only).
// ---------------------------------------------------------------------------
__global__ __launch_bounds__(256) void gemm_f32b_kernel(
    const float* __restrict__ A, const float* __restrict__ B, float* __restrict__ C,
    int M, int N, int Kd, long sA, long sB, long sC, float alpha)
{
  int b = blockIdx.z;
  const float* Ab = A + (long)b * sA;
  const float* Bb = B + (long)b * sB;
  float* Cb = C + (long)b * sC;
  int row0 = blockIdx.y * 128, col0 = blockIdx.x * 128;
  int t = threadIdx.x;
  int lane = t & 63, wid = t >> 6, wm = wid >> 1, wn = wid & 1;
  int fi = lane & 15, fq = lane >> 4;
  __shared__ __align__(16) short Ah[128][36];
  __shared__ __align__(16) short Al[128][36];
  __shared__ __align__(16) short Bsh[128][36];
  __shared__ __align__(16) short Bsl[128][36];
  f32x4 acc[4][4];
  #pragma unroll
  for (int i = 0; i < 4; i++)
    #pragma unroll
    for (int j = 0; j < 4; j++)
      acc[i][j] = (f32x4){0.f, 0.f, 0.f, 0.f};
  int tr = t >> 3, tc = (t & 7) * 4;
  int bn = (t & 31) * 4, bk = t >> 5;
  for (int k0 = 0; k0 < Kd; k0 += 32) {
    #pragma unroll
    for (int p = 0; p < 4; p++) {
      int r = tr + p * 32, gr = row0 + r;
      float4 v = make_float4(0.f, 0.f, 0.f, 0.f);
      if (gr < M) v = *(const float4*)&Ab[(long)gr * Kd + k0 + tc];
      float vv[4] = {v.x, v.y, v.z, v.w};
      #pragma unroll
      for (int e = 0; e < 4; e++) {
        short h = f2bf(vv[e]); Ah[r][tc + e] = h; Al[r][tc + e] = f2bf(vv[e] - bf2f(h));
      }
    }
    #pragma unroll
    for (int p = 0; p < 4; p++) {
      int kk = bk + p * 8;
      long gkN = (long)(k0 + kk) * N;
      #pragma unroll
      for (int e = 0; e < 4; e++) {
        int gc = col0 + bn + e;
        float v = (gc < N) ? Bb[gkN + gc] : 0.f;
        short h = f2bf(v); Bsh[bn + e][kk] = h; Bsl[bn + e][kk] = f2bf(v - bf2f(h));
      }
    }
    __syncthreads();
    short8 ah[4], al[4], bh[4], bl[4];
    #pragma unroll
    for (int i = 0; i < 4; i++) {
      ah[i] = *(const short8*)&Ah[wm * 64 + i * 16 + fi][fq * 8];
      al[i] = *(const short8*)&Al[wm * 64 + i * 16 + fi][fq * 8];
    }
    #pragma unroll
    for (int j = 0; j < 4; j++) {
      bh[j] = *(const short8*)&Bsh[wn * 64 + j * 16 + fi][fq * 8];
      bl[j] = *(const short8*)&Bsl[wn * 64 + j * 16 + fi][fq * 8];
    }
    #pragma unroll
    for (int i = 0; i < 4; i++)
      #pragma unroll
      for (int j = 0; j < 4; j++) {
        acc[i][j] = __builtin_amdgcn_mfma_f32_16x16x32_bf16(ah[i], bh[j], acc[i][j], 0, 0, 0);
        acc[i][j] = __builtin_amdgcn_mfma_f32_16x16x32_bf16(ah[i], bl[j], acc[i][j], 0, 0, 0);
        acc[i][j] = __builtin_amdgcn_mfma_f32_16x16x32_bf16(al[i], bh[j], acc[i][j], 0, 0, 0);
      }
    __syncthreads();
  }
  #pragma unroll
  for (int i = 0; i < 4; i++) {
    #pragma unroll
    for (int reg = 0; reg < 4; reg++) {
      int gr = row0 + wm * 64 + i * 16 + fq * 4 + reg;
      if (gr >= M) continue;
      #pragma unroll
      for (int j = 0; j < 4; j++) {
        int gc = col0 + wn * 64 + j * 16 + fi;
        if (gc < N) Cb[(long)gr * N + gc] = acc[i][j][reg] * alpha;
      }
    }
  }
}

// ---------------------------------------------------------------------------
__device__ __forceinline__ float2 blk_sum2_256(float a, float b)
{
  __shared__ float sa[4], sb[4];
  int lane = threadIdx.x & 63, w = threadIdx.x >> 6;
  #pragma unroll
  for (int off = 32; off > 0; off >>= 1) { a += __shfl_down(a, off, 64); b += __shfl_down(b, off, 64); }
  if (lane == 0) { sa[w] = a; sb[w] = b; }
  __syncthreads();
  float ra = sa[0] + sa[1] + sa[2] + sa[3];
  float rb = sb[0] + sb[1] + sb[2] + sb[3];
  __syncthreads();
  return make_float2(ra, rb);
}

__global__ void cvt2_kernel(float* dst, const float* s0, const float* s1, long n) {
  long i = (long)blockIdx.x * 256 + threadIdx.x;
  if (i < n) dst[i] = s0[i];
  else if (i < 2 * n) dst[i] = s1[i - n];
}

__global__ void bcast_seeds_kernel(float* seeds, const float* st) {
  long i = (long)blockIdx.x * 256 + threadIdx.x;
  if (i < 4L * 25600) seeds[i] = st[i % 25600];
}

// KV[s,h,d,e] = / += sum_r K*V*inv_s ; Ksum[s,h,d] = / += sum_r K.
__global__ __launch_bounds__(1024) void kv_kernel(
    const float* __restrict__ Kb, const float* __restrict__ Vb,
    float* __restrict__ KV, float* __restrict__ Ksum,
    int s_len, float inv_s, int bmask, int bxor,
    const int* __restrict__ segOff, const int* __restrict__ segCnt,
    int axor, int gmin, int gmax, int chunk)
{
  int s = blockIdx.x, h = blockIdx.y;
  long srcBase; int slim;
  if (segOff) {
    int g = s & 7;
    if (g < gmin || g > gmax) return;
    int src = s ^ axor;
    srcBase = (long)(src & 7) * ARENA + segOff[src];
    slim = segCnt[src];
  } else {
    srcBase = (long)s * s_len;
    slim = s_len;
  }
  bool direct = (gridDim.z == 1);
  int s0b = blockIdx.z * chunk;
  int send = min(s0b + chunk, slim);
  __shared__ float Kt[32][33];
  __shared__ float Vt[32][33];
  int tx = threadIdx.x, ty = threadIdx.y;
  float acc = 0.f, ks = 0.f;
  for (int s0 = s0b; s0 < send; s0 += 32) {
    int sr = s0 + ty;
    float kvv = 0.f, vvv = 0.f;
    if (sr < send) {
      long base = (srcBase + sr) * 256 + h * 32 + tx;
      kvv = Kb[base]; vvv = Vb[base];
    }
    Kt[ty][tx] = kvv; Vt[ty][tx] = vvv;
    __syncthreads();
    #pragma unroll
    for (int j = 0; j < 32; j++) acc += Kt[j][ty] * Vt[j][tx];
    if (tx == 0) {
      #pragma unroll
      for (int j = 0; j < 32; j++) ks += Kt[j][ty];
    }
    __syncthreads();
  }
  if (direct) {
    KV[((s * 8 + h) * 32 + ty) * 32 + tx] = acc * inv_s;
    if (tx == 0) Ksum[s * 256 + h * 32 + ty] = ks;
  } else {
    if (s0b >= send) return;
    atomicAdd(&KV[((s * 8 + h) * 32 + ty) * 32 + tx], acc * inv_s);
    if (tx == 0) atomicAdd(&Ksum[s * 256 + h * 32 + ty], ks);
  }
}

// msg = (Q·KV) * Z * s_scale ; Z = 1/(Q·Ksum + 1e-6).
__global__ __launch_bounds__(256) void zmsg_kernel(
    const float* __restrict__ Q, const float* __restrict__ KV,
    const float* __restrict__ Ksum, float* __restrict__ msg, int l, float s_scale,
    const int* __restrict__ segOff, const int* __restrict__ segCnt, int gmin, int gmax)
{
  int s = blockIdx.x;
  long rowBase; int cb;
  if (segOff) {
    int g = s & 7;
    if (g < gmin || g > gmax) return;
    rowBase = (long)g * ARENA + segOff[s];
    cb = segCnt[s];
  } else {
    rowBase = (long)s * l;
    cb = l;
  }
  int r0 = blockIdx.y * 32;
  if (r0 >= cb) return;
  int t = threadIdx.x;
  __shared__ float KVs[8192];
  __shared__ float QL[256];
  __shared__ float Zl[8];
  for (int i = t; i < 8192; i += 256) KVs[i] = KV[s * 8192 + i];
  float Ks = Ksum[s * 256 + t];
  __syncthreads();
  int h = t >> 5, e = t & 31;
  for (int rr = 0; rr < 32; rr++) {
    int row = r0 + rr;
    if (row >= cb) break;
    long base = (rowBase + row) * 256;
    QL[t] = Q[base + t];
    __syncthreads();
    float p = QL[t] * Ks;
    #pragma unroll
    for (int off = 16; off > 0; off >>= 1) p += __shfl_down(p, off, 32);
    if (e == 0) Zl[h] = 1.f / (p + 1e-6f);
    __syncthreads();
    float acc = 0.f;
    const float* kvh = KVs + h * 1024;
    #pragma unroll
    for (int d = 0; d < 32; d++) acc += QL[h * 32 + d] * kvh[d * 32 + e];
    msg[base + t] = acc * Zl[h] * s_scale;
    __syncthreads();
  }
}

// ---------------- topic pipeline (R5: parallel build + LDS post) ----------
// tm_build: TM[n][m][l] = floor(dot(t0[:,m], t1[:,l]) / 16). Block (n,m),
// 128 threads: t0 column staged in LDS; t1 rows read coalesced across lanes.
__global__ void tm_build_kernel(const float* __restrict__ t0,
                                const float* __restrict__ t1, float* __restrict__ tm) {
  int n = blockIdx.x, m = blockIdx.y, l = threadIdx.x;
  __shared__ float t0s[96];
  if (l < 96) t0s[l] = t0[(n * 96 + l) * 100 + m];
  __syncthreads();
  if (l >= 100) return;
  float acc = 0.f;
  #pragma unroll 4
  for (int d = 0; d < 96; d++)
    acc += t0s[d] * t1[(n * 96 + d) * 100 + l];
  tm[(n * 100 + m) * 100 + l] = floorf(acc * 0.0625f);
}

// tm_post: load TM into LDS, col/row softmax stats + per-row argmax of
// softmax(col)*softmax(row). First-max tie-break (matches jnp.argmax).
__global__ __launch_bounds__(256) void tm_post_kernel(const float* __restrict__ tm,
                                                      int* __restrict__ tmidx) {
  int n = blockIdx.x, t = threadIdx.x;
  __shared__ float TM[100][100];
  __shared__ float cmax[100], csum[100], rmax[100], rsum[100];
  for (int i = t; i < 10000; i += 256) TM[i / 100][i % 100] = tm[n * 10000 + i];
  __syncthreads();
  if (t < 100) {
    int l = t;
    float mx = -1e30f;
    for (int m = 0; m < 100; m++) mx = fmaxf(mx, TM[m][l]);
    float s = 0.f;
    for (int m = 0; m < 100; m++) s += expf(TM[m][l] - mx);
    cmax[l] = mx; csum[l] = s;
    int m = t;
    float mx2 = -1e30f;
    for (int l2 = 0; l2 < 100; l2++) mx2 = fmaxf(mx2, TM[m][l2]);
    float s2 = 0.f;
    for (int l2 = 0; l2 < 100; l2++) s2 += expf(TM[m][l2] - mx2);
    rmax[m] = mx2; rsum[m] = s2;
  }
  __syncthreads();
  if (t < 100) {
    int m = t;
    float best = -1e30f; int bi = 0;
    for (int l = 0; l < 100; l++) {
      float x = TM[m][l];
      float v = (expf(x - cmax[l]) / csum[l]) * (expf(x - rmax[m]) / rsum[m]);
      if (v > best) { best = v; bi = l; }
    }
    tmidx[n * 100 + m] = bi;
  }
}

// seedsF: adaptive-pool(seeds,160) ++ topicp (inline) -> LN -> transposed sT.
__global__ void seedsF_kernel(const float* __restrict__ seeds,
                              const float* __restrict__ t0raw,
                              const float* __restrict__ t1raw,
                              const int* __restrict__ tmidx, float* __restrict__ sT) {
  int n = blockIdx.x, k = blockIdx.y, t = threadIdx.x;
  float v;
  if (t < 160) {
    int s = (t * 256) / 160;
    int e = ((t + 1) * 256 + 159) / 160;
    float a = 0.f;
    for (int i = s; i < e; i++) a += seeds[(n * 100 + k) * 256 + i];
    v = a / (float)(e - s);
  } else {
    int j = t - 160;
    int g = tmidx[300 + k];
    float a, b;
    if (j < 48) {
      a = t0raw[(n * 96 + 2 * j) * 100 + k];
      b = t0raw[(n * 96 + 2 * j + 1) * 100 + k];
    } else {
      int d0 = 2 * j - 96;
      a = t1raw[(n * 96 + d0) * 100 + g];
      b = t1raw[(n * 96 + d0 + 1) * 100 + g];
    }
    v = 0.5f * (a + b);
  }
  float2 r = blk_sum2_256(v, v * v);
  float m = r.x * (1.f / 256.f);
  float var = r.y * (1.f / 256.f) - m * m;
  sT[n * 25600 + t * 100 + k] = (v - m) * rsqrtf(var + 1e-5f);
}

// ---------------- dmatrix post ----------------
__global__ void softmax_rows_kernel(const float* dm, float* prob, int* amax) {
  long row = blockIdx.x; int t = threadIdx.x;
  __shared__ float red[128]; __shared__ int ri[128];
  float v = (t < 100) ? dm[row * 100 + t] : -1e30f;
  red[t] = v; ri[t] = t; __syncthreads();
  for (int off = 64; off > 0; off >>= 1) {
    if (t < off) {
      if (red[t + off] > red[t] || (red[t + off] == red[t] && ri[t + off] < ri[t])) {
        red[t] = red[t + off]; ri[t] = ri[t + off];
      }
    }
    __syncthreads();
  }
  float mx = red[0];
  if (t == 0) amax[row] = ri[0];
  __syncthreads();
  float e = (t < 100) ? expf(v - mx) : 0.f;
  red[t] = e; __syncthreads();
  for (int off = 64; off > 0; off >>= 1) { if (t < off) red[t] += red[t + off]; __syncthreads(); }
  float s = red[0];
  if (t < 100) prob[row * 100 + t] = e / s;
}

__global__ void colsum_kernel(const float* prob, float* cs0, float* cs1) {
  int k = blockIdx.x, n = blockIdx.y, half = blockIdx.z;
  int t = threadIdx.x;
  const float* p = prob + ((long)n * 8192 + half * 4096) * 100 + k;
  float s = 0.f;
  for (int m = t; m < 4096; m += 256) s += p[(long)m * 100];
  float2 r = blk_sum2_256(s, 0.f);
  if (t == 0) (half ? cs1 : cs0)[n * 100 + k] = r.x;
}

__global__ void topk_kernel(const float* cs0, const float* cs1, int* inds) {
  int n = blockIdx.x, t = threadIdx.x;
  __shared__ float rv[128]; __shared__ int ri[128]; __shared__ int sbest;
  float base = (t < 100) ? cs0[n * 100 + t] * cs1[n * 100 + t] : -1.f;
  for (int kk = 0; kk < 6; kk++) {
    rv[t] = base; ri[t] = t; __syncthreads();
    for (int off = 64; off > 0; off >>= 1) {
      if (t < off) {
        if (rv[t + off] > rv[t] || (rv[t + off] == rv[t] && ri[t + off] < ri[t])) { rv[t] = rv[t + off]; ri[t] = ri[t + off]; }
      }
      __syncthreads();
    }
    if (t == 0) { inds[n * 6 + kk] = ri[0]; sbest = ri[0]; }
    __syncthreads();
    if (t == sbest) base = -1.f;
    __syncthreads();
  }
}

// ---------------- packed sample machinery ----------------
__global__ __launch_bounds__(1024) void count_kernel(const int* amax, const int* inds, int* segCnt) {
  int seg = blockIdx.x;
  int kk = seg >> 3, g = seg & 7, n = g & 3, half = g >> 2;
  int target = inds[n * 6 + kk];
  const int* am = amax + n * 8192 + half * 4096;
  int t = threadIdx.x;
  int lc = 0;
  #pragma unroll
  for (int j = 0; j < 4; j++) lc += (am[t * 4 + j] == target) ? 1 : 0;
  __shared__ int red[16];
  #pragma unroll
  for (int off = 32; off > 0; off >>= 1) lc += __shfl_down(lc, off, 64);
  if ((t & 63) == 0) red[t >> 6] = lc;
  __syncthreads();
  if (t == 0) {
    int s = 0;
    for (int w = 0; w < 16; w++) s += red[w];
    segCnt[seg] = s;
  }
}

// offs: segment offsets + cond flags + DENSE BLOCK TABLES.
__global__ void offs_kernel(const int* segCnt, int* segOff, float* condf,
                            int* tabCnt,
                            int2* t128_07, int2* t128_03, int2* t128_47,
                            int2* t32_07, int2* t32_03, int2* t32_47) {
  int t = threadIdx.x;
  if (t < 8) {
    int run = 0;
    for (int kk = 0; kk < 6; kk++) {
      segOff[kk * 8 + t] = run;
      run += (segCnt[kk * 8 + t] + 127) & ~127;
    }
  }
  if (t >= 8 && t < 14) {
    int kk = t - 8;
    int a = 0, b = 0;
    for (int g = 0; g < 4; g++) { a += segCnt[kk * 8 + g]; b += segCnt[kk * 8 + 4 + g]; }
    condf[kk] = (a > 0 && b > 0) ? 1.f : 0.f;
  }
  __syncthreads();
  __shared__ int pref[48];
  int2* tabs[6] = {t128_07, t128_03, t128_47, t32_07, t32_03, t32_47};
  for (int tb = 0; tb < 6; tb++) {
    int tile = (tb < 3) ? 128 : 32;
    int r = tb % 3;
    int nb = 0;
    if (t < 48) {
      int g = t & 7;
      bool in = (r == 0) || (r == 1 && g < 4) || (r == 2 && g >= 4);
      if (in) nb = (min(segCnt[t], 4096) + tile - 1) / tile;
      pref[t] = nb;
    }
    __syncthreads();
    for (int o = 1; o < 48; o <<= 1) {
      int v = 0;
      if (t < 48 && t >= o) v = pref[t - o];
      __syncthreads();
      if (t < 48) pref[t] += v;
      __syncthreads();
    }
    if (t < 48 && nb > 0) {
      int st = pref[t] - nb;
      for (int j = 0; j < nb; j++) tabs[tb][st + j] = make_int2(t, j * tile);
    }
    if (t == 0) tabCnt[tb] = pref[47];
    __syncthreads();
  }
}

// ord: stable compaction order + direct gather of packed rows.
__global__ __launch_bounds__(1024) void ord_kernel(const int* amax, const int* inds,
                                                   const int* segOff, int* ordP,
                                                   float* __restrict__ nf,
                                                   const float* __restrict__ f01) {
  int seg = blockIdx.x;
  int kk = seg >> 3, g = seg & 7, n = g & 3, half = g >> 2;
  int target = inds[n * 6 + kk];
  const int* am = amax + n * 8192 + half * 4096;
  int t = threadIdx.x;
  __shared__ int ts[1024];
  int f[4]; int lc = 0;
  #pragma unroll
  for (int j = 0; j < 4; j++) { f[j] = (am[t * 4 + j] == target) ? 1 : 0; lc += f[j]; }
  ts[t] = lc; __syncthreads();
  for (int off = 1; off < 1024; off <<= 1) {
    int add = (t >= off) ? ts[t - off] : 0;
    __syncthreads();
    ts[t] += add;
    __syncthreads();
  }
  int run = (t == 0) ? 0 : ts[t - 1];
  long base = (long)g * ARENA + segOff[seg];
  int* o = ordP + base;
  #pragma unroll
  for (int j = 0; j < 4; j++) {
    if (f[j]) {
      int tok = t * 4 + j;
      o[run] = tok;
      const float4* s4p = (const float4*)&f01[((long)g * 4096 + tok) * 256];
      float4* d4p = (float4*)&nf[(base + run) * 256];
      for (int c = 0; c < 64; c++) d4p[c] = s4p[c];
      run++;
    }
  }
}

// R5: blockIdx.x = seg (spreads active blocks across XCDs; was y-major with
// only x=0 active -> idx = 32*seg == 0 mod 8 -> all on XCD 0).
__global__ void scatter_kernel(float* up, const float* nf, const int* ordP,
                               const int* segOff, const int* segCnt, const float* condf) {
  int seg = blockIdx.x;
  int kk = seg >> 3, g = seg & 7;
  int cntb = segCnt[seg];
  int row0 = blockIdx.y * 128;
  if (row0 >= cntb) return;
  long base = (long)g * ARENA + segOff[seg];
  float cf = condf[kk];
  int t = threadIdx.x;
  int c4 = (t & 63) * 4, rr = t >> 6;
  for (int p = 0; p < 32; p++) {
    int r = row0 + p * 4 + rr;
    if (r >= cntb) break;
    int tok = ordP[base + r];
    float4 add = *(const float4*)&nf[(base + r) * 256 + c4];
    float4* dst = (float4*)&up[((long)g * 4096 + tok) * 256 + c4];
    float4 cur = *dst;
    cur.x += add.x * cf; cur.y += add.y * cf; cur.z += add.z * cf; cur.w += add.w * cf;
    *dst = cur;
  }
}

// up01 aliases out's feat region (index-identical); in-place RMW.
__global__ void final_mix_kernel(const float* f01, float* out_up, const int* amax,
                                 const int* inds) {
  int b = blockIdx.y, half = b >> 2, n = b & 3;
  int l = blockIdx.x, c = threadIdx.x;
  int a = amax[n * 8192 + half * 4096 + l];
  const int* in_ = inds + n * 6;
  bool member = (a == in_[0]) | (a == in_[1]) | (a == in_[2]) | (a == in_[3]) | (a == in_[4]) | (a == in_[5]);
  long idx = ((long)b * 4096 + l) * 256 + c;
  float up = out_up[idx];
  out_up[idx] = (member ? 0.f : 1.f) * f01[idx] + up;
}

__global__ void tmi_kernel(const float* dmat, float* out) {
  int n = blockIdx.y, half = blockIdx.z;
  long i = (long)blockIdx.x * 256 + threadIdx.x;
  const float* dm = dmat + (long)n * 819200 + (long)half * 409600;
  int a = (int)(i / 100), b = (int)(i % 100);
  int y = a >> 6, x = a & 63;
  float sum = 0.f;
  for (int dy = -1; dy <= 1; dy++) {
    int yy = y + dy; if (yy < 0 || yy >= 64) continue;
    for (int dx = -1; dx <= 1; dx++) {
      int xc = x + dx; if (xc < 0 || xc >= 64) continue;
      sum += dm[b * 4096 + yy * 64 + xc];
    }
  }
  out[8388608L + (long)half * 1638400 + (long)n * 409600 + i] = dm[i] * (sum * (1.f / 9.f));
}

// ---------------------------------------------------------------------------
extern "C" void kernel_launch(void* const* d_in, const int* in_sizes, int n_in,
                              void* d_out, int out_size, void* d_ws, size_t ws_size,
                              hipStream_t stream)
{
  (void)in_sizes; (void)n_in; (void)out_size; (void)ws_size;
  const float* feat0_in = (const float*)d_in[0];
  const float* feat1_in = (const float*)d_in[1];
  const float* topic0 = (const float*)d_in[2];
  const float* topic1 = (const float*)d_in[3];
  const float* seed_tokens = (const float*)d_in[4];
  const float* Wq = (const float*)d_in[5];
  const float* Wk = (const float*)d_in[6];
  const float* Wv = (const float*)d_in[7];
  const float* Wm = (const float*)d_in[8];
  const float* W1 = (const float*)d_in[9];
  const float* W2 = (const float*)d_in[10];
  float* out = (float*)d_out;

  float* base = (float*)d_ws;
  long off = 0;
  auto alloc = [&](long n) -> float* { float* p = base + off; off += (n + 255) & ~255L; return p; };
  float* f01   = alloc(8388608);          // [8][4096][256]
  float* qb    = alloc(8L * ARENA * 256); // Q / LN(msg2)
  float* kb    = alloc(8L * ARENA * 256); // K / msg / h1 low   (kb,vb contiguous)
  float* vb    = alloc(8L * ARENA * 256); // V / h1 high
  float* nf    = alloc(8L * ARENA * 256); // packed sample tokens
  float* seeds = alloc(102400);
  float* kvks  = alloc(48 * 8192 + 48 * 256);
  float* dmat  = alloc(3276800);
  short* wbuf  = (short*)alloc(5242880);
  float* tmb   = alloc(40000);
  float* sT    = alloc(102400);
  float* cs0   = alloc(400);
  float* cs1   = alloc(400);
  float* condf = alloc(256);
  int* tmidx  = (int*)alloc(400);
  int* amax   = (int*)alloc(32768);
  int* inds   = (int*)alloc(256);
  int* segCnt = (int*)alloc(256);
  int* segOffA= (int*)alloc(256);
  int* ordP   = (int*)alloc(8L * ARENA);
  int* tabCnt = (int*)alloc(64);
  int2* T128_07 = (int2*)alloc(640);
  int2* T128_03 = (int2*)alloc(320);
  int2* T128_47 = (int2*)alloc(320);
  int2* T32_07  = (int2*)alloc(2176);
  int2* T32_03  = (int2*)alloc(1088);
  int2* T32_47  = (int2*)alloc(1088);
  float* up01 = out;                      // aliases out's feat region

  const int m128[3] = {304, 152, 152};
  const int m32[3]  = {1072, 536, 536};
  int2* T128[3] = {T128_07, T128_03, T128_47};
  int2* T32[3]  = {T32_07, T32_03, T32_47};

  auto WOFF = [](int l) -> long { return (long)l * 1310720; };

  auto gmainZ = [&](const float* A, const float* A2, int aw, long wOff, int loD,
                    float* c0, float* c1, float* c2, int M, int Kd, int Ntot, int outW,
                    long sA_, long sC_, int bm, int bx,
                    int m0, int m1, int m2_, int nb) {
    dim3 g(Ntot / 128, (M + 127) / 128, nb), blk(256);
    gemm_main_kernel<<<g, blk, 0, stream>>>(A, A2, aw, wbuf + wOff, loD, c0, c1, c2,
        M, Kd, outW, sA_, sC_, bm, bx, nullptr, nullptr,
        nullptr, nullptr, nullptr, 0, 0, m0, m1, m2_);
  };
  auto gmainP = [&](const float* A, const float* A2, int aw, long wOff, int loD,
                    float* c0, float* c1, float* c2, int Kd, int Ntot, int outW,
                    int rQ, int rKV, int m0, int m1, int m2_) {
    int ymax = max(m128[rQ], m128[rKV]);
    dim3 g(Ntot / 128, ymax, 1), blk(256);
    gemm_main_kernel<<<g, blk, 0, stream>>>(A, A2, aw, wbuf + wOff, loD, c0, c1, c2,
        4096, Kd, outW, 0, 0, 0, 0, segOffA, segCnt,
        T128[rQ], T128[rKV], tabCnt, rQ, rKV, m0, m1, m2_);
  };
  auto g256Z = [&](const float* A, int aw, long wOff, int loD, float* C, float* X,
                   int M, int Kd, long sA_, long sC_, long sX_, int bm, int bx,
                   int mode, int nb) {
    dim3 g(1, (M + 127) / 128, nb), blk(256);
    gemm256_kernel<<<g, blk, 0, stream>>>(A, aw, wbuf + wOff, loD, C, X,
        M, Kd, sA_, sC_, sX_, bm, bx, mode);
  };
  auto g256P = [&](const float* A, int aw, long wOff, int loD, float* C, float* X,
                   int r, int mode) {
    dim3 g(1, m32[r], 1), blk(256);
    gemm256_seg_kernel<<<g, blk, 0, stream>>>(A, aw, wbuf + wOff, loD, C, X,
        segOffA, segCnt, T32[r], tabCnt + 3 + r, mode);
  };

  auto encTailZ = [&](float* x, int l, int s_len, float s_scale, int layer, int nb,
                      long sAx, int bmKV, int bxKV, int nch) {
    if (nch > 1)
      hipMemsetAsync(kvks, 0, (48 * 8192 + 48 * 256) * sizeof(float), stream);
    int chunk = (s_len + nch - 1) / nch;
    kv_kernel<<<dim3(nb, 8, nch), dim3(32, 32), 0, stream>>>(
        kb, vb, kvks, kvks + 48 * 8192, s_len, 1.f / s_scale, bmKV, bxKV,
        nullptr, nullptr, 0, 0, 7, chunk);
    zmsg_kernel<<<dim3(nb, (l + 31) / 32), 256, 0, stream>>>(
        qb, kvks, kvks + 48 * 8192, kb, l, s_scale, nullptr, nullptr, 0, 7);
    g256Z(kb, 256, WOFF(layer) + 393216, 65536, qb, nullptr,
          l, 256, sAx, sAx, 0, 7, 0, 3, nb);
    gmainZ(x, qb, 256, WOFF(layer) + 524288, 262144, kb, nullptr, nullptr,
           l, 512, 512, 512, sAx, sAx * 2, 7, 0, 1, 0, 0, nb);
    g256Z(kb, 512, WOFF(layer) + 1048576, 131072, nullptr, x,
          l, 512, sAx * 2, 0, sAx, 7, 0, 4, nb);
  };
  auto encTailP = [&](float* x, float s_scale, int layer, int r, int axor,
                      int gmin, int gmax) {
    kv_kernel<<<dim3(48, 8, 1), dim3(32, 32), 0, stream>>>(
        kb, vb, kvks, kvks + 48 * 8192, 4096, 1.f / s_scale, 0, 0,
        segOffA, segCnt, axor, gmin, gmax, 4096);
    zmsg_kernel<<<dim3(48, 128), 256, 0, stream>>>(
        qb, kvks, kvks + 48 * 8192, kb, 4096, s_scale, segOffA, segCnt, gmin, gmax);
    g256P(kb, 256, WOFF(layer) + 393216, 65536, qb, nullptr, r, 3);
    gmainP(x, qb, 256, WOFF(layer) + 524288, 262144, kb, nullptr, nullptr,
           512, 512, 512, r, r, 1, 0, 0);
    g256P(kb, 512, WOFF(layer) + 1048576, 131072, nullptr, x, r, 4);
  };

  // ---- init ----
  cvt2_kernel<<<32768, 256, 0, stream>>>(f01, feat0_in, feat1_in, 4194304);
  bcast_seeds_kernel<<<400, 256, 0, stream>>>(seeds, seed_tokens);
  prep_w_kernel<<<20480, 256, 0, stream>>>(Wq, Wk, Wv, Wm, W1, W2, wbuf);

  // ---- topic pipeline ----
  tm_build_kernel<<<dim3(4, 100), 128, 0, stream>>>(topic0, topic1, tmb);
  tm_post_kernel<<<4, 256, 0, stream>>>(tmb, tmidx);

  // ---- main encoder layers ----
  auto encSeedLayer = [&](int layer) {
    g256Z(seeds, 256, WOFF(layer), 196608, qb, nullptr,
          100, 256, 25600, 25600, 0, 7, 0, 2, 4);
    gmainZ(feat0_in, nullptr, 256, WOFF(layer) + 65536, 196608, kb, vb, nullptr,
           4096, 256, 512, 256, 1048576, 2097152, 7, 0, 2, 0, 0, 4);
    gmainZ(feat1_in, nullptr, 256, WOFF(layer) + 65536, 196608, kb + 1048576, vb + 1048576, nullptr,
           4096, 256, 512, 256, 1048576, 2097152, 7, 0, 2, 0, 0, 4);
    encTailZ(seeds, 100, 8192, 8192.f, layer, 4, 25600, 7, 0, 8);
  };
  auto encFeatLayer = [&](int layer) {
    g256Z(f01, 256, WOFF(layer), 196608, qb, nullptr,
          4096, 256, 1048576, 1048576, 0, 7, 0, 2, 8);
    gmainZ(seeds, nullptr, 256, WOFF(layer) + 65536, 196608, kb, vb, nullptr,
           100, 256, 512, 256, 25600, 25600, 3, 0, 2, 0, 0, 8);
    encTailZ(f01, 4096, 100, 100.f, layer, 8, 1048576, 7, 0, 1);
  };

  encSeedLayer(0);
  encFeatLayer(1);
  encSeedLayer(2);
  encFeatLayer(3);

  // ---- seeds final + dmatrix ----
  seedsF_kernel<<<dim3(4, 100), 256, 0, stream>>>(seeds, topic0, topic1, tmidx, sT);
  {
    dim3 g(1, 32, 4), blk(256);
    gemm_f32b_kernel<<<g, blk, 0, stream>>>(feat0_in, sT, dmat, 4096, 100, 256, 1048576, 25600, 819200, 0.0625f);
    gemm_f32b_kernel<<<g, blk, 0, stream>>>(feat1_in, sT, dmat + 409600, 4096, 100, 256, 1048576, 25600, 819200, 0.0625f);
  }
  float* prob = kb;
  softmax_rows_kernel<<<32768, 128, 0, stream>>>(dmat, prob, amax);
  colsum_kernel<<<dim3(100, 4, 2), 256, 0, stream>>>(prob, cs0, cs1);
  topk_kernel<<<4, 128, 0, stream>>>(cs0, cs1, inds);

  hipMemsetAsync(up01, 0, 8388608 * sizeof(float), stream);

  // ---- sample phase: 48 packed segments, table-driven GEMMs ----
  count_kernel<<<48, 1024, 0, stream>>>(amax, inds, segCnt);
  offs_kernel<<<1, 64, 0, stream>>>(segCnt, segOffA, condf, tabCnt,
                                    T128_07, T128_03, T128_47, T32_07, T32_03, T32_47);
  ord_kernel<<<48, 1024, 0, stream>>>(amax, inds, segOffA, ordP, nf, f01);

  for (int idt = 0; idt < 2; idt++) {
    int wA = 4 + idt * 2, wB = wA + 1;
    gmainP(nf, nullptr, 256, WOFF(wA), 196608, qb, kb, vb,
           256, 768, 256, 0, 0, 2, 2, 0);
    encTailP(nf, 4096.f, wA, 0, 0, 0, 7);
    gmainP(nf, nullptr, 256, WOFF(wB), 196608, qb, kb, vb,
           256, 768, 256, 1, 2, 2, 2, 0);
    encTailP(nf, 4096.f, wB, 1, 4, 0, 3);
    gmainP(nf, nullptr, 256, WOFF(wB), 196608, qb, kb, vb,
           256, 768, 256, 2, 1, 2, 2, 0);
    encTailP(nf, 4096.f, wB, 2, 4, 4, 7);
  }
  scatter_kernel<<<dim3(48, 32), 256, 0, stream>>>(up01, nf, ordP, segOffA, segCnt, condf);

  // ---- outputs ----
  final_mix_kernel<<<dim3(4096, 8), 256, 0, stream>>>(f01, up01, amax, inds);
  tmi_kernel<<<dim3(1600, 4, 2), 256, 0, stream>>>(dmat, out);
}

// Round 7
// 2392.209 us; speedup vs baseline: 2.2338x; 1.0278x over previous
//
#include <hip/hip_runtime.h>
#include <math.h>

// N=4, L=S=4096, C=256, K=100, NHEAD=8, D=32. FP32 I/O.
// Big GEMMs: bf16x3 split MFMA (hi*hi + hi*lo + lo*hi, fp32 acc) ~ fp32 fidelity.
// Sample loop batched into 48 packed segments (6 samples x 8 batch-halves),
// 128-aligned inside an [8][4864]-row arena.
// R1: panel-major weights (256-col groups of [k/32][n&255][32]); depth-1 prefetch.
// R2: wB Q fused into K/V gmain; zmsg 32 rows/block; softmax+argmax fused.
// R3: kv direct-store; seedsF folds topicp+transpose; ord folds gather.
// R4: packed GEMMs via device-built dense block tables (fix block->XCD
//     aliasing: active idx % 8 == 0 put everything on XCD 0). 5343 -> 2609us.
// R5: tm_all split into tm_build + tm_post; scatter grid transposed. -> 2459us.
// R6: tmi was top dispatch (82us, 10% BW): neighbor reads dm[b*4096+...] put
//     consecutive lanes 16KB apart (64 lines/wave-load x9). tmi2 stages 3
//     y-rows x 50 topics in LDS (P[50][3][66], pad->4-way max), coalesced
//     loads + contiguous center/out. colsum same disease (400B-stride lanes):
//     colsum2 reads rows contiguously, reg-accumulates, 1 atomic/k.

typedef __attribute__((ext_vector_type(8))) short short8;
typedef __attribute__((ext_vector_type(4))) short s4;
typedef __attribute__((ext_vector_type(4))) float f32x4;

#define ARENA 4864  // rows per g in packed arena (4096 + 6*128 alignment pad)

__device__ __forceinline__ short f2bf(float f) {
  unsigned u = __float_as_uint(f);
  return (short)((u + 0x7FFFu + ((u >> 16) & 1u)) >> 16);
}
__device__ __forceinline__ float bf2f(short s) {
  return __uint_as_float(((unsigned)(unsigned short)s) << 16);
}

// ---------------------------------------------------------------------------
// Weight prep: per layer L, panel-major bf16 hi/lo planes.
// Layout per matrix: 256-col groups; group g holds cols [g*256,(g+1)*256);
// within group: panel p = k/32 (8192 shorts each); within panel: (n&255)*32+(k&31).
// Per-layer stride 1310720 shorts:
//   +0       QKV [768][256] hi (Wq group0, Wk group1, Wv group2), lo +196608
//   +393216  Wm  [256][256] hi, lo +65536
//   +524288  W1  [512][512] hi (2 groups of 131072), lo +262144
//   +1048576 W2  [256][512] hi, lo +131072
// ---------------------------------------------------------------------------
__global__ void prep_w_kernel(const float* __restrict__ Wq, const float* __restrict__ Wk,
                              const float* __restrict__ Wv, const float* __restrict__ Wm,
                              const float* __restrict__ W1, const float* __restrict__ W2,
                              short* __restrict__ wb) {
  long i = (long)blockIdx.x * 256 + threadIdx.x;
  if (i >= 8L * 655360) return;
  int L = (int)(i / 655360);
  int r = (int)(i % 655360);
  long base = (long)L * 1310720;
  float v; long dhi; int loD;
  if (r < 196608) {
    int n = r >> 8, k = r & 255;
    const float* s = (n < 256) ? (Wq + (long)L * 65536)
                   : (n < 512) ? (Wk + (long)L * 65536) : (Wv + (long)L * 65536);
    v = s[k * 256 + (n & 255)];
    dhi = base + ((long)(n >> 8) << 16) + ((long)(k >> 5) << 13) + ((n & 255) << 5) + (k & 31);
    loD = 196608;
  } else if (r < 262144) {
    int j = r - 196608; int n = j >> 8, k = j & 255;
    v = Wm[(long)L * 65536 + k * 256 + n];
    dhi = base + 393216 + ((long)(k >> 5) << 13) + (n << 5) + (k & 31);
    loD = 65536;
  } else if (r < 524288) {
    int j = r - 262144; int n = j >> 9, k = j & 511;
    v = W1[(long)L * 262144 + (long)k * 512 + n];
    dhi = base + 524288 + ((long)(n >> 8) << 17) + ((long)(k >> 5) << 13) + ((n & 255) << 5) + (k & 31);
    loD = 262144;
  } else {
    int j = r - 524288; int n = j >> 9, k = j & 511;
    v = W2[(long)L * 131072 + (long)k * 256 + n];
    dhi = base + 1048576 + ((long)(k >> 5) << 13) + (n << 5) + (k & 31);
    loD = 131072;
  }
  short h = f2bf(v);
  wb[dhi] = h;
  wb[dhi + loD] = f2bf(v - bf2f(h));
}

// ---------------------------------------------------------------------------
// gemm_main: 128x128 tiles. Plain-batch (z-grid) OR packed via dense block
// table (grid.y indexes (seg,row0); sel==0 -> tabQ, sel>=1 -> tabKV).
// modes: 0 none, 1 relu, 2 elu(x)+1.
// ---------------------------------------------------------------------------
__global__ __launch_bounds__(256) void gemm_main_kernel(
    const float* __restrict__ A, const float* __restrict__ A2, int aw,
    const short* __restrict__ Bh, int loD,
    float* __restrict__ C0, float* __restrict__ C1, float* __restrict__ C2,
    int M, int Kd, int outW, long sA, long sC,
    int bmask, int bxor,
    const int* __restrict__ segOff, const int* __restrict__ segCnt,
    const int2* __restrict__ tabQ, const int2* __restrict__ tabKV,
    const int* __restrict__ tabCnt, int tQ, int tKV,
    int mode0, int mode1, int mode2)
{
  int colg = blockIdx.x * 128;
  int sel = colg / outW;
  long aBase, cBase; int cntb, row0;
  if (tabQ) {
    const int2* tab = (sel == 0) ? tabQ : tabKV;
    int n = tabCnt[(sel == 0) ? tQ : tKV];
    int y = blockIdx.y;
    if (y >= n) return;
    int2 e = tab[y];
    long rb = (long)(e.x & 7) * ARENA + segOff[e.x];
    aBase = rb * aw; cBase = rb * (long)outW;
    cntb = segCnt[e.x];
    row0 = e.y;
  } else {
    int z = blockIdx.z;
    int ab = (z & bmask) ^ bxor;
    aBase = (long)ab * sA; cBase = (long)z * sC;
    cntb = M;
    row0 = blockIdx.y * 128;
    if (row0 >= cntb) return;
  }
  float* Cb = (sel == 0 ? C0 : (sel == 1 ? C1 : C2)) + cBase;
  int mode = (sel == 0 ? mode0 : (sel == 1 ? mode1 : mode2));
  int colo = colg % outW;

  int t = threadIdx.x;
  int lane = t & 63, wid = t >> 6, wm = wid >> 1, wn = wid & 1;
  int fi = lane & 15, fq = lane >> 4;

  __shared__ __align__(16) short Ah[128][36];
  __shared__ __align__(16) short Al[128][36];
  __shared__ __align__(16) short Bsh[128][36];
  __shared__ __align__(16) short Bsl[128][36];

  f32x4 acc[4][4];
  #pragma unroll
  for (int i = 0; i < 4; i++)
    #pragma unroll
    for (int j = 0; j < 4; j++)
      acc[i][j] = (f32x4){0.f, 0.f, 0.f, 0.f};

  int tr = t >> 3, tc = (t & 7) * 4;
  int nc = t >> 1, kh = (t & 1) * 16;
  int gb = colg >> 8;
  int cg = (colg & 255) + nc;
  const short* bBase = Bh + (long)gb * ((long)Kd << 8) + (long)cg * 32 + kh;

  float4 avp[4];
  short8 bhp[2], blp[2];

  auto issueA = [&](int k0) {
    bool useA2 = (A2 != nullptr) && (k0 >= 256);
    const float* Asrc = useA2 ? A2 : A;
    int kcol = useA2 ? (k0 - 256) : k0;
    #pragma unroll
    for (int p = 0; p < 4; p++) {
      int gr = row0 + tr + p * 32;
      avp[p] = make_float4(0.f, 0.f, 0.f, 0.f);
      if (gr < M) avp[p] = *(const float4*)&Asrc[aBase + (long)gr * aw + kcol + tc];
    }
  };
  auto issueB = [&](int k0) {
    const short* bs = bBase + ((long)(k0 >> 5) << 13);
    bhp[0] = *(const short8*)bs;
    bhp[1] = *(const short8*)(bs + 8);
    blp[0] = *(const short8*)(bs + loD);
    blp[1] = *(const short8*)(bs + loD + 8);
  };

  issueA(0); issueB(0);
  for (int k0 = 0; k0 < Kd; k0 += 32) {
    #pragma unroll
    for (int p = 0; p < 4; p++) {
      float vv[4] = {avp[p].x, avp[p].y, avp[p].z, avp[p].w};
      s4 h4, l4;
      #pragma unroll
      for (int e = 0; e < 4; e++) {
        short h = f2bf(vv[e]); h4[e] = h; l4[e] = f2bf(vv[e] - bf2f(h));
      }
      *(s4*)&Ah[tr + p * 32][tc] = h4;
      *(s4*)&Al[tr + p * 32][tc] = l4;
    }
    *(short8*)&Bsh[nc][kh]     = bhp[0];
    *(short8*)&Bsh[nc][kh + 8] = bhp[1];
    *(short8*)&Bsl[nc][kh]     = blp[0];
    *(short8*)&Bsl[nc][kh + 8] = blp[1];
    if (k0 + 32 < Kd) { issueA(k0 + 32); issueB(k0 + 32); }
    __syncthreads();
    short8 ah[4], al[4], bh[4], bl[4];
    #pragma unroll
    for (int i = 0; i < 4; i++) {
      ah[i] = *(const short8*)&Ah[wm * 64 + i * 16 + fi][fq * 8];
      al[i] = *(const short8*)&Al[wm * 64 + i * 16 + fi][fq * 8];
    }
    #pragma unroll
    for (int j = 0; j < 4; j++) {
      bh[j] = *(const short8*)&Bsh[wn * 64 + j * 16 + fi][fq * 8];
      bl[j] = *(const short8*)&Bsl[wn * 64 + j * 16 + fi][fq * 8];
    }
    #pragma unroll
    for (int i = 0; i < 4; i++)
      #pragma unroll
      for (int j = 0; j < 4; j++) {
        acc[i][j] = __builtin_amdgcn_mfma_f32_16x16x32_bf16(ah[i], bh[j], acc[i][j], 0, 0, 0);
        acc[i][j] = __builtin_amdgcn_mfma_f32_16x16x32_bf16(ah[i], bl[j], acc[i][j], 0, 0, 0);
        acc[i][j] = __builtin_amdgcn_mfma_f32_16x16x32_bf16(al[i], bh[j], acc[i][j], 0, 0, 0);
      }
    __syncthreads();
  }
  #pragma unroll
  for (int i = 0; i < 4; i++) {
    #pragma unroll
    for (int reg = 0; reg < 4; reg++) {
      int gr = row0 + wm * 64 + i * 16 + fq * 4 + reg;
      if (gr >= M || gr >= cntb) continue;
      #pragma unroll
      for (int j = 0; j < 4; j++) {
        int cc = colo + wn * 64 + j * 16 + fi;
        float v = acc[i][j][reg];
        if (mode == 1) { if (v < 0.f) v = 0.f; }
        else if (mode == 2) { v = (v > 0.f) ? (v + 1.f) : expf(v); }
        Cb[(long)gr * outW + cc] = v;
      }
    }
  }
}

// ---------------------------------------------------------------------------
// gemm256: N=256, 128x256 tile, PLAIN batch only. modes: 0 none, 2 elu+1,
// 3 LN->C, 4 X += LN.
// ---------------------------------------------------------------------------
__global__ __launch_bounds__(256) void gemm256_kernel(
    const float* __restrict__ A, int aw, const short* __restrict__ Bh, int loD,
    float* __restrict__ C, float* __restrict__ X,
    int M, int Kd, long sA, long sC, long sX,
    int bmask, int bxor, int mode)
{
  int z = blockIdx.z;
  int ab = (z & bmask) ^ bxor;
  long aBase = (long)ab * sA, cBase = (long)z * sC, xBase = (long)ab * sX;
  int row0 = blockIdx.y * 128;
  if (row0 >= M) return;

  int t = threadIdx.x;
  int lane = t & 63, wid = t >> 6, wm = wid >> 1, wn = wid & 1;
  int fi = lane & 15, fq = lane >> 4;

  __shared__ __align__(16) short Ah[128][36];
  __shared__ __align__(16) short Al[128][36];
  __shared__ __align__(16) short Bsh[256][36];
  __shared__ __align__(16) short Bsl[256][36];
  __shared__ float lnS[2][128];
  __shared__ float lnQ[2][128];
  __shared__ float muS[128];
  __shared__ float rsS[128];

  f32x4 acc[4][8];
  #pragma unroll
  for (int i = 0; i < 4; i++)
    #pragma unroll
    for (int j = 0; j < 8; j++)
      acc[i][j] = (f32x4){0.f, 0.f, 0.f, 0.f};

  int tr = t >> 3, tc = (t & 7) * 4;
  const short* bBase = Bh + (long)t * 32;

  float4 avp[4];
  short8 bhp[4], blp[4];

  auto issueA = [&](int k0) {
    #pragma unroll
    for (int p = 0; p < 4; p++) {
      int gr = row0 + tr + p * 32;
      avp[p] = make_float4(0.f, 0.f, 0.f, 0.f);
      if (gr < M) avp[p] = *(const float4*)&A[aBase + (long)gr * aw + k0 + tc];
    }
  };
  auto issueB = [&](int k0) {
    const short* bs = bBase + ((long)(k0 >> 5) << 13);
    #pragma unroll
    for (int q = 0; q < 4; q++) {
      bhp[q] = *(const short8*)(bs + q * 8);
      blp[q] = *(const short8*)(bs + loD + q * 8);
    }
  };

  issueA(0); issueB(0);
  for (int k0 = 0; k0 < Kd; k0 += 32) {
    #pragma unroll
    for (int p = 0; p < 4; p++) {
      float vv[4] = {avp[p].x, avp[p].y, avp[p].z, avp[p].w};
      s4 h4, l4;
      #pragma unroll
      for (int e = 0; e < 4; e++) {
        short h = f2bf(vv[e]); h4[e] = h; l4[e] = f2bf(vv[e] - bf2f(h));
      }
      *(s4*)&Ah[tr + p * 32][tc] = h4;
      *(s4*)&Al[tr + p * 32][tc] = l4;
    }
    #pragma unroll
    for (int q = 0; q < 4; q++) {
      *(short8*)&Bsh[t][q * 8] = bhp[q];
      *(short8*)&Bsl[t][q * 8] = blp[q];
    }
    if (k0 + 32 < Kd) { issueA(k0 + 32); issueB(k0 + 32); }
    __syncthreads();
    short8 ah[4], al[4];
    #pragma unroll
    for (int i = 0; i < 4; i++) {
      ah[i] = *(const short8*)&Ah[wm * 64 + i * 16 + fi][fq * 8];
      al[i] = *(const short8*)&Al[wm * 64 + i * 16 + fi][fq * 8];
    }
    #pragma unroll
    for (int jh = 0; jh < 2; jh++) {
      short8 bh[4], bl[4];
      #pragma unroll
      for (int j = 0; j < 4; j++) {
        bh[j] = *(const short8*)&Bsh[wn * 128 + (jh * 4 + j) * 16 + fi][fq * 8];
        bl[j] = *(const short8*)&Bsl[wn * 128 + (jh * 4 + j) * 16 + fi][fq * 8];
      }
      #pragma unroll
      for (int i = 0; i < 4; i++)
        #pragma unroll
        for (int j = 0; j < 4; j++) {
          acc[i][jh * 4 + j] = __builtin_amdgcn_mfma_f32_16x16x32_bf16(ah[i], bh[j], acc[i][jh * 4 + j], 0, 0, 0);
          acc[i][jh * 4 + j] = __builtin_amdgcn_mfma_f32_16x16x32_bf16(ah[i], bl[j], acc[i][jh * 4 + j], 0, 0, 0);
          acc[i][jh * 4 + j] = __builtin_amdgcn_mfma_f32_16x16x32_bf16(al[i], bh[j], acc[i][jh * 4 + j], 0, 0, 0);
        }
    }
    __syncthreads();
  }

  if (mode >= 3) {
    #pragma unroll
    for (int i = 0; i < 4; i++)
      #pragma unroll
      for (int reg = 0; reg < 4; reg++) {
        float s = 0.f, q = 0.f;
        #pragma unroll
        for (int j = 0; j < 8; j++) { float v = acc[i][j][reg]; s += v; q += v * v; }
        #pragma unroll
        for (int m = 1; m < 16; m <<= 1) { s += __shfl_xor(s, m, 64); q += __shfl_xor(q, m, 64); }
        if (fi == 0) {
          int row = wm * 64 + i * 16 + fq * 4 + reg;
          lnS[wn][row] = s; lnQ[wn][row] = q;
        }
      }
    __syncthreads();
    if (t < 128) {
      float s = lnS[0][t] + lnS[1][t];
      float q = lnQ[0][t] + lnQ[1][t];
      float m = s * (1.f / 256.f);
      float var = q * (1.f / 256.f) - m * m;
      muS[t] = m; rsS[t] = rsqrtf(var + 1e-5f);
    }
    __syncthreads();
  }

  #pragma unroll
  for (int i = 0; i < 4; i++) {
    #pragma unroll
    for (int reg = 0; reg < 4; reg++) {
      int row = wm * 64 + i * 16 + fq * 4 + reg;
      int gr = row0 + row;
      if (gr >= M) continue;
      #pragma unroll
      for (int j = 0; j < 8; j++) {
        int col = wn * 128 + j * 16 + fi;
        float v = acc[i][j][reg];
        if (mode == 2) { v = (v > 0.f) ? (v + 1.f) : expf(v); C[cBase + (long)gr * 256 + col] = v; }
        else if (mode == 3) { C[cBase + (long)gr * 256 + col] = (v - muS[row]) * rsS[row]; }
        else if (mode == 4) { X[xBase + (long)gr * 256 + col] += (v - muS[row]) * rsS[row]; }
        else { C[cBase + (long)gr * 256 + col] = v; }
      }
    }
  }
}

// ---------------------------------------------------------------------------
// gemm256_seg: N=256, 32x256 tile, packed-only, dense block table.
// 4 waves: wave w covers cols [64w,64w+64), rows 0..31. ~42KB LDS -> 3 blk/CU.
// Kd == aw (256 or 512). modes: 3 LN->C, 4 X += LN.
// ---------------------------------------------------------------------------
__global__ __launch_bounds__(256) void gemm256_seg_kernel(
    const float* __restrict__ A, int aw, const short* __restrict__ Bh, int loD,
    float* __restrict__ C, float* __restrict__ X,
    const int* __restrict__ segOff, const int* __restrict__ segCnt,
    const int2* __restrict__ tab, const int* __restrict__ nTab, int mode)
{
  int y = blockIdx.y;
  if (y >= nTab[0]) return;
  int2 e = tab[y];
  long rb = (long)(e.x & 7) * ARENA + segOff[e.x];
  int cntb = segCnt[e.x];
  int row0 = e.y;
  long aBase = rb * aw, cBase = rb * 256, xBase = rb * 256;

  int t = threadIdx.x;
  int lane = t & 63, w = t >> 6;
  int fi = lane & 15, fq = lane >> 4;

  __shared__ __align__(16) short Ah[32][36];
  __shared__ __align__(16) short Al[32][36];
  __shared__ __align__(16) short Bsh[256][36];
  __shared__ __align__(16) short Bsl[256][36];
  __shared__ float lnS[4][32];
  __shared__ float lnQ[4][32];
  __shared__ float muS[32];
  __shared__ float rsS[32];

  f32x4 acc[2][4];
  #pragma unroll
  for (int i = 0; i < 2; i++)
    #pragma unroll
    for (int j = 0; j < 4; j++)
      acc[i][j] = (f32x4){0.f, 0.f, 0.f, 0.f};

  int tr = t >> 3, tc = (t & 7) * 4;  // tr 0..31
  const short* bBase = Bh + (long)t * 32;

  float4 avp;
  short8 bhp[4], blp[4];

  auto issueA = [&](int k0) {
    avp = *(const float4*)&A[aBase + (long)(row0 + tr) * aw + k0 + tc];
  };
  auto issueB = [&](int k0) {
    const short* bs = bBase + ((long)(k0 >> 5) << 13);
    #pragma unroll
    for (int q = 0; q < 4; q++) {
      bhp[q] = *(const short8*)(bs + q * 8);
      blp[q] = *(const short8*)(bs + loD + q * 8);
    }
  };

  issueA(0); issueB(0);
  for (int k0 = 0; k0 < aw; k0 += 32) {
    {
      float vv[4] = {avp.x, avp.y, avp.z, avp.w};
      s4 h4, l4;
      #pragma unroll
      for (int e2 = 0; e2 < 4; e2++) {
        short h = f2bf(vv[e2]); h4[e2] = h; l4[e2] = f2bf(vv[e2] - bf2f(h));
      }
      *(s4*)&Ah[tr][tc] = h4;
      *(s4*)&Al[tr][tc] = l4;
    }
    #pragma unroll
    for (int q = 0; q < 4; q++) {
      *(short8*)&Bsh[t][q * 8] = bhp[q];
      *(short8*)&Bsl[t][q * 8] = blp[q];
    }
    if (k0 + 32 < aw) { issueA(k0 + 32); issueB(k0 + 32); }
    __syncthreads();
    short8 ah[2], al[2];
    #pragma unroll
    for (int i = 0; i < 2; i++) {
      ah[i] = *(const short8*)&Ah[i * 16 + fi][fq * 8];
      al[i] = *(const short8*)&Al[i * 16 + fi][fq * 8];
    }
    #pragma unroll
    for (int j = 0; j < 4; j++) {
      short8 bh = *(const short8*)&Bsh[w * 64 + j * 16 + fi][fq * 8];
      short8 bl = *(const short8*)&Bsl[w * 64 + j * 16 + fi][fq * 8];
      #pragma unroll
      for (int i = 0; i < 2; i++) {
        acc[i][j] = __builtin_amdgcn_mfma_f32_16x16x32_bf16(ah[i], bh, acc[i][j], 0, 0, 0);
        acc[i][j] = __builtin_amdgcn_mfma_f32_16x16x32_bf16(ah[i], bl, acc[i][j], 0, 0, 0);
        acc[i][j] = __builtin_amdgcn_mfma_f32_16x16x32_bf16(al[i], bh, acc[i][j], 0, 0, 0);
      }
    }
    __syncthreads();
  }

  if (mode >= 3) {
    #pragma unroll
    for (int i = 0; i < 2; i++)
      #pragma unroll
      for (int reg = 0; reg < 4; reg++) {
        float s = 0.f, q = 0.f;
        #pragma unroll
        for (int j = 0; j < 4; j++) { float v = acc[i][j][reg]; s += v; q += v * v; }
        #pragma unroll
        for (int m = 1; m < 16; m <<= 1) { s += __shfl_xor(s, m, 64); q += __shfl_xor(q, m, 64); }
        if (fi == 0) {
          int row = i * 16 + fq * 4 + reg;
          lnS[w][row] = s; lnQ[w][row] = q;
        }
      }
    __syncthreads();
    if (t < 32) {
      float s = lnS[0][t] + lnS[1][t] + lnS[2][t] + lnS[3][t];
      float q = lnQ[0][t] + lnQ[1][t] + lnQ[2][t] + lnQ[3][t];
      float m = s * (1.f / 256.f);
      float var = q * (1.f / 256.f) - m * m;
      muS[t] = m; rsS[t] = rsqrtf(var + 1e-5f);
    }
    __syncthreads();
  }

  #pragma unroll
  for (int i = 0; i < 2; i++) {
    #pragma unroll
    for (int reg = 0; reg < 4; reg++) {
      int row = i * 16 + fq * 4 + reg;
      int gr = row0 + row;
      if (gr >= cntb) continue;
      #pragma unroll
      for (int j = 0; j < 4; j++) {
        int col = w * 64 + j * 16 + fi;
        float v = acc[i][j][reg];
        if (mode == 3) { C[cBase + (long)gr * 256 + col] = (v - muS[row]) * rsS[row]; }
        else if (mode == 4) { X[xBase + (long)gr * 256 + col] += (v - muS[row]) * rsS[row]; }
        else if (mode == 2) { v = (v > 0.f) ? (v + 1.f) : expf(v); C[cBase + (long)gr * 256 + col] = v; }
        else { C[cBase + (long)gr * 256 + col] = v; }
      }
    }
  }
}

// ---------------------------------------------------------------------------
// fp32-B MFMA GEMM (dmatrix only).
// ---------------------------------------------------------------------------
__global__ __launch_bounds__(256) void gemm_f32b_kernel(
    const float* __restrict__ A, const float* __restrict__ B, float* __restrict__ C,
    int M, int N, int Kd, long sA, long sB, long sC, float alpha)
{
  int b = blockIdx.z;
  const float* Ab = A + (long)b * sA;
  const float* Bb = B + (long)b * sB;
  float* Cb = C + (long)b * sC;
  int row0 = blockIdx.y * 128, col0 = blockIdx.x * 128;
  int t = threadIdx.x;
  int lane = t & 63, wid = t >> 6, wm = wid >> 1, wn = wid & 1;
  int fi = lane & 15, fq = lane >> 4;
  __shared__ __align__(16) short Ah[128][36];
  __shared__ __align__(16) short Al[128][36];
  __shared__ __align__(16) short Bsh[128][36];
  __shared__ __align__(16) short Bsl[128][36];
  f32x4 acc[4][4];
  #pragma unroll
  for (int i = 0; i < 4; i++)
    #pragma unroll
    for (int j = 0; j < 4; j++)
      acc[i][j] = (f32x4){0.f, 0.f, 0.f, 0.f};
  int tr = t >> 3, tc = (t & 7) * 4;
  int bn = (t & 31) * 4, bk = t >> 5;
  for (int k0 = 0; k0 < Kd; k0 += 32) {
    #pragma unroll
    for (int p = 0; p < 4; p++) {
      int r = tr + p * 32, gr = row0 + r;
      float4 v = make_float4(0.f, 0.f, 0.f, 0.f);
      if (gr < M) v = *(const float4*)&Ab[(long)gr * Kd + k0 + tc];
      float vv[4] = {v.x, v.y, v.z, v.w};
      #pragma unroll
      for (int e = 0; e < 4; e++) {
        short h = f2bf(vv[e]); Ah[r][tc + e] = h; Al[r][tc + e] = f2bf(vv[e] - bf2f(h));
      }
    }
    #pragma unroll
    for (int p = 0; p < 4; p++) {
      int kk = bk + p * 8;
      long gkN = (long)(k0 + kk) * N;
      #pragma unroll
      for (int e = 0; e < 4; e++) {
        int gc = col0 + bn + e;
        float v = (gc < N) ? Bb[gkN + gc] : 0.f;
        short h = f2bf(v); Bsh[bn + e][kk] = h; Bsl[bn + e][kk] = f2bf(v - bf2f(h));
      }
    }
    __syncthreads();
    short8 ah[4], al[4], bh[4], bl[4];
    #pragma unroll
    for (int i = 0; i < 4; i++) {
      ah[i] = *(const short8*)&Ah[wm * 64 + i * 16 + fi][fq * 8];
      al[i] = *(const short8*)&Al[wm * 64 + i * 16 + fi][fq * 8];
    }
    #pragma unroll
    for (int j = 0; j < 4; j++) {
      bh[j] = *(const short8*)&Bsh[wn * 64 + j * 16 + fi][fq * 8];
      bl[j] = *(const short8*)&Bsl[wn * 64 + j * 16 + fi][fq * 8];
    }
    #pragma unroll
    for (int i = 0; i < 4; i++)
      #pragma unroll
      for (int j = 0; j < 4; j++) {
        acc[i][j] = __builtin_amdgcn_mfma_f32_16x16x32_bf16(ah[i], bh[j], acc[i][j], 0, 0, 0);
        acc[i][j] = __builtin_amdgcn_mfma_f32_16x16x32_bf16(ah[i], bl[j], acc[i][j], 0, 0, 0);
        acc[i][j] = __builtin_amdgcn_mfma_f32_16x16x32_bf16(al[i], bh[j], acc[i][j], 0, 0, 0);
      }
    __syncthreads();
  }
  #pragma unroll
  for (int i = 0; i < 4; i++) {
    #pragma unroll
    for (int reg = 0; reg < 4; reg++) {
      int gr = row0 + wm * 64 + i * 16 + fq * 4 + reg;
      if (gr >= M) continue;
      #pragma unroll
      for (int j = 0; j < 4; j++) {
        int gc = col0 + wn * 64 + j * 16 + fi;
        if (gc < N) Cb[(long)gr * N + gc] = acc[i][j][reg] * alpha;
      }
    }
  }
}

// ---------------------------------------------------------------------------
__device__ __forceinline__ float2 blk_sum2_256(float a, float b)
{
  __shared__ float sa[4], sb[4];
  int lane = threadIdx.x & 63, w = threadIdx.x >> 6;
  #pragma unroll
  for (int off = 32; off > 0; off >>= 1) { a += __shfl_down(a, off, 64); b += __shfl_down(b, off, 64); }
  if (lane == 0) { sa[w] = a; sb[w] = b; }
  __syncthreads();
  float ra = sa[0] + sa[1] + sa[2] + sa[3];
  float rb = sb[0] + sb[1] + sb[2] + sb[3];
  __syncthreads();
  return make_float2(ra, rb);
}

__global__ void cvt2_kernel(float* dst, const float* s0, const float* s1, long n) {
  long i = (long)blockIdx.x * 256 + threadIdx.x;
  if (i < n) dst[i] = s0[i];
  else if (i < 2 * n) dst[i] = s1[i - n];
}

__global__ void bcast_seeds_kernel(float* seeds, const float* st) {
  long i = (long)blockIdx.x * 256 + threadIdx.x;
  if (i < 4L * 25600) seeds[i] = st[i % 25600];
}

// KV[s,h,d,e] = / += sum_r K*V*inv_s ; Ksum[s,h,d] = / += sum_r K.
__global__ __launch_bounds__(1024) void kv_kernel(
    const float* __restrict__ Kb, const float* __restrict__ Vb,
    float* __restrict__ KV, float* __restrict__ Ksum,
    int s_len, float inv_s, int bmask, int bxor,
    const int* __restrict__ segOff, const int* __restrict__ segCnt,
    int axor, int gmin, int gmax, int chunk)
{
  int s = blockIdx.x, h = blockIdx.y;
  long srcBase; int slim;
  if (segOff) {
    int g = s & 7;
    if (g < gmin || g > gmax) return;
    int src = s ^ axor;
    srcBase = (long)(src & 7) * ARENA + segOff[src];
    slim = segCnt[src];
  } else {
    srcBase = (long)s * s_len;
    slim = s_len;
  }
  bool direct = (gridDim.z == 1);
  int s0b = blockIdx.z * chunk;
  int send = min(s0b + chunk, slim);
  __shared__ float Kt[32][33];
  __shared__ float Vt[32][33];
  int tx = threadIdx.x, ty = threadIdx.y;
  float acc = 0.f, ks = 0.f;
  for (int s0 = s0b; s0 < send; s0 += 32) {
    int sr = s0 + ty;
    float kvv = 0.f, vvv = 0.f;
    if (sr < send) {
      long base = (srcBase + sr) * 256 + h * 32 + tx;
      kvv = Kb[base]; vvv = Vb[base];
    }
    Kt[ty][tx] = kvv; Vt[ty][tx] = vvv;
    __syncthreads();
    #pragma unroll
    for (int j = 0; j < 32; j++) acc += Kt[j][ty] * Vt[j][tx];
    if (tx == 0) {
      #pragma unroll
      for (int j = 0; j < 32; j++) ks += Kt[j][ty];
    }
    __syncthreads();
  }
  if (direct) {
    KV[((s * 8 + h) * 32 + ty) * 32 + tx] = acc * inv_s;
    if (tx == 0) Ksum[s * 256 + h * 32 + ty] = ks;
  } else {
    if (s0b >= send) return;
    atomicAdd(&KV[((s * 8 + h) * 32 + ty) * 32 + tx], acc * inv_s);
    if (tx == 0) atomicAdd(&Ksum[s * 256 + h * 32 + ty], ks);
  }
}

// msg = (Q·KV) * Z * s_scale ; Z = 1/(Q·Ksum + 1e-6).
__global__ __launch_bounds__(256) void zmsg_kernel(
    const float* __restrict__ Q, const float* __restrict__ KV,
    const float* __restrict__ Ksum, float* __restrict__ msg, int l, float s_scale,
    const int* __restrict__ segOff, const int* __restrict__ segCnt, int gmin, int gmax)
{
  int s = blockIdx.x;
  long rowBase; int cb;
  if (segOff) {
    int g = s & 7;
    if (g < gmin || g > gmax) return;
    rowBase = (long)g * ARENA + segOff[s];
    cb = segCnt[s];
  } else {
    rowBase = (long)s * l;
    cb = l;
  }
  int r0 = blockIdx.y * 32;
  if (r0 >= cb) return;
  int t = threadIdx.x;
  __shared__ float KVs[8192];
  __shared__ float QL[256];
  __shared__ float Zl[8];
  for (int i = t; i < 8192; i += 256) KVs[i] = KV[s * 8192 + i];
  float Ks = Ksum[s * 256 + t];
  __syncthreads();
  int h = t >> 5, e = t & 31;
  for (int rr = 0; rr < 32; rr++) {
    int row = r0 + rr;
    if (row >= cb) break;
    long base = (rowBase + row) * 256;
    QL[t] = Q[base + t];
    __syncthreads();
    float p = QL[t] * Ks;
    #pragma unroll
    for (int off = 16; off > 0; off >>= 1) p += __shfl_down(p, off, 32);
    if (e == 0) Zl[h] = 1.f / (p + 1e-6f);
    __syncthreads();
    float acc = 0.f;
    const float* kvh = KVs + h * 1024;
    #pragma unroll
    for (int d = 0; d < 32; d++) acc += QL[h * 32 + d] * kvh[d * 32 + e];
    msg[base + t] = acc * Zl[h] * s_scale;
    __syncthreads();
  }
}

// ---------------- topic pipeline ----------
__global__ void tm_build_kernel(const float* __restrict__ t0,
                                const float* __restrict__ t1, float* __restrict__ tm) {
  int n = blockIdx.x, m = blockIdx.y, l = threadIdx.x;
  __shared__ float t0s[96];
  if (l < 96) t0s[l] = t0[(n * 96 + l) * 100 + m];
  __syncthreads();
  if (l >= 100) return;
  float acc = 0.f;
  #pragma unroll 4
  for (int d = 0; d < 96; d++)
    acc += t0s[d] * t1[(n * 96 + d) * 100 + l];
  tm[(n * 100 + m) * 100 + l] = floorf(acc * 0.0625f);
}

__global__ __launch_bounds__(256) void tm_post_kernel(const float* __restrict__ tm,
                                                      int* __restrict__ tmidx) {
  int n = blockIdx.x, t = threadIdx.x;
  __shared__ float TM[100][100];
  __shared__ float cmax[100], csum[100], rmax[100], rsum[100];
  for (int i = t; i < 10000; i += 256) TM[i / 100][i % 100] = tm[n * 10000 + i];
  __syncthreads();
  if (t < 100) {
    int l = t;
    float mx = -1e30f;
    for (int m = 0; m < 100; m++) mx = fmaxf(mx, TM[m][l]);
    float s = 0.f;
    for (int m = 0; m < 100; m++) s += expf(TM[m][l] - mx);
    cmax[l] = mx; csum[l] = s;
    int m = t;
    float mx2 = -1e30f;
    for (int l2 = 0; l2 < 100; l2++) mx2 = fmaxf(mx2, TM[m][l2]);
    float s2 = 0.f;
    for (int l2 = 0; l2 < 100; l2++) s2 += expf(TM[m][l2] - mx2);
    rmax[m] = mx2; rsum[m] = s2;
  }
  __syncthreads();
  if (t < 100) {
    int m = t;
    float best = -1e30f; int bi = 0;
    for (int l = 0; l < 100; l++) {
      float x = TM[m][l];
      float v = (expf(x - cmax[l]) / csum[l]) * (expf(x - rmax[m]) / rsum[m]);
      if (v > best) { best = v; bi = l; }
    }
    tmidx[n * 100 + m] = bi;
  }
}

// seedsF: adaptive-pool(seeds,160) ++ topicp (inline) -> LN -> transposed sT.
__global__ void seedsF_kernel(const float* __restrict__ seeds,
                              const float* __restrict__ t0raw,
                              const float* __restrict__ t1raw,
                              const int* __restrict__ tmidx, float* __restrict__ sT) {
  int n = blockIdx.x, k = blockIdx.y, t = threadIdx.x;
  float v;
  if (t < 160) {
    int s = (t * 256) / 160;
    int e = ((t + 1) * 256 + 159) / 160;
    float a = 0.f;
    for (int i = s; i < e; i++) a += seeds[(n * 100 + k) * 256 + i];
    v = a / (float)(e - s);
  } else {
    int j = t - 160;
    int g = tmidx[300 + k];
    float a, b;
    if (j < 48) {
      a = t0raw[(n * 96 + 2 * j) * 100 + k];
      b = t0raw[(n * 96 + 2 * j + 1) * 100 + k];
    } else {
      int d0 = 2 * j - 96;
      a = t1raw[(n * 96 + d0) * 100 + g];
      b = t1raw[(n * 96 + d0 + 1) * 100 + g];
    }
    v = 0.5f * (a + b);
  }
  float2 r = blk_sum2_256(v, v * v);
  float m = r.x * (1.f / 256.f);
  float var = r.y * (1.f / 256.f) - m * m;
  sT[n * 25600 + t * 100 + k] = (v - m) * rsqrtf(var + 1e-5f);
}

// ---------------- dmatrix post ----------------
__global__ void softmax_rows_kernel(const float* dm, float* prob, int* amax) {
  long row = blockIdx.x; int t = threadIdx.x;
  __shared__ float red[128]; __shared__ int ri[128];
  float v = (t < 100) ? dm[row * 100 + t] : -1e30f;
  red[t] = v; ri[t] = t; __syncthreads();
  for (int off = 64; off > 0; off >>= 1) {
    if (t < off) {
      if (red[t + off] > red[t] || (red[t + off] == red[t] && ri[t + off] < ri[t])) {
        red[t] = red[t + off]; ri[t] = ri[t + off];
      }
    }
    __syncthreads();
  }
  float mx = red[0];
  if (t == 0) amax[row] = ri[0];
  __syncthreads();
  float e = (t < 100) ? expf(v - mx) : 0.f;
  red[t] = e; __syncthreads();
  for (int off = 64; off > 0; off >>= 1) { if (t < off) red[t] += red[t + off]; __syncthreads(); }
  float s = red[0];
  if (t < 100) prob[row * 100 + t] = e / s;
}

// R6: coalesced column-sum. Block (nh, 128-row chunk): rows read contiguously,
// per-thread register accumulate, one atomicAdd per topic at the end.
__global__ void colsum2_kernel(const float* __restrict__ prob, float* cs0, float* cs1) {
  int nh = blockIdx.x; int n = nh >> 1, half = nh & 1;
  int mc = blockIdx.y;
  int t = threadIdx.x;  // 128
  const float* p = prob + ((long)n * 8192 + (long)half * 4096 + (long)mc * 128) * 100;
  float acc = 0.f;
  if (t < 100) {
    for (int r = 0; r < 128; r++) acc += p[r * 100 + t];
    atomicAdd(&(half ? cs1 : cs0)[n * 100 + t], acc);
  }
}

__global__ void topk_kernel(const float* cs0, const float* cs1, int* inds) {
  int n = blockIdx.x, t = threadIdx.x;
  __shared__ float rv[128]; __shared__ int ri[128]; __shared__ int sbest;
  float base = (t < 100) ? cs0[n * 100 + t] * cs1[n * 100 + t] : -1.f;
  for (int kk = 0; kk < 6; kk++) {
    rv[t] = base; ri[t] = t; __syncthreads();
    for (int off = 64; off > 0; off >>= 1) {
      if (t < off) {
        if (rv[t + off] > rv[t] || (rv[t + off] == rv[t] && ri[t + off] < ri[t])) { rv[t] = rv[t + off]; ri[t] = ri[t + off]; }
      }
      __syncthreads();
    }
    if (t == 0) { inds[n * 6 + kk] = ri[0]; sbest = ri[0]; }
    __syncthreads();
    if (t == sbest) base = -1.f;
    __syncthreads();
  }
}

// ---------------- packed sample machinery ----------------
__global__ __launch_bounds__(1024) void count_kernel(const int* amax, const int* inds, int* segCnt) {
  int seg = blockIdx.x;
  int kk = seg >> 3, g = seg & 7, n = g & 3, half = g >> 2;
  int target = inds[n * 6 + kk];
  const int* am = amax + n * 8192 + half * 4096;
  int t = threadIdx.x;
  int lc = 0;
  #pragma unroll
  for (int j = 0; j < 4; j++) lc += (am[t * 4 + j] == target) ? 1 : 0;
  __shared__ int red[16];
  #pragma unroll
  for (int off = 32; off > 0; off >>= 1) lc += __shfl_down(lc, off, 64);
  if ((t & 63) == 0) red[t >> 6] = lc;
  __syncthreads();
  if (t == 0) {
    int s = 0;
    for (int w = 0; w < 16; w++) s += red[w];
    segCnt[seg] = s;
  }
}

// offs: segment offsets + cond flags + DENSE BLOCK TABLES.
__global__ void offs_kernel(const int* segCnt, int* segOff, float* condf,
                            int* tabCnt,
                            int2* t128_07, int2* t128_03, int2* t128_47,
                            int2* t32_07, int2* t32_03, int2* t32_47) {
  int t = threadIdx.x;
  if (t < 8) {
    int run = 0;
    for (int kk = 0; kk < 6; kk++) {
      segOff[kk * 8 + t] = run;
      run += (segCnt[kk * 8 + t] + 127) & ~127;
    }
  }
  if (t >= 8 && t < 14) {
    int kk = t - 8;
    int a = 0, b = 0;
    for (int g = 0; g < 4; g++) { a += segCnt[kk * 8 + g]; b += segCnt[kk * 8 + 4 + g]; }
    condf[kk] = (a > 0 && b > 0) ? 1.f : 0.f;
  }
  __syncthreads();
  __shared__ int pref[48];
  int2* tabs[6] = {t128_07, t128_03, t128_47, t32_07, t32_03, t32_47};
  for (int tb = 0; tb < 6; tb++) {
    int tile = (tb < 3) ? 128 : 32;
    int r = tb % 3;
    int nb = 0;
    if (t < 48) {
      int g = t & 7;
      bool in = (r == 0) || (r == 1 && g < 4) || (r == 2 && g >= 4);
      if (in) nb = (min(segCnt[t], 4096) + tile - 1) / tile;
      pref[t] = nb;
    }
    __syncthreads();
    for (int o = 1; o < 48; o <<= 1) {
      int v = 0;
      if (t < 48 && t >= o) v = pref[t - o];
      __syncthreads();
      if (t < 48) pref[t] += v;
      __syncthreads();
    }
    if (t < 48 && nb > 0) {
      int st = pref[t] - nb;
      for (int j = 0; j < nb; j++) tabs[tb][st + j] = make_int2(t, j * tile);
    }
    if (t == 0) tabCnt[tb] = pref[47];
    __syncthreads();
  }
}

// ord: stable compaction order + direct gather of packed rows.
__global__ __launch_bounds__(1024) void ord_kernel(const int* amax, const int* inds,
                                                   const int* segOff, int* ordP,
                                                   float* __restrict__ nf,
                                                   const float* __restrict__ f01) {
  int seg = blockIdx.x;
  int kk = seg >> 3, g = seg & 7, n = g & 3, half = g >> 2;
  int target = inds[n * 6 + kk];
  const int* am = amax + n * 8192 + half * 4096;
  int t = threadIdx.x;
  __shared__ int ts[1024];
  int f[4]; int lc = 0;
  #pragma unroll
  for (int j = 0; j < 4; j++) { f[j] = (am[t * 4 + j] == target) ? 1 : 0; lc += f[j]; }
  ts[t] = lc; __syncthreads();
  for (int off = 1; off < 1024; off <<= 1) {
    int add = (t >= off) ? ts[t - off] : 0;
    __syncthreads();
    ts[t] += add;
    __syncthreads();
  }
  int run = (t == 0) ? 0 : ts[t - 1];
  long base = (long)g * ARENA + segOff[seg];
  int* o = ordP + base;
  #pragma unroll
  for (int j = 0; j < 4; j++) {
    if (f[j]) {
      int tok = t * 4 + j;
      o[run] = tok;
      const float4* s4p = (const float4*)&f01[((long)g * 4096 + tok) * 256];
      float4* d4p = (float4*)&nf[(base + run) * 256];
      for (int c = 0; c < 64; c++) d4p[c] = s4p[c];
      run++;
    }
  }
}

// blockIdx.x = seg (spreads active blocks across XCDs).
__global__ void scatter_kernel(float* up, const float* nf, const int* ordP,
                               const int* segOff, const int* segCnt, const float* condf) {
  int seg = blockIdx.x;
  int kk = seg >> 3, g = seg & 7;
  int cntb = segCnt[seg];
  int row0 = blockIdx.y * 128;
  if (row0 >= cntb) return;
  long base = (long)g * ARENA + segOff[seg];
  float cf = condf[kk];
  int t = threadIdx.x;
  int c4 = (t & 63) * 4, rr = t >> 6;
  for (int p = 0; p < 32; p++) {
    int r = row0 + p * 4 + rr;
    if (r >= cntb) break;
    int tok = ordP[base + r];
    float4 add = *(const float4*)&nf[(base + r) * 256 + c4];
    float4* dst = (float4*)&up[((long)g * 4096 + tok) * 256 + c4];
    float4 cur = *dst;
    cur.x += add.x * cf; cur.y += add.y * cf; cur.z += add.z * cf; cur.w += add.w * cf;
    *dst = cur;
  }
}

// up01 aliases out's feat region (index-identical); in-place RMW.
__global__ void final_mix_kernel(const float* f01, float* out_up, const int* amax,
                                 const int* inds) {
  int b = blockIdx.y, half = b >> 2, n = b & 3;
  int l = blockIdx.x, c = threadIdx.x;
  int a = amax[n * 8192 + half * 4096 + l];
  const int* in_ = inds + n * 6;
  bool member = (a == in_[0]) | (a == in_[1]) | (a == in_[2]) | (a == in_[3]) | (a == in_[4]) | (a == in_[5]);
  long idx = ((long)b * 4096 + l) * 256 + c;
  float up = out_up[idx];
  out_up[idx] = (member ? 0.f : 1.f) * f01[idx] + up;
}

// R6: tmi2 — block per (y-row, n*2+half, topic-group of 50). 3 y-rows x 50
// topics staged in LDS ([50][3][66] pad: stride 198 -> <=4-way bank alias);
// loads are 256B-contiguous runs; center read + out write fully contiguous.
__global__ __launch_bounds__(256) void tmi2_kernel(const float* __restrict__ dmat,
                                                   float* __restrict__ out) {
  int y = blockIdx.x;          // 0..63
  int nh = blockIdx.y;         // n*2+half
  int n = nh >> 1, half = nh & 1;
  int bg = blockIdx.z;         // topic group: 0 -> 0..49, 1 -> 50..99
  const float* dm = dmat + (long)n * 819200 + (long)half * 409600;
  __shared__ float P[50][3][66];
  int t = threadIdx.x;
  for (int j = t; j < 50 * 64; j += 256) {
    int bb = j >> 6, x = j & 63;
    long pb = (long)(bg * 50 + bb) * 4096;
    #pragma unroll
    for (int r = 0; r < 3; r++) {
      int gy = y + r - 1;
      P[bb][r][x] = (gy >= 0 && gy < 64) ? dm[pb + (long)gy * 64 + x] : 0.f;
    }
  }
  __syncthreads();
  long outBase = 8388608L + (long)half * 1638400 + (long)n * 409600;
  for (int j = t; j < 64 * 50; j += 256) {
    int x = j / 50, bb = j % 50;
    float s = 0.f;
    #pragma unroll
    for (int r = 0; r < 3; r++) {
      s += P[bb][r][x];
      if (x > 0) s += P[bb][r][x - 1];
      if (x < 63) s += P[bb][r][x + 1];
    }
    long i = (long)(y * 64 + x) * 100 + bg * 50 + bb;
    out[outBase + i] = dm[i] * (s * (1.f / 9.f));
  }
}

// ---------------------------------------------------------------------------
extern "C" void kernel_launch(void* const* d_in, const int* in_sizes, int n_in,
                              void* d_out, int out_size, void* d_ws, size_t ws_size,
                              hipStream_t stream)
{
  (void)in_sizes; (void)n_in; (void)out_size; (void)ws_size;
  const float* feat0_in = (const float*)d_in[0];
  const float* feat1_in = (const float*)d_in[1];
  const float* topic0 = (const float*)d_in[2];
  const float* topic1 = (const float*)d_in[3];
  const float* seed_tokens = (const float*)d_in[4];
  const float* Wq = (const float*)d_in[5];
  const float* Wk = (const float*)d_in[6];
  const float* Wv = (const float*)d_in[7];
  const float* Wm = (const float*)d_in[8];
  const float* W1 = (const float*)d_in[9];
  const float* W2 = (const float*)d_in[10];
  float* out = (float*)d_out;

  float* base = (float*)d_ws;
  long off = 0;
  auto alloc = [&](long n) -> float* { float* p = base + off; off += (n + 255) & ~255L; return p; };
  float* f01   = alloc(8388608);          // [8][4096][256]
  float* qb    = alloc(8L * ARENA * 256); // Q / LN(msg2)
  float* kb    = alloc(8L * ARENA * 256); // K / msg / h1 low   (kb,vb contiguous)
  float* vb    = alloc(8L * ARENA * 256); // V / h1 high
  float* nf    = alloc(8L * ARENA * 256); // packed sample tokens
  float* seeds = alloc(102400);
  float* kvks  = alloc(48 * 8192 + 48 * 256);
  float* dmat  = alloc(3276800);
  short* wbuf  = (short*)alloc(5242880);
  float* tmb   = alloc(40000);
  float* sT    = alloc(102400);
  float* cs0   = alloc(400);
  float* cs1   = alloc(400);
  float* condf = alloc(256);
  int* tmidx  = (int*)alloc(400);
  int* amax   = (int*)alloc(32768);
  int* inds   = (int*)alloc(256);
  int* segCnt = (int*)alloc(256);
  int* segOffA= (int*)alloc(256);
  int* ordP   = (int*)alloc(8L * ARENA);
  int* tabCnt = (int*)alloc(64);
  int2* T128_07 = (int2*)alloc(640);
  int2* T128_03 = (int2*)alloc(320);
  int2* T128_47 = (int2*)alloc(320);
  int2* T32_07  = (int2*)alloc(2176);
  int2* T32_03  = (int2*)alloc(1088);
  int2* T32_47  = (int2*)alloc(1088);
  float* up01 = out;                      // aliases out's feat region

  const int m128[3] = {304, 152, 152};
  const int m32[3]  = {1072, 536, 536};
  int2* T128[3] = {T128_07, T128_03, T128_47};
  int2* T32[3]  = {T32_07, T32_03, T32_47};

  auto WOFF = [](int l) -> long { return (long)l * 1310720; };

  auto gmainZ = [&](const float* A, const float* A2, int aw, long wOff, int loD,
                    float* c0, float* c1, float* c2, int M, int Kd, int Ntot, int outW,
                    long sA_, long sC_, int bm, int bx,
                    int m0, int m1, int m2_, int nb) {
    dim3 g(Ntot / 128, (M + 127) / 128, nb), blk(256);
    gemm_main_kernel<<<g, blk, 0, stream>>>(A, A2, aw, wbuf + wOff, loD, c0, c1, c2,
        M, Kd, outW, sA_, sC_, bm, bx, nullptr, nullptr,
        nullptr, nullptr, nullptr, 0, 0, m0, m1, m2_);
  };
  auto gmainP = [&](const float* A, const float* A2, int aw, long wOff, int loD,
                    float* c0, float* c1, float* c2, int Kd, int Ntot, int outW,
                    int rQ, int rKV, int m0, int m1, int m2_) {
    int ymax = max(m128[rQ], m128[rKV]);
    dim3 g(Ntot / 128, ymax, 1), blk(256);
    gemm_main_kernel<<<g, blk, 0, stream>>>(A, A2, aw, wbuf + wOff, loD, c0, c1, c2,
        4096, Kd, outW, 0, 0, 0, 0, segOffA, segCnt,
        T128[rQ], T128[rKV], tabCnt, rQ, rKV, m0, m1, m2_);
  };
  auto g256Z = [&](const float* A, int aw, long wOff, int loD, float* C, float* X,
                   int M, int Kd, long sA_, long sC_, long sX_, int bm, int bx,
                   int mode, int nb) {
    dim3 g(1, (M + 127) / 128, nb), blk(256);
    gemm256_kernel<<<g, blk, 0, stream>>>(A, aw, wbuf + wOff, loD, C, X,
        M, Kd, sA_, sC_, sX_, bm, bx, mode);
  };
  auto g256P = [&](const float* A, int aw, long wOff, int loD, float* C, float* X,
                   int r, int mode) {
    dim3 g(1, m32[r], 1), blk(256);
    gemm256_seg_kernel<<<g, blk, 0, stream>>>(A, aw, wbuf + wOff, loD, C, X,
        segOffA, segCnt, T32[r], tabCnt + 3 + r, mode);
  };

  auto encTailZ = [&](float* x, int l, int s_len, float s_scale, int layer, int nb,
                      long sAx, int bmKV, int bxKV, int nch) {
    if (nch > 1)
      hipMemsetAsync(kvks, 0, (48 * 8192 + 48 * 256) * sizeof(float), stream);
    int chunk = (s_len + nch - 1) / nch;
    kv_kernel<<<dim3(nb, 8, nch), dim3(32, 32), 0, stream>>>(
        kb, vb, kvks, kvks + 48 * 8192, s_len, 1.f / s_scale, bmKV, bxKV,
        nullptr, nullptr, 0, 0, 7, chunk);
    zmsg_kernel<<<dim3(nb, (l + 31) / 32), 256, 0, stream>>>(
        qb, kvks, kvks + 48 * 8192, kb, l, s_scale, nullptr, nullptr, 0, 7);
    g256Z(kb, 256, WOFF(layer) + 393216, 65536, qb, nullptr,
          l, 256, sAx, sAx, 0, 7, 0, 3, nb);
    gmainZ(x, qb, 256, WOFF(layer) + 524288, 262144, kb, nullptr, nullptr,
           l, 512, 512, 512, sAx, sAx * 2, 7, 0, 1, 0, 0, nb);
    g256Z(kb, 512, WOFF(layer) + 1048576, 131072, nullptr, x,
          l, 512, sAx * 2, 0, sAx, 7, 0, 4, nb);
  };
  auto encTailP = [&](float* x, float s_scale, int layer, int r, int axor,
                      int gmin, int gmax) {
    kv_kernel<<<dim3(48, 8, 1), dim3(32, 32), 0, stream>>>(
        kb, vb, kvks, kvks + 48 * 8192, 4096, 1.f / s_scale, 0, 0,
        segOffA, segCnt, axor, gmin, gmax, 4096);
    zmsg_kernel<<<dim3(48, 128), 256, 0, stream>>>(
        qb, kvks, kvks + 48 * 8192, kb, 4096, s_scale, segOffA, segCnt, gmin, gmax);
    g256P(kb, 256, WOFF(layer) + 393216, 65536, qb, nullptr, r, 3);
    gmainP(x, qb, 256, WOFF(layer) + 524288, 262144, kb, nullptr, nullptr,
           512, 512, 512, r, r, 1, 0, 0);
    g256P(kb, 512, WOFF(layer) + 1048576, 131072, nullptr, x, r, 4);
  };

  // ---- init ----
  cvt2_kernel<<<32768, 256, 0, stream>>>(f01, feat0_in, feat1_in, 4194304);
  bcast_seeds_kernel<<<400, 256, 0, stream>>>(seeds, seed_tokens);
  prep_w_kernel<<<20480, 256, 0, stream>>>(Wq, Wk, Wv, Wm, W1, W2, wbuf);

  // ---- topic pipeline ----
  tm_build_kernel<<<dim3(4, 100), 128, 0, stream>>>(topic0, topic1, tmb);
  tm_post_kernel<<<4, 256, 0, stream>>>(tmb, tmidx);

  // ---- main encoder layers ----
  auto encSeedLayer = [&](int layer) {
    g256Z(seeds, 256, WOFF(layer), 196608, qb, nullptr,
          100, 256, 25600, 25600, 0, 7, 0, 2, 4);
    gmainZ(feat0_in, nullptr, 256, WOFF(layer) + 65536, 196608, kb, vb, nullptr,
           4096, 256, 512, 256, 1048576, 2097152, 7, 0, 2, 0, 0, 4);
    gmainZ(feat1_in, nullptr, 256, WOFF(layer) + 65536, 196608, kb + 1048576, vb + 1048576, nullptr,
           4096, 256, 512, 256, 1048576, 2097152, 7, 0, 2, 0, 0, 4);
    encTailZ(seeds, 100, 8192, 8192.f, layer, 4, 25600, 7, 0, 8);
  };
  auto encFeatLayer = [&](int layer) {
    g256Z(f01, 256, WOFF(layer), 196608, qb, nullptr,
          4096, 256, 1048576, 1048576, 0, 7, 0, 2, 8);
    gmainZ(seeds, nullptr, 256, WOFF(layer) + 65536, 196608, kb, vb, nullptr,
           100, 256, 512, 256, 25600, 25600, 3, 0, 2, 0, 0, 8);
    encTailZ(f01, 4096, 100, 100.f, layer, 8, 1048576, 7, 0, 1);
  };

  encSeedLayer(0);
  encFeatLayer(1);
  encSeedLayer(2);
  encFeatLayer(3);

  // ---- seeds final + dmatrix ----
  seedsF_kernel<<<dim3(4, 100), 256, 0, stream>>>(seeds, topic0, topic1, tmidx, sT);
  {
    dim3 g(1, 32, 4), blk(256);
    gemm_f32b_kernel<<<g, blk, 0, stream>>>(feat0_in, sT, dmat, 4096, 100, 256, 1048576, 25600, 819200, 0.0625f);
    gemm_f32b_kernel<<<g, blk, 0, stream>>>(feat1_in, sT, dmat + 409600, 4096, 100, 256, 1048576, 25600, 819200, 0.0625f);
  }
  float* prob = kb;
  softmax_rows_kernel<<<32768, 128, 0, stream>>>(dmat, prob, amax);
  hipMemsetAsync(cs0, 0, 1024 * sizeof(float), stream);  // covers cs0+cs1 slots
  colsum2_kernel<<<dim3(8, 32), 128, 0, stream>>>(prob, cs0, cs1);
  topk_kernel<<<4, 128, 0, stream>>>(cs0, cs1, inds);

  hipMemsetAsync(up01, 0, 8388608 * sizeof(float), stream);

  // ---- sample phase: 48 packed segments, table-driven GEMMs ----
  count_kernel<<<48, 1024, 0, stream>>>(amax, inds, segCnt);
  offs_kernel<<<1, 64, 0, stream>>>(segCnt, segOffA, condf, tabCnt,
                                    T128_07, T128_03, T128_47, T32_07, T32_03, T32_47);
  ord_kernel<<<48, 1024, 0, stream>>>(amax, inds, segOffA, ordP, nf, f01);

  for (int idt = 0; idt < 2; idt++) {
    int wA = 4 + idt * 2, wB = wA + 1;
    gmainP(nf, nullptr, 256, WOFF(wA), 196608, qb, kb, vb,
           256, 768, 256, 0, 0, 2, 2, 0);
    encTailP(nf, 4096.f, wA, 0, 0, 0, 7);
    gmainP(nf, nullptr, 256, WOFF(wB), 196608, qb, kb, vb,
           256, 768, 256, 1, 2, 2, 2, 0);
    encTailP(nf, 4096.f, wB, 1, 4, 0, 3);
    gmainP(nf, nullptr, 256, WOFF(wB), 196608, qb, kb, vb,
           256, 768, 256, 2, 1, 2, 2, 0);
    encTailP(nf, 4096.f, wB, 2, 4, 4, 7);
  }
  scatter_kernel<<<dim3(48, 32), 256, 0, stream>>>(up01, nf, ordP, segOffA, segCnt, condf);

  // ---- outputs ----
  final_mix_kernel<<<dim3(4096, 8), 256, 0, stream>>>(f01, up01, amax, inds);
  tmi2_kernel<<<dim3(64, 8, 2), 256, 0, stream>>>(dmat, out);
}

// Round 8
// 2189.054 us; speedup vs baseline: 2.4411x; 1.0928x over previous
//
#include <hip/hip_runtime.h>
#include <math.h>

// N=4, L=S=4096, C=256, K=100, NHEAD=8, D=32. FP32 I/O.
// Big GEMMs: bf16x3 split MFMA (hi*hi + hi*lo + lo*hi, fp32 acc) ~ fp32 fidelity.
// Sample loop batched into 48 packed segments (6 samples x 8 batch-halves),
// 128-aligned inside an [8][4864]-row arena.
// R1: panel-major weights (256-col groups of [k/32][n&255][32]); depth-1 prefetch.
// R2: wB Q fused into K/V gmain; zmsg 32 rows/block; softmax+argmax fused.
// R3: kv direct-store; seedsF folds topicp+transpose; ord folds gather.
// R4: packed GEMMs via device-built dense block tables (fix block->XCD
//     aliasing: active idx % 8 == 0 put everything on XCD 0). 5343 -> 2609us.
// R5: tm_all split into tm_build + tm_post; scatter grid transposed. -> 2459us.
// R6: tmi2 (LDS-staged 3-row halo, coalesced); colsum2 (contiguous rows,
//     1 atomic/topic). -> 2392us.
// R7: plain gemm256 re-tiled 128x256 -> 64x256 rows. h2/msg2/Q feat sites ran
//     grid(1,32,8)=256 blocks = 1 block/CU (4 waves: HBM latency exposed,
//     80us vs 14us roofline, Occ 10%). 64-row tile: 512 blocks = 2/CU,
//     8 waves/CU, LDS 58->48KB, acc[2][8] (VGPR ~100).

typedef __attribute__((ext_vector_type(8))) short short8;
typedef __attribute__((ext_vector_type(4))) short s4;
typedef __attribute__((ext_vector_type(4))) float f32x4;

#define ARENA 4864  // rows per g in packed arena (4096 + 6*128 alignment pad)

__device__ __forceinline__ short f2bf(float f) {
  unsigned u = __float_as_uint(f);
  return (short)((u + 0x7FFFu + ((u >> 16) & 1u)) >> 16);
}
__device__ __forceinline__ float bf2f(short s) {
  return __uint_as_float(((unsigned)(unsigned short)s) << 16);
}

// ---------------------------------------------------------------------------
// Weight prep: per layer L, panel-major bf16 hi/lo planes.
// Layout per matrix: 256-col groups; group g holds cols [g*256,(g+1)*256);
// within group: panel p = k/32 (8192 shorts each); within panel: (n&255)*32+(k&31).
// Per-layer stride 1310720 shorts:
//   +0       QKV [768][256] hi (Wq group0, Wk group1, Wv group2), lo +196608
//   +393216  Wm  [256][256] hi, lo +65536
//   +524288  W1  [512][512] hi (2 groups of 131072), lo +262144
//   +1048576 W2  [256][512] hi, lo +131072
// ---------------------------------------------------------------------------
__global__ void prep_w_kernel(const float* __restrict__ Wq, const float* __restrict__ Wk,
                              const float* __restrict__ Wv, const float* __restrict__ Wm,
                              const float* __restrict__ W1, const float* __restrict__ W2,
                              short* __restrict__ wb) {
  long i = (long)blockIdx.x * 256 + threadIdx.x;
  if (i >= 8L * 655360) return;
  int L = (int)(i / 655360);
  int r = (int)(i % 655360);
  long base = (long)L * 1310720;
  float v; long dhi; int loD;
  if (r < 196608) {
    int n = r >> 8, k = r & 255;
    const float* s = (n < 256) ? (Wq + (long)L * 65536)
                   : (n < 512) ? (Wk + (long)L * 65536) : (Wv + (long)L * 65536);
    v = s[k * 256 + (n & 255)];
    dhi = base + ((long)(n >> 8) << 16) + ((long)(k >> 5) << 13) + ((n & 255) << 5) + (k & 31);
    loD = 196608;
  } else if (r < 262144) {
    int j = r - 196608; int n = j >> 8, k = j & 255;
    v = Wm[(long)L * 65536 + k * 256 + n];
    dhi = base + 393216 + ((long)(k >> 5) << 13) + (n << 5) + (k & 31);
    loD = 65536;
  } else if (r < 524288) {
    int j = r - 262144; int n = j >> 9, k = j & 511;
    v = W1[(long)L * 262144 + (long)k * 512 + n];
    dhi = base + 524288 + ((long)(n >> 8) << 17) + ((long)(k >> 5) << 13) + ((n & 255) << 5) + (k & 31);
    loD = 262144;
  } else {
    int j = r - 524288; int n = j >> 9, k = j & 511;
    v = W2[(long)L * 131072 + (long)k * 256 + n];
    dhi = base + 1048576 + ((long)(k >> 5) << 13) + (n << 5) + (k & 31);
    loD = 131072;
  }
  short h = f2bf(v);
  wb[dhi] = h;
  wb[dhi + loD] = f2bf(v - bf2f(h));
}

// ---------------------------------------------------------------------------
// gemm_main: 128x128 tiles. Plain-batch (z-grid) OR packed via dense block
// table (grid.y indexes (seg,row0); sel==0 -> tabQ, sel>=1 -> tabKV).
// modes: 0 none, 1 relu, 2 elu(x)+1.
// ---------------------------------------------------------------------------
__global__ __launch_bounds__(256) void gemm_main_kernel(
    const float* __restrict__ A, const float* __restrict__ A2, int aw,
    const short* __restrict__ Bh, int loD,
    float* __restrict__ C0, float* __restrict__ C1, float* __restrict__ C2,
    int M, int Kd, int outW, long sA, long sC,
    int bmask, int bxor,
    const int* __restrict__ segOff, const int* __restrict__ segCnt,
    const int2* __restrict__ tabQ, const int2* __restrict__ tabKV,
    const int* __restrict__ tabCnt, int tQ, int tKV,
    int mode0, int mode1, int mode2)
{
  int colg = blockIdx.x * 128;
  int sel = colg / outW;
  long aBase, cBase; int cntb, row0;
  if (tabQ) {
    const int2* tab = (sel == 0) ? tabQ : tabKV;
    int n = tabCnt[(sel == 0) ? tQ : tKV];
    int y = blockIdx.y;
    if (y >= n) return;
    int2 e = tab[y];
    long rb = (long)(e.x & 7) * ARENA + segOff[e.x];
    aBase = rb * aw; cBase = rb * (long)outW;
    cntb = segCnt[e.x];
    row0 = e.y;
  } else {
    int z = blockIdx.z;
    int ab = (z & bmask) ^ bxor;
    aBase = (long)ab * sA; cBase = (long)z * sC;
    cntb = M;
    row0 = blockIdx.y * 128;
    if (row0 >= cntb) return;
  }
  float* Cb = (sel == 0 ? C0 : (sel == 1 ? C1 : C2)) + cBase;
  int mode = (sel == 0 ? mode0 : (sel == 1 ? mode1 : mode2));
  int colo = colg % outW;

  int t = threadIdx.x;
  int lane = t & 63, wid = t >> 6, wm = wid >> 1, wn = wid & 1;
  int fi = lane & 15, fq = lane >> 4;

  __shared__ __align__(16) short Ah[128][36];
  __shared__ __align__(16) short Al[128][36];
  __shared__ __align__(16) short Bsh[128][36];
  __shared__ __align__(16) short Bsl[128][36];

  f32x4 acc[4][4];
  #pragma unroll
  for (int i = 0; i < 4; i++)
    #pragma unroll
    for (int j = 0; j < 4; j++)
      acc[i][j] = (f32x4){0.f, 0.f, 0.f, 0.f};

  int tr = t >> 3, tc = (t & 7) * 4;
  int nc = t >> 1, kh = (t & 1) * 16;
  int gb = colg >> 8;
  int cg = (colg & 255) + nc;
  const short* bBase = Bh + (long)gb * ((long)Kd << 8) + (long)cg * 32 + kh;

  float4 avp[4];
  short8 bhp[2], blp[2];

  auto issueA = [&](int k0) {
    bool useA2 = (A2 != nullptr) && (k0 >= 256);
    const float* Asrc = useA2 ? A2 : A;
    int kcol = useA2 ? (k0 - 256) : k0;
    #pragma unroll
    for (int p = 0; p < 4; p++) {
      int gr = row0 + tr + p * 32;
      avp[p] = make_float4(0.f, 0.f, 0.f, 0.f);
      if (gr < M) avp[p] = *(const float4*)&Asrc[aBase + (long)gr * aw + kcol + tc];
    }
  };
  auto issueB = [&](int k0) {
    const short* bs = bBase + ((long)(k0 >> 5) << 13);
    bhp[0] = *(const short8*)bs;
    bhp[1] = *(const short8*)(bs + 8);
    blp[0] = *(const short8*)(bs + loD);
    blp[1] = *(const short8*)(bs + loD + 8);
  };

  issueA(0); issueB(0);
  for (int k0 = 0; k0 < Kd; k0 += 32) {
    #pragma unroll
    for (int p = 0; p < 4; p++) {
      float vv[4] = {avp[p].x, avp[p].y, avp[p].z, avp[p].w};
      s4 h4, l4;
      #pragma unroll
      for (int e = 0; e < 4; e++) {
        short h = f2bf(vv[e]); h4[e] = h; l4[e] = f2bf(vv[e] - bf2f(h));
      }
      *(s4*)&Ah[tr + p * 32][tc] = h4;
      *(s4*)&Al[tr + p * 32][tc] = l4;
    }
    *(short8*)&Bsh[nc][kh]     = bhp[0];
    *(short8*)&Bsh[nc][kh + 8] = bhp[1];
    *(short8*)&Bsl[nc][kh]     = blp[0];
    *(short8*)&Bsl[nc][kh + 8] = blp[1];
    if (k0 + 32 < Kd) { issueA(k0 + 32); issueB(k0 + 32); }
    __syncthreads();
    short8 ah[4], al[4], bh[4], bl[4];
    #pragma unroll
    for (int i = 0; i < 4; i++) {
      ah[i] = *(const short8*)&Ah[wm * 64 + i * 16 + fi][fq * 8];
      al[i] = *(const short8*)&Al[wm * 64 + i * 16 + fi][fq * 8];
    }
    #pragma unroll
    for (int j = 0; j < 4; j++) {
      bh[j] = *(const short8*)&Bsh[wn * 64 + j * 16 + fi][fq * 8];
      bl[j] = *(const short8*)&Bsl[wn * 64 + j * 16 + fi][fq * 8];
    }
    #pragma unroll
    for (int i = 0; i < 4; i++)
      #pragma unroll
      for (int j = 0; j < 4; j++) {
        acc[i][j] = __builtin_amdgcn_mfma_f32_16x16x32_bf16(ah[i], bh[j], acc[i][j], 0, 0, 0);
        acc[i][j] = __builtin_amdgcn_mfma_f32_16x16x32_bf16(ah[i], bl[j], acc[i][j], 0, 0, 0);
        acc[i][j] = __builtin_amdgcn_mfma_f32_16x16x32_bf16(al[i], bh[j], acc[i][j], 0, 0, 0);
      }
    __syncthreads();
  }
  #pragma unroll
  for (int i = 0; i < 4; i++) {
    #pragma unroll
    for (int reg = 0; reg < 4; reg++) {
      int gr = row0 + wm * 64 + i * 16 + fq * 4 + reg;
      if (gr >= M || gr >= cntb) continue;
      #pragma unroll
      for (int j = 0; j < 4; j++) {
        int cc = colo + wn * 64 + j * 16 + fi;
        float v = acc[i][j][reg];
        if (mode == 1) { if (v < 0.f) v = 0.f; }
        else if (mode == 2) { v = (v > 0.f) ? (v + 1.f) : expf(v); }
        Cb[(long)gr * outW + cc] = v;
      }
    }
  }
}

// ---------------------------------------------------------------------------
// gemm256: N=256, R7: 64x256 tile, PLAIN batch only (2 blocks/CU at M=4096
// vs 1 with the old 128-row tile; HBM latency was exposed at 4 waves/CU).
// modes: 0 none, 2 elu+1, 3 LN->C, 4 X += LN.
// ---------------------------------------------------------------------------
__global__ __launch_bounds__(256) void gemm256_kernel(
    const float* __restrict__ A, int aw, const short* __restrict__ Bh, int loD,
    float* __restrict__ C, float* __restrict__ X,
    int M, int Kd, long sA, long sC, long sX,
    int bmask, int bxor, int mode)
{
  int z = blockIdx.z;
  int ab = (z & bmask) ^ bxor;
  long aBase = (long)ab * sA, cBase = (long)z * sC, xBase = (long)ab * sX;
  int row0 = blockIdx.y * 64;
  if (row0 >= M) return;

  int t = threadIdx.x;
  int lane = t & 63, wid = t >> 6, wm = wid >> 1, wn = wid & 1;
  int fi = lane & 15, fq = lane >> 4;

  __shared__ __align__(16) short Ah[64][36];
  __shared__ __align__(16) short Al[64][36];
  __shared__ __align__(16) short Bsh[256][36];
  __shared__ __align__(16) short Bsl[256][36];
  __shared__ float lnS[2][64];
  __shared__ float lnQ[2][64];
  __shared__ float muS[64];
  __shared__ float rsS[64];

  f32x4 acc[2][8];
  #pragma unroll
  for (int i = 0; i < 2; i++)
    #pragma unroll
    for (int j = 0; j < 8; j++)
      acc[i][j] = (f32x4){0.f, 0.f, 0.f, 0.f};

  int tr = t >> 3, tc = (t & 7) * 4;   // tr 0..31; rows tr + p*32, p=0..1
  const short* bBase = Bh + (long)t * 32;

  float4 avp[2];
  short8 bhp[4], blp[4];

  auto issueA = [&](int k0) {
    #pragma unroll
    for (int p = 0; p < 2; p++) {
      int gr = row0 + tr + p * 32;
      avp[p] = make_float4(0.f, 0.f, 0.f, 0.f);
      if (gr < M) avp[p] = *(const float4*)&A[aBase + (long)gr * aw + k0 + tc];
    }
  };
  auto issueB = [&](int k0) {
    const short* bs = bBase + ((long)(k0 >> 5) << 13);
    #pragma unroll
    for (int q = 0; q < 4; q++) {
      bhp[q] = *(const short8*)(bs + q * 8);
      blp[q] = *(const short8*)(bs + loD + q * 8);
    }
  };

  issueA(0); issueB(0);
  for (int k0 = 0; k0 < Kd; k0 += 32) {
    #pragma unroll
    for (int p = 0; p < 2; p++) {
      float vv[4] = {avp[p].x, avp[p].y, avp[p].z, avp[p].w};
      s4 h4, l4;
      #pragma unroll
      for (int e = 0; e < 4; e++) {
        short h = f2bf(vv[e]); h4[e] = h; l4[e] = f2bf(vv[e] - bf2f(h));
      }
      *(s4*)&Ah[tr + p * 32][tc] = h4;
      *(s4*)&Al[tr + p * 32][tc] = l4;
    }
    #pragma unroll
    for (int q = 0; q < 4; q++) {
      *(short8*)&Bsh[t][q * 8] = bhp[q];
      *(short8*)&Bsl[t][q * 8] = blp[q];
    }
    if (k0 + 32 < Kd) { issueA(k0 + 32); issueB(k0 + 32); }
    __syncthreads();
    short8 ah[2], al[2];
    #pragma unroll
    for (int i = 0; i < 2; i++) {
      ah[i] = *(const short8*)&Ah[wm * 32 + i * 16 + fi][fq * 8];
      al[i] = *(const short8*)&Al[wm * 32 + i * 16 + fi][fq * 8];
    }
    #pragma unroll
    for (int jh = 0; jh < 2; jh++) {
      short8 bh[4], bl[4];
      #pragma unroll
      for (int j = 0; j < 4; j++) {
        bh[j] = *(const short8*)&Bsh[wn * 128 + (jh * 4 + j) * 16 + fi][fq * 8];
        bl[j] = *(const short8*)&Bsl[wn * 128 + (jh * 4 + j) * 16 + fi][fq * 8];
      }
      #pragma unroll
      for (int i = 0; i < 2; i++)
        #pragma unroll
        for (int j = 0; j < 4; j++) {
          acc[i][jh * 4 + j] = __builtin_amdgcn_mfma_f32_16x16x32_bf16(ah[i], bh[j], acc[i][jh * 4 + j], 0, 0, 0);
          acc[i][jh * 4 + j] = __builtin_amdgcn_mfma_f32_16x16x32_bf16(ah[i], bl[j], acc[i][jh * 4 + j], 0, 0, 0);
          acc[i][jh * 4 + j] = __builtin_amdgcn_mfma_f32_16x16x32_bf16(al[i], bh[j], acc[i][jh * 4 + j], 0, 0, 0);
        }
    }
    __syncthreads();
  }

  if (mode >= 3) {
    // per-row LN stats across all 256 cols (64 rows)
    #pragma unroll
    for (int i = 0; i < 2; i++)
      #pragma unroll
      for (int reg = 0; reg < 4; reg++) {
        float s = 0.f, q = 0.f;
        #pragma unroll
        for (int j = 0; j < 8; j++) { float v = acc[i][j][reg]; s += v; q += v * v; }
        #pragma unroll
        for (int m = 1; m < 16; m <<= 1) { s += __shfl_xor(s, m, 64); q += __shfl_xor(q, m, 64); }
        if (fi == 0) {
          int row = wm * 32 + i * 16 + fq * 4 + reg;
          lnS[wn][row] = s; lnQ[wn][row] = q;
        }
      }
    __syncthreads();
    if (t < 64) {
      float s = lnS[0][t] + lnS[1][t];
      float q = lnQ[0][t] + lnQ[1][t];
      float m = s * (1.f / 256.f);
      float var = q * (1.f / 256.f) - m * m;
      muS[t] = m; rsS[t] = rsqrtf(var + 1e-5f);
    }
    __syncthreads();
  }

  #pragma unroll
  for (int i = 0; i < 2; i++) {
    #pragma unroll
    for (int reg = 0; reg < 4; reg++) {
      int row = wm * 32 + i * 16 + fq * 4 + reg;
      int gr = row0 + row;
      if (gr >= M) continue;
      #pragma unroll
      for (int j = 0; j < 8; j++) {
        int col = wn * 128 + j * 16 + fi;
        float v = acc[i][j][reg];
        if (mode == 2) { v = (v > 0.f) ? (v + 1.f) : expf(v); C[cBase + (long)gr * 256 + col] = v; }
        else if (mode == 3) { C[cBase + (long)gr * 256 + col] = (v - muS[row]) * rsS[row]; }
        else if (mode == 4) { X[xBase + (long)gr * 256 + col] += (v - muS[row]) * rsS[row]; }
        else { C[cBase + (long)gr * 256 + col] = v; }
      }
    }
  }
}

// ---------------------------------------------------------------------------
// gemm256_seg: N=256, 32x256 tile, packed-only, dense block table.
// 4 waves: wave w covers cols [64w,64w+64), rows 0..31. ~42KB LDS -> 3 blk/CU.
// Kd == aw (256 or 512). modes: 3 LN->C, 4 X += LN.
// ---------------------------------------------------------------------------
__global__ __launch_bounds__(256) void gemm256_seg_kernel(
    const float* __restrict__ A, int aw, const short* __restrict__ Bh, int loD,
    float* __restrict__ C, float* __restrict__ X,
    const int* __restrict__ segOff, const int* __restrict__ segCnt,
    const int2* __restrict__ tab, const int* __restrict__ nTab, int mode)
{
  int y = blockIdx.y;
  if (y >= nTab[0]) return;
  int2 e = tab[y];
  long rb = (long)(e.x & 7) * ARENA + segOff[e.x];
  int cntb = segCnt[e.x];
  int row0 = e.y;
  long aBase = rb * aw, cBase = rb * 256, xBase = rb * 256;

  int t = threadIdx.x;
  int lane = t & 63, w = t >> 6;
  int fi = lane & 15, fq = lane >> 4;

  __shared__ __align__(16) short Ah[32][36];
  __shared__ __align__(16) short Al[32][36];
  __shared__ __align__(16) short Bsh[256][36];
  __shared__ __align__(16) short Bsl[256][36];
  __shared__ float lnS[4][32];
  __shared__ float lnQ[4][32];
  __shared__ float muS[32];
  __shared__ float rsS[32];

  f32x4 acc[2][4];
  #pragma unroll
  for (int i = 0; i < 2; i++)
    #pragma unroll
    for (int j = 0; j < 4; j++)
      acc[i][j] = (f32x4){0.f, 0.f, 0.f, 0.f};

  int tr = t >> 3, tc = (t & 7) * 4;  // tr 0..31
  const short* bBase = Bh + (long)t * 32;

  float4 avp;
  short8 bhp[4], blp[4];

  auto issueA = [&](int k0) {
    avp = *(const float4*)&A[aBase + (long)(row0 + tr) * aw + k0 + tc];
  };
  auto issueB = [&](int k0) {
    const short* bs = bBase + ((long)(k0 >> 5) << 13);
    #pragma unroll
    for (int q = 0; q < 4; q++) {
      bhp[q] = *(const short8*)(bs + q * 8);
      blp[q] = *(const short8*)(bs + loD + q * 8);
    }
  };

  issueA(0); issueB(0);
  for (int k0 = 0; k0 < aw; k0 += 32) {
    {
      float vv[4] = {avp.x, avp.y, avp.z, avp.w};
      s4 h4, l4;
      #pragma unroll
      for (int e2 = 0; e2 < 4; e2++) {
        short h = f2bf(vv[e2]); h4[e2] = h; l4[e2] = f2bf(vv[e2] - bf2f(h));
      }
      *(s4*)&Ah[tr][tc] = h4;
      *(s4*)&Al[tr][tc] = l4;
    }
    #pragma unroll
    for (int q = 0; q < 4; q++) {
      *(short8*)&Bsh[t][q * 8] = bhp[q];
      *(short8*)&Bsl[t][q * 8] = blp[q];
    }
    if (k0 + 32 < aw) { issueA(k0 + 32); issueB(k0 + 32); }
    __syncthreads();
    short8 ah[2], al[2];
    #pragma unroll
    for (int i = 0; i < 2; i++) {
      ah[i] = *(const short8*)&Ah[i * 16 + fi][fq * 8];
      al[i] = *(const short8*)&Al[i * 16 + fi][fq * 8];
    }
    #pragma unroll
    for (int j = 0; j < 4; j++) {
      short8 bh = *(const short8*)&Bsh[w * 64 + j * 16 + fi][fq * 8];
      short8 bl = *(const short8*)&Bsl[w * 64 + j * 16 + fi][fq * 8];
      #pragma unroll
      for (int i = 0; i < 2; i++) {
        acc[i][j] = __builtin_amdgcn_mfma_f32_16x16x32_bf16(ah[i], bh, acc[i][j], 0, 0, 0);
        acc[i][j] = __builtin_amdgcn_mfma_f32_16x16x32_bf16(ah[i], bl, acc[i][j], 0, 0, 0);
        acc[i][j] = __builtin_amdgcn_mfma_f32_16x16x32_bf16(al[i], bh, acc[i][j], 0, 0, 0);
      }
    }
    __syncthreads();
  }

  if (mode >= 3) {
    #pragma unroll
    for (int i = 0; i < 2; i++)
      #pragma unroll
      for (int reg = 0; reg < 4; reg++) {
        float s = 0.f, q = 0.f;
        #pragma unroll
        for (int j = 0; j < 4; j++) { float v = acc[i][j][reg]; s += v; q += v * v; }
        #pragma unroll
        for (int m = 1; m < 16; m <<= 1) { s += __shfl_xor(s, m, 64); q += __shfl_xor(q, m, 64); }
        if (fi == 0) {
          int row = i * 16 + fq * 4 + reg;
          lnS[w][row] = s; lnQ[w][row] = q;
        }
      }
    __syncthreads();
    if (t < 32) {
      float s = lnS[0][t] + lnS[1][t] + lnS[2][t] + lnS[3][t];
      float q = lnQ[0][t] + lnQ[1][t] + lnQ[2][t] + lnQ[3][t];
      float m = s * (1.f / 256.f);
      float var = q * (1.f / 256.f) - m * m;
      muS[t] = m; rsS[t] = rsqrtf(var + 1e-5f);
    }
    __syncthreads();
  }

  #pragma unroll
  for (int i = 0; i < 2; i++) {
    #pragma unroll
    for (int reg = 0; reg < 4; reg++) {
      int row = i * 16 + fq * 4 + reg;
      int gr = row0 + row;
      if (gr >= cntb) continue;
      #pragma unroll
      for (int j = 0; j < 4; j++) {
        int col = w * 64 + j * 16 + fi;
        float v = acc[i][j][reg];
        if (mode == 3) { C[cBase + (long)gr * 256 + col] = (v - muS[row]) * rsS[row]; }
        else if (mode == 4) { X[xBase + (long)gr * 256 + col] += (v - muS[row]) * rsS[row]; }
        else if (mode == 2) { v = (v > 0.f) ? (v + 1.f) : expf(v); C[cBase + (long)gr * 256 + col] = v; }
        else { C[cBase + (long)gr * 256 + col] = v; }
      }
    }
  }
}

// ---------------------------------------------------------------------------
// fp32-B MFMA GEMM (dmatrix only).
// ---------------------------------------------------------------------------
__global__ __launch_bounds__(256) void gemm_f32b_kernel(
    const float* __restrict__ A, const float* __restrict__ B, float* __restrict__ C,
    int M, int N, int Kd, long sA, long sB, long sC, float alpha)
{
  int b = blockIdx.z;
  const float* Ab = A + (long)b * sA;
  const float* Bb = B + (long)b * sB;
  float* Cb = C + (long)b * sC;
  int row0 = blockIdx.y * 128, col0 = blockIdx.x * 128;
  int t = threadIdx.x;
  int lane = t & 63, wid = t >> 6, wm = wid >> 1, wn = wid & 1;
  int fi = lane & 15, fq = lane >> 4;
  __shared__ __align__(16) short Ah[128][36];
  __shared__ __align__(16) short Al[128][36];
  __shared__ __align__(16) short Bsh[128][36];
  __shared__ __align__(16) short Bsl[128][36];
  f32x4 acc[4][4];
  #pragma unroll
  for (int i = 0; i < 4; i++)
    #pragma unroll
    for (int j = 0; j < 4; j++)
      acc[i][j] = (f32x4){0.f, 0.f, 0.f, 0.f};
  int tr = t >> 3, tc = (t & 7) * 4;
  int bn = (t & 31) * 4, bk = t >> 5;
  for (int k0 = 0; k0 < Kd; k0 += 32) {
    #pragma unroll
    for (int p = 0; p < 4; p++) {
      int r = tr + p * 32, gr = row0 + r;
      float4 v = make_float4(0.f, 0.f, 0.f, 0.f);
      if (gr < M) v = *(const float4*)&Ab[(long)gr * Kd + k0 + tc];
      float vv[4] = {v.x, v.y, v.z, v.w};
      #pragma unroll
      for (int e = 0; e < 4; e++) {
        short h = f2bf(vv[e]); Ah[r][tc + e] = h; Al[r][tc + e] = f2bf(vv[e] - bf2f(h));
      }
    }
    #pragma unroll
    for (int p = 0; p < 4; p++) {
      int kk = bk + p * 8;
      long gkN = (long)(k0 + kk) * N;
      #pragma unroll
      for (int e = 0; e < 4; e++) {
        int gc = col0 + bn + e;
        float v = (gc < N) ? Bb[gkN + gc] : 0.f;
        short h = f2bf(v); Bsh[bn + e][kk] = h; Bsl[bn + e][kk] = f2bf(v - bf2f(h));
      }
    }
    __syncthreads();
    short8 ah[4], al[4], bh[4], bl[4];
    #pragma unroll
    for (int i = 0; i < 4; i++) {
      ah[i] = *(const short8*)&Ah[wm * 64 + i * 16 + fi][fq * 8];
      al[i] = *(const short8*)&Al[wm * 64 + i * 16 + fi][fq * 8];
    }
    #pragma unroll
    for (int j = 0; j < 4; j++) {
      bh[j] = *(const short8*)&Bsh[wn * 64 + j * 16 + fi][fq * 8];
      bl[j] = *(const short8*)&Bsl[wn * 64 + j * 16 + fi][fq * 8];
    }
    #pragma unroll
    for (int i = 0; i < 4; i++)
      #pragma unroll
      for (int j = 0; j < 4; j++) {
        acc[i][j] = __builtin_amdgcn_mfma_f32_16x16x32_bf16(ah[i], bh[j], acc[i][j], 0, 0, 0);
        acc[i][j] = __builtin_amdgcn_mfma_f32_16x16x32_bf16(ah[i], bl[j], acc[i][j], 0, 0, 0);
        acc[i][j] = __builtin_amdgcn_mfma_f32_16x16x32_bf16(al[i], bh[j], acc[i][j], 0, 0, 0);
      }
    __syncthreads();
  }
  #pragma unroll
  for (int i = 0; i < 4; i++) {
    #pragma unroll
    for (int reg = 0; reg < 4; reg++) {
      int gr = row0 + wm * 64 + i * 16 + fq * 4 + reg;
      if (gr >= M) continue;
      #pragma unroll
      for (int j = 0; j < 4; j++) {
        int gc = col0 + wn * 64 + j * 16 + fi;
        if (gc < N) Cb[(long)gr * N + gc] = acc[i][j][reg] * alpha;
      }
    }
  }
}

// ---------------------------------------------------------------------------
__device__ __forceinline__ float2 blk_sum2_256(float a, float b)
{
  __shared__ float sa[4], sb[4];
  int lane = threadIdx.x & 63, w = threadIdx.x >> 6;
  #pragma unroll
  for (int off = 32; off > 0; off >>= 1) { a += __shfl_down(a, off, 64); b += __shfl_down(b, off, 64); }
  if (lane == 0) { sa[w] = a; sb[w] = b; }
  __syncthreads();
  float ra = sa[0] + sa[1] + sa[2] + sa[3];
  float rb = sb[0] + sb[1] + sb[2] + sb[3];
  __syncthreads();
  return make_float2(ra, rb);
}

__global__ void cvt2_kernel(float* dst, const float* s0, const float* s1, long n) {
  long i = (long)blockIdx.x * 256 + threadIdx.x;
  if (i < n) dst[i] = s0[i];
  else if (i < 2 * n) dst[i] = s1[i - n];
}

__global__ void bcast_seeds_kernel(float* seeds, const float* st) {
  long i = (long)blockIdx.x * 256 + threadIdx.x;
  if (i < 4L * 25600) seeds[i] = st[i % 25600];
}

// KV[s,h,d,e] = / += sum_r K*V*inv_s ; Ksum[s,h,d] = / += sum_r K.
__global__ __launch_bounds__(1024) void kv_kernel(
    const float* __restrict__ Kb, const float* __restrict__ Vb,
    float* __restrict__ KV, float* __restrict__ Ksum,
    int s_len, float inv_s, int bmask, int bxor,
    const int* __restrict__ segOff, const int* __restrict__ segCnt,
    int axor, int gmin, int gmax, int chunk)
{
  int s = blockIdx.x, h = blockIdx.y;
  long srcBase; int slim;
  if (segOff) {
    int g = s & 7;
    if (g < gmin || g > gmax) return;
    int src = s ^ axor;
    srcBase = (long)(src & 7) * ARENA + segOff[src];
    slim = segCnt[src];
  } else {
    srcBase = (long)s * s_len;
    slim = s_len;
  }
  bool direct = (gridDim.z == 1);
  int s0b = blockIdx.z * chunk;
  int send = min(s0b + chunk, slim);
  __shared__ float Kt[32][33];
  __shared__ float Vt[32][33];
  int tx = threadIdx.x, ty = threadIdx.y;
  float acc = 0.f, ks = 0.f;
  for (int s0 = s0b; s0 < send; s0 += 32) {
    int sr = s0 + ty;
    float kvv = 0.f, vvv = 0.f;
    if (sr < send) {
      long base = (srcBase + sr) * 256 + h * 32 + tx;
      kvv = Kb[base]; vvv = Vb[base];
    }
    Kt[ty][tx] = kvv; Vt[ty][tx] = vvv;
    __syncthreads();
    #pragma unroll
    for (int j = 0; j < 32; j++) acc += Kt[j][ty] * Vt[j][tx];
    if (tx == 0) {
      #pragma unroll
      for (int j = 0; j < 32; j++) ks += Kt[j][ty];
    }
    __syncthreads();
  }
  if (direct) {
    KV[((s * 8 + h) * 32 + ty) * 32 + tx] = acc * inv_s;
    if (tx == 0) Ksum[s * 256 + h * 32 + ty] = ks;
  } else {
    if (s0b >= send) return;
    atomicAdd(&KV[((s * 8 + h) * 32 + ty) * 32 + tx], acc * inv_s);
    if (tx == 0) atomicAdd(&Ksum[s * 256 + h * 32 + ty], ks);
  }
}

// msg = (Q·KV) * Z * s_scale ; Z = 1/(Q·Ksum + 1e-6).
__global__ __launch_bounds__(256) void zmsg_kernel(
    const float* __restrict__ Q, const float* __restrict__ KV,
    const float* __restrict__ Ksum, float* __restrict__ msg, int l, float s_scale,
    const int* __restrict__ segOff, const int* __restrict__ segCnt, int gmin, int gmax)
{
  int s = blockIdx.x;
  long rowBase; int cb;
  if (segOff) {
    int g = s & 7;
    if (g < gmin || g > gmax) return;
    rowBase = (long)g * ARENA + segOff[s];
    cb = segCnt[s];
  } else {
    rowBase = (long)s * l;
    cb = l;
  }
  int r0 = blockIdx.y * 32;
  if (r0 >= cb) return;
  int t = threadIdx.x;
  __shared__ float KVs[8192];
  __shared__ float QL[256];
  __shared__ float Zl[8];
  for (int i = t; i < 8192; i += 256) KVs[i] = KV[s * 8192 + i];
  float Ks = Ksum[s * 256 + t];
  __syncthreads();
  int h = t >> 5, e = t & 31;
  for (int rr = 0; rr < 32; rr++) {
    int row = r0 + rr;
    if (row >= cb) break;
    long base = (rowBase + row) * 256;
    QL[t] = Q[base + t];
    __syncthreads();
    float p = QL[t] * Ks;
    #pragma unroll
    for (int off = 16; off > 0; off >>= 1) p += __shfl_down(p, off, 32);
    if (e == 0) Zl[h] = 1.f / (p + 1e-6f);
    __syncthreads();
    float acc = 0.f;
    const float* kvh = KVs + h * 1024;
    #pragma unroll
    for (int d = 0; d < 32; d++) acc += QL[h * 32 + d] * kvh[d * 32 + e];
    msg[base + t] = acc * Zl[h] * s_scale;
    __syncthreads();
  }
}

// ---------------- topic pipeline ----------
__global__ void tm_build_kernel(const float* __restrict__ t0,
                                const float* __restrict__ t1, float* __restrict__ tm) {
  int n = blockIdx.x, m = blockIdx.y, l = threadIdx.x;
  __shared__ float t0s[96];
  if (l < 96) t0s[l] = t0[(n * 96 + l) * 100 + m];
  __syncthreads();
  if (l >= 100) return;
  float acc = 0.f;
  #pragma unroll 4
  for (int d = 0; d < 96; d++)
    acc += t0s[d] * t1[(n * 96 + d) * 100 + l];
  tm[(n * 100 + m) * 100 + l] = floorf(acc * 0.0625f);
}

__global__ __launch_bounds__(256) void tm_post_kernel(const float* __restrict__ tm,
                                                      int* __restrict__ tmidx) {
  int n = blockIdx.x, t = threadIdx.x;
  __shared__ float TM[100][100];
  __shared__ float cmax[100], csum[100], rmax[100], rsum[100];
  for (int i = t; i < 10000; i += 256) TM[i / 100][i % 100] = tm[n * 10000 + i];
  __syncthreads();
  if (t < 100) {
    int l = t;
    float mx = -1e30f;
    for (int m = 0; m < 100; m++) mx = fmaxf(mx, TM[m][l]);
    float s = 0.f;
    for (int m = 0; m < 100; m++) s += expf(TM[m][l] - mx);
    cmax[l] = mx; csum[l] = s;
    int m = t;
    float mx2 = -1e30f;
    for (int l2 = 0; l2 < 100; l2++) mx2 = fmaxf(mx2, TM[m][l2]);
    float s2 = 0.f;
    for (int l2 = 0; l2 < 100; l2++) s2 += expf(TM[m][l2] - mx2);
    rmax[m] = mx2; rsum[m] = s2;
  }
  __syncthreads();
  if (t < 100) {
    int m = t;
    float best = -1e30f; int bi = 0;
    for (int l = 0; l < 100; l++) {
      float x = TM[m][l];
      float v = (expf(x - cmax[l]) / csum[l]) * (expf(x - rmax[m]) / rsum[m]);
      if (v > best) { best = v; bi = l; }
    }
    tmidx[n * 100 + m] = bi;
  }
}

// seedsF: adaptive-pool(seeds,160) ++ topicp (inline) -> LN -> transposed sT.
__global__ void seedsF_kernel(const float* __restrict__ seeds,
                              const float* __restrict__ t0raw,
                              const float* __restrict__ t1raw,
                              const int* __restrict__ tmidx, float* __restrict__ sT) {
  int n = blockIdx.x, k = blockIdx.y, t = threadIdx.x;
  float v;
  if (t < 160) {
    int s = (t * 256) / 160;
    int e = ((t + 1) * 256 + 159) / 160;
    float a = 0.f;
    for (int i = s; i < e; i++) a += seeds[(n * 100 + k) * 256 + i];
    v = a / (float)(e - s);
  } else {
    int j = t - 160;
    int g = tmidx[300 + k];
    float a, b;
    if (j < 48) {
      a = t0raw[(n * 96 + 2 * j) * 100 + k];
      b = t0raw[(n * 96 + 2 * j + 1) * 100 + k];
    } else {
      int d0 = 2 * j - 96;
      a = t1raw[(n * 96 + d0) * 100 + g];
      b = t1raw[(n * 96 + d0 + 1) * 100 + g];
    }
    v = 0.5f * (a + b);
  }
  float2 r = blk_sum2_256(v, v * v);
  float m = r.x * (1.f / 256.f);
  float var = r.y * (1.f / 256.f) - m * m;
  sT[n * 25600 + t * 100 + k] = (v - m) * rsqrtf(var + 1e-5f);
}

// ---------------- dmatrix post ----------------
__global__ void softmax_rows_kernel(const float* dm, float* prob, int* amax) {
  long row = blockIdx.x; int t = threadIdx.x;
  __shared__ float red[128]; __shared__ int ri[128];
  float v = (t < 100) ? dm[row * 100 + t] : -1e30f;
  red[t] = v; ri[t] = t; __syncthreads();
  for (int off = 64; off > 0; off >>= 1) {
    if (t < off) {
      if (red[t + off] > red[t] || (red[t + off] == red[t] && ri[t + off] < ri[t])) {
        red[t] = red[t + off]; ri[t] = ri[t + off];
      }
    }
    __syncthreads();
  }
  float mx = red[0];
  if (t == 0) amax[row] = ri[0];
  __syncthreads();
  float e = (t < 100) ? expf(v - mx) : 0.f;
  red[t] = e; __syncthreads();
  for (int off = 64; off > 0; off >>= 1) { if (t < off) red[t] += red[t + off]; __syncthreads(); }
  float s = red[0];
  if (t < 100) prob[row * 100 + t] = e / s;
}

// coalesced column-sum: rows read contiguously, reg accumulate, 1 atomic/topic.
__global__ void colsum2_kernel(const float* __restrict__ prob, float* cs0, float* cs1) {
  int nh = blockIdx.x; int n = nh >> 1, half = nh & 1;
  int mc = blockIdx.y;
  int t = threadIdx.x;  // 128
  const float* p = prob + ((long)n * 8192 + (long)half * 4096 + (long)mc * 128) * 100;
  float acc = 0.f;
  if (t < 100) {
    for (int r = 0; r < 128; r++) acc += p[r * 100 + t];
    atomicAdd(&(half ? cs1 : cs0)[n * 100 + t], acc);
  }
}

__global__ void topk_kernel(const float* cs0, const float* cs1, int* inds) {
  int n = blockIdx.x, t = threadIdx.x;
  __shared__ float rv[128]; __shared__ int ri[128]; __shared__ int sbest;
  float base = (t < 100) ? cs0[n * 100 + t] * cs1[n * 100 + t] : -1.f;
  for (int kk = 0; kk < 6; kk++) {
    rv[t] = base; ri[t] = t; __syncthreads();
    for (int off = 64; off > 0; off >>= 1) {
      if (t < off) {
        if (rv[t + off] > rv[t] || (rv[t + off] == rv[t] && ri[t + off] < ri[t])) { rv[t] = rv[t + off]; ri[t] = ri[t + off]; }
      }
      __syncthreads();
    }
    if (t == 0) { inds[n * 6 + kk] = ri[0]; sbest = ri[0]; }
    __syncthreads();
    if (t == sbest) base = -1.f;
    __syncthreads();
  }
}

// ---------------- packed sample machinery ----------------
__global__ __launch_bounds__(1024) void count_kernel(const int* amax, const int* inds, int* segCnt) {
  int seg = blockIdx.x;
  int kk = seg >> 3, g = seg & 7, n = g & 3, half = g >> 2;
  int target = inds[n * 6 + kk];
  const int* am = amax + n * 8192 + half * 4096;
  int t = threadIdx.x;
  int lc = 0;
  #pragma unroll
  for (int j = 0; j < 4; j++) lc += (am[t * 4 + j] == target) ? 1 : 0;
  __shared__ int red[16];
  #pragma unroll
  for (int off = 32; off > 0; off >>= 1) lc += __shfl_down(lc, off, 64);
  if ((t & 63) == 0) red[t >> 6] = lc;
  __syncthreads();
  if (t == 0) {
    int s = 0;
    for (int w = 0; w < 16; w++) s += red[w];
    segCnt[seg] = s;
  }
}

// offs: segment offsets + cond flags + DENSE BLOCK TABLES.
__global__ void offs_kernel(const int* segCnt, int* segOff, float* condf,
                            int* tabCnt,
                            int2* t128_07, int2* t128_03, int2* t128_47,
                            int2* t32_07, int2* t32_03, int2* t32_47) {
  int t = threadIdx.x;
  if (t < 8) {
    int run = 0;
    for (int kk = 0; kk < 6; kk++) {
      segOff[kk * 8 + t] = run;
      run += (segCnt[kk * 8 + t] + 127) & ~127;
    }
  }
  if (t >= 8 && t < 14) {
    int kk = t - 8;
    int a = 0, b = 0;
    for (int g = 0; g < 4; g++) { a += segCnt[kk * 8 + g]; b += segCnt[kk * 8 + 4 + g]; }
    condf[kk] = (a > 0 && b > 0) ? 1.f : 0.f;
  }
  __syncthreads();
  __shared__ int pref[48];
  int2* tabs[6] = {t128_07, t128_03, t128_47, t32_07, t32_03, t32_47};
  for (int tb = 0; tb < 6; tb++) {
    int tile = (tb < 3) ? 128 : 32;
    int r = tb % 3;
    int nb = 0;
    if (t < 48) {
      int g = t & 7;
      bool in = (r == 0) || (r == 1 && g < 4) || (r == 2 && g >= 4);
      if (in) nb = (min(segCnt[t], 4096) + tile - 1) / tile;
      pref[t] = nb;
    }
    __syncthreads();
    for (int o = 1; o < 48; o <<= 1) {
      int v = 0;
      if (t < 48 && t >= o) v = pref[t - o];
      __syncthreads();
      if (t < 48) pref[t] += v;
      __syncthreads();
    }
    if (t < 48 && nb > 0) {
      int st = pref[t] - nb;
      for (int j = 0; j < nb; j++) tabs[tb][st + j] = make_int2(t, j * tile);
    }
    if (t == 0) tabCnt[tb] = pref[47];
    __syncthreads();
  }
}

// ord: stable compaction order + direct gather of packed rows.
__global__ __launch_bounds__(1024) void ord_kernel(const int* amax, const int* inds,
                                                   const int* segOff, int* ordP,
                                                   float* __restrict__ nf,
                                                   const float* __restrict__ f01) {
  int seg = blockIdx.x;
  int kk = seg >> 3, g = seg & 7, n = g & 3, half = g >> 2;
  int target = inds[n * 6 + kk];
  const int* am = amax + n * 8192 + half * 4096;
  int t = threadIdx.x;
  __shared__ int ts[1024];
  int f[4]; int lc = 0;
  #pragma unroll
  for (int j = 0; j < 4; j++) { f[j] = (am[t * 4 + j] == target) ? 1 : 0; lc += f[j]; }
  ts[t] = lc; __syncthreads();
  for (int off = 1; off < 1024; off <<= 1) {
    int add = (t >= off) ? ts[t - off] : 0;
    __syncthreads();
    ts[t] += add;
    __syncthreads();
  }
  int run = (t == 0) ? 0 : ts[t - 1];
  long base = (long)g * ARENA + segOff[seg];
  int* o = ordP + base;
  #pragma unroll
  for (int j = 0; j < 4; j++) {
    if (f[j]) {
      int tok = t * 4 + j;
      o[run] = tok;
      const float4* s4p = (const float4*)&f01[((long)g * 4096 + tok) * 256];
      float4* d4p = (float4*)&nf[(base + run) * 256];
      for (int c = 0; c < 64; c++) d4p[c] = s4p[c];
      run++;
    }
  }
}

// blockIdx.x = seg (spreads active blocks across XCDs).
__global__ void scatter_kernel(float* up, const float* nf, const int* ordP,
                               const int* segOff, const int* segCnt, const float* condf) {
  int seg = blockIdx.x;
  int kk = seg >> 3, g = seg & 7;
  int cntb = segCnt[seg];
  int row0 = blockIdx.y * 128;
  if (row0 >= cntb) return;
  long base = (long)g * ARENA + segOff[seg];
  float cf = condf[kk];
  int t = threadIdx.x;
  int c4 = (t & 63) * 4, rr = t >> 6;
  for (int p = 0; p < 32; p++) {
    int r = row0 + p * 4 + rr;
    if (r >= cntb) break;
    int tok = ordP[base + r];
    float4 add = *(const float4*)&nf[(base + r) * 256 + c4];
    float4* dst = (float4*)&up[((long)g * 4096 + tok) * 256 + c4];
    float4 cur = *dst;
    cur.x += add.x * cf; cur.y += add.y * cf; cur.z += add.z * cf; cur.w += add.w * cf;
    *dst = cur;
  }
}

// up01 aliases out's feat region (index-identical); in-place RMW.
__global__ void final_mix_kernel(const float* f01, float* out_up, const int* amax,
                                 const int* inds) {
  int b = blockIdx.y, half = b >> 2, n = b & 3;
  int l = blockIdx.x, c = threadIdx.x;
  int a = amax[n * 8192 + half * 4096 + l];
  const int* in_ = inds + n * 6;
  bool member = (a == in_[0]) | (a == in_[1]) | (a == in_[2]) | (a == in_[3]) | (a == in_[4]) | (a == in_[5]);
  long idx = ((long)b * 4096 + l) * 256 + c;
  float up = out_up[idx];
  out_up[idx] = (member ? 0.f : 1.f) * f01[idx] + up;
}

// tmi2 — block per (y-row, n*2+half, topic-group of 50). 3 y-rows x 50 topics
// staged in LDS; coalesced loads; contiguous center reads + out writes.
__global__ __launch_bounds__(256) void tmi2_kernel(const float* __restrict__ dmat,
                                                   float* __restrict__ out) {
  int y = blockIdx.x;          // 0..63
  int nh = blockIdx.y;         // n*2+half
  int n = nh >> 1, half = nh & 1;
  int bg = blockIdx.z;         // topic group: 0 -> 0..49, 1 -> 50..99
  const float* dm = dmat + (long)n * 819200 + (long)half * 409600;
  __shared__ float P[50][3][66];
  int t = threadIdx.x;
  for (int j = t; j < 50 * 64; j += 256) {
    int bb = j >> 6, x = j & 63;
    long pb = (long)(bg * 50 + bb) * 4096;
    #pragma unroll
    for (int r = 0; r < 3; r++) {
      int gy = y + r - 1;
      P[bb][r][x] = (gy >= 0 && gy < 64) ? dm[pb + (long)gy * 64 + x] : 0.f;
    }
  }
  __syncthreads();
  long outBase = 8388608L + (long)half * 1638400 + (long)n * 409600;
  for (int j = t; j < 64 * 50; j += 256) {
    int x = j / 50, bb = j % 50;
    float s = 0.f;
    #pragma unroll
    for (int r = 0; r < 3; r++) {
      s += P[bb][r][x];
      if (x > 0) s += P[bb][r][x - 1];
      if (x < 63) s += P[bb][r][x + 1];
    }
    long i = (long)(y * 64 + x) * 100 + bg * 50 + bb;
    out[outBase + i] = dm[i] * (s * (1.f / 9.f));
  }
}

// ---------------------------------------------------------------------------
extern "C" void kernel_launch(void* const* d_in, const int* in_sizes, int n_in,
                              void* d_out, int out_size, void* d_ws, size_t ws_size,
                              hipStream_t stream)
{
  (void)in_sizes; (void)n_in; (void)out_size; (void)ws_size;
  const float* feat0_in = (const float*)d_in[0];
  const float* feat1_in = (const float*)d_in[1];
  const float* topic0 = (const float*)d_in[2];
  const float* topic1 = (const float*)d_in[3];
  const float* seed_tokens = (const float*)d_in[4];
  const float* Wq = (const float*)d_in[5];
  const float* Wk = (const float*)d_in[6];
  const float* Wv = (const float*)d_in[7];
  const float* Wm = (const float*)d_in[8];
  const float* W1 = (const float*)d_in[9];
  const float* W2 = (const float*)d_in[10];
  float* out = (float*)d_out;

  float* base = (float*)d_ws;
  long off = 0;
  auto alloc = [&](long n) -> float* { float* p = base + off; off += (n + 255) & ~255L; return p; };
  float* f01   = alloc(8388608);          // [8][4096][256]
  float* qb    = alloc(8L * ARENA * 256); // Q / LN(msg2)
  float* kb    = alloc(8L * ARENA * 256); // K / msg / h1 low   (kb,vb contiguous)
  float* vb    = alloc(8L * ARENA * 256); // V / h1 high
  float* nf    = alloc(8L * ARENA * 256); // packed sample tokens
  float* seeds = alloc(102400);
  float* kvks  = alloc(48 * 8192 + 48 * 256);
  float* dmat  = alloc(3276800);
  short* wbuf  = (short*)alloc(5242880);
  float* tmb   = alloc(40000);
  float* sT    = alloc(102400);
  float* cs0   = alloc(400);
  float* cs1   = alloc(400);
  float* condf = alloc(256);
  int* tmidx  = (int*)alloc(400);
  int* amax   = (int*)alloc(32768);
  int* inds   = (int*)alloc(256);
  int* segCnt = (int*)alloc(256);
  int* segOffA= (int*)alloc(256);
  int* ordP   = (int*)alloc(8L * ARENA);
  int* tabCnt = (int*)alloc(64);
  int2* T128_07 = (int2*)alloc(640);
  int2* T128_03 = (int2*)alloc(320);
  int2* T128_47 = (int2*)alloc(320);
  int2* T32_07  = (int2*)alloc(2176);
  int2* T32_03  = (int2*)alloc(1088);
  int2* T32_47  = (int2*)alloc(1088);
  float* up01 = out;                      // aliases out's feat region

  const int m128[3] = {304, 152, 152};
  const int m32[3]  = {1072, 536, 536};
  int2* T128[3] = {T128_07, T128_03, T128_47};
  int2* T32[3]  = {T32_07, T32_03, T32_47};

  auto WOFF = [](int l) -> long { return (long)l * 1310720; };

  auto gmainZ = [&](const float* A, const float* A2, int aw, long wOff, int loD,
                    float* c0, float* c1, float* c2, int M, int Kd, int Ntot, int outW,
                    long sA_, long sC_, int bm, int bx,
                    int m0, int m1, int m2_, int nb) {
    dim3 g(Ntot / 128, (M + 127) / 128, nb), blk(256);
    gemm_main_kernel<<<g, blk, 0, stream>>>(A, A2, aw, wbuf + wOff, loD, c0, c1, c2,
        M, Kd, outW, sA_, sC_, bm, bx, nullptr, nullptr,
        nullptr, nullptr, nullptr, 0, 0, m0, m1, m2_);
  };
  auto gmainP = [&](const float* A, const float* A2, int aw, long wOff, int loD,
                    float* c0, float* c1, float* c2, int Kd, int Ntot, int outW,
                    int rQ, int rKV, int m0, int m1, int m2_) {
    int ymax = max(m128[rQ], m128[rKV]);
    dim3 g(Ntot / 128, ymax, 1), blk(256);
    gemm_main_kernel<<<g, blk, 0, stream>>>(A, A2, aw, wbuf + wOff, loD, c0, c1, c2,
        4096, Kd, outW, 0, 0, 0, 0, segOffA, segCnt,
        T128[rQ], T128[rKV], tabCnt, rQ, rKV, m0, m1, m2_);
  };
  auto g256Z = [&](const float* A, int aw, long wOff, int loD, float* C, float* X,
                   int M, int Kd, long sA_, long sC_, long sX_, int bm, int bx,
                   int mode, int nb) {
    dim3 g(1, (M + 63) / 64, nb), blk(256);
    gemm256_kernel<<<g, blk, 0, stream>>>(A, aw, wbuf + wOff, loD, C, X,
        M, Kd, sA_, sC_, sX_, bm, bx, mode);
  };
  auto g256P = [&](const float* A, int aw, long wOff, int loD, float* C, float* X,
                   int r, int mode) {
    dim3 g(1, m32[r], 1), blk(256);
    gemm256_seg_kernel<<<g, blk, 0, stream>>>(A, aw, wbuf + wOff, loD, C, X,
        segOffA, segCnt, T32[r], tabCnt + 3 + r, mode);
  };

  auto encTailZ = [&](float* x, int l, int s_len, float s_scale, int layer, int nb,
                      long sAx, int bmKV, int bxKV, int nch) {
    if (nch > 1)
      hipMemsetAsync(kvks, 0, (48 * 8192 + 48 * 256) * sizeof(float), stream);
    int chunk = (s_len + nch - 1) / nch;
    kv_kernel<<<dim3(nb, 8, nch), dim3(32, 32), 0, stream>>>(
        kb, vb, kvks, kvks + 48 * 8192, s_len, 1.f / s_scale, bmKV, bxKV,
        nullptr, nullptr, 0, 0, 7, chunk);
    zmsg_kernel<<<dim3(nb, (l + 31) / 32), 256, 0, stream>>>(
        qb, kvks, kvks + 48 * 8192, kb, l, s_scale, nullptr, nullptr, 0, 7);
    g256Z(kb, 256, WOFF(layer) + 393216, 65536, qb, nullptr,
          l, 256, sAx, sAx, 0, 7, 0, 3, nb);
    gmainZ(x, qb, 256, WOFF(layer) + 524288, 262144, kb, nullptr, nullptr,
           l, 512, 512, 512, sAx, sAx * 2, 7, 0, 1, 0, 0, nb);
    g256Z(kb, 512, WOFF(layer) + 1048576, 131072, nullptr, x,
          l, 512, sAx * 2, 0, sAx, 7, 0, 4, nb);
  };
  auto encTailP = [&](float* x, float s_scale, int layer, int r, int axor,
                      int gmin, int gmax) {
    kv_kernel<<<dim3(48, 8, 1), dim3(32, 32), 0, stream>>>(
        kb, vb, kvks, kvks + 48 * 8192, 4096, 1.f / s_scale, 0, 0,
        segOffA, segCnt, axor, gmin, gmax, 4096);
    zmsg_kernel<<<dim3(48, 128), 256, 0, stream>>>(
        qb, kvks, kvks + 48 * 8192, kb, 4096, s_scale, segOffA, segCnt, gmin, gmax);
    g256P(kb, 256, WOFF(layer) + 393216, 65536, qb, nullptr, r, 3);
    gmainP(x, qb, 256, WOFF(layer) + 524288, 262144, kb, nullptr, nullptr,
           512, 512, 512, r, r, 1, 0, 0);
    g256P(kb, 512, WOFF(layer) + 1048576, 131072, nullptr, x, r, 4);
  };

  // ---- init ----
  cvt2_kernel<<<32768, 256, 0, stream>>>(f01, feat0_in, feat1_in, 4194304);
  bcast_seeds_kernel<<<400, 256, 0, stream>>>(seeds, seed_tokens);
  prep_w_kernel<<<20480, 256, 0, stream>>>(Wq, Wk, Wv, Wm, W1, W2, wbuf);

  // ---- topic pipeline ----
  tm_build_kernel<<<dim3(4, 100), 128, 0, stream>>>(topic0, topic1, tmb);
  tm_post_kernel<<<4, 256, 0, stream>>>(tmb, tmidx);

  // ---- main encoder layers ----
  auto encSeedLayer = [&](int layer) {
    g256Z(seeds, 256, WOFF(layer), 196608, qb, nullptr,
          100, 256, 25600, 25600, 0, 7, 0, 2, 4);
    gmainZ(feat0_in, nullptr, 256, WOFF(layer) + 65536, 196608, kb, vb, nullptr,
           4096, 256, 512, 256, 1048576, 2097152, 7, 0, 2, 0, 0, 4);
    gmainZ(feat1_in, nullptr, 256, WOFF(layer) + 65536, 196608, kb + 1048576, vb + 1048576, nullptr,
           4096, 256, 512, 256, 1048576, 2097152, 7, 0, 2, 0, 0, 4);
    encTailZ(seeds, 100, 8192, 8192.f, layer, 4, 25600, 7, 0, 8);
  };
  auto encFeatLayer = [&](int layer) {
    g256Z(f01, 256, WOFF(layer), 196608, qb, nullptr,
          4096, 256, 1048576, 1048576, 0, 7, 0, 2, 8);
    gmainZ(seeds, nullptr, 256, WOFF(layer) + 65536, 196608, kb, vb, nullptr,
           100, 256, 512, 256, 25600, 25600, 3, 0, 2, 0, 0, 8);
    encTailZ(f01, 4096, 100, 100.f, layer, 8, 1048576, 7, 0, 1);
  };

  encSeedLayer(0);
  encFeatLayer(1);
  encSeedLayer(2);
  encFeatLayer(3);

  // ---- seeds final + dmatrix ----
  seedsF_kernel<<<dim3(4, 100), 256, 0, stream>>>(seeds, topic0, topic1, tmidx, sT);
  {
    dim3 g(1, 32, 4), blk(256);
    gemm_f32b_kernel<<<g, blk, 0, stream>>>(feat0_in, sT, dmat, 4096, 100, 256, 1048576, 25600, 819200, 0.0625f);
    gemm_f32b_kernel<<<g, blk, 0, stream>>>(feat1_in, sT, dmat + 409600, 4096, 100, 256, 1048576, 25600, 819200, 0.0625f);
  }
  float* prob = kb;
  softmax_rows_kernel<<<32768, 128, 0, stream>>>(dmat, prob, amax);
  hipMemsetAsync(cs0, 0, 1024 * sizeof(float), stream);  // covers cs0+cs1 slots
  colsum2_kernel<<<dim3(8, 32), 128, 0, stream>>>(prob, cs0, cs1);
  topk_kernel<<<4, 128, 0, stream>>>(cs0, cs1, inds);

  hipMemsetAsync(up01, 0, 8388608 * sizeof(float), stream);

  // ---- sample phase: 48 packed segments, table-driven GEMMs ----
  count_kernel<<<48, 1024, 0, stream>>>(amax, inds, segCnt);
  offs_kernel<<<1, 64, 0, stream>>>(segCnt, segOffA, condf, tabCnt,
                                    T128_07, T128_03, T128_47, T32_07, T32_03, T32_47);
  ord_kernel<<<48, 1024, 0, stream>>>(amax, inds, segOffA, ordP, nf, f01);

  for (int idt = 0; idt < 2; idt++) {
    int wA = 4 + idt * 2, wB = wA + 1;
    gmainP(nf, nullptr, 256, WOFF(wA), 196608, qb, kb, vb,
           256, 768, 256, 0, 0, 2, 2, 0);
    encTailP(nf, 4096.f, wA, 0, 0, 0, 7);
    gmainP(nf, nullptr, 256, WOFF(wB), 196608, qb, kb, vb,
           256, 768, 256, 1, 2, 2, 2, 0);
    encTailP(nf, 4096.f, wB, 1, 4, 0, 3);
    gmainP(nf, nullptr, 256, WOFF(wB), 196608, qb, kb, vb,
           256, 768, 256, 2, 1, 2, 2, 0);
    encTailP(nf, 4096.f, wB, 2, 4, 4, 7);
  }
  scatter_kernel<<<dim3(48, 32), 256, 0, stream>>>(up01, nf, ordP, segOffA, segCnt, condf);

  // ---- outputs ----
  final_mix_kernel<<<dim3(4096, 8), 256, 0, stream>>>(f01, up01, amax, inds);
  tmi2_kernel<<<dim3(64, 8, 2), 256, 0, stream>>>(dmat, out);
}